// Round 22
// baseline (278.114 us; speedup 1.0000x reference)
//
#include <hip/hip_runtime.h>
#include <stdint.h>

#define DMODEL 1024
#define NHEAD 16
#define HDIM 64
#define SEQ 2048
#define NBATCH 2
#define MTOK 4096  // NBATCH*SEQ

typedef float f32x4 __attribute__((ext_vector_type(4)));
typedef short s16x8 __attribute__((ext_vector_type(8)));
typedef unsigned short u16;
typedef u16 u16x4 __attribute__((ext_vector_type(4)));

typedef __attribute__((address_space(1))) const void* as1_cvp;
typedef __attribute__((address_space(3))) void* as3_vp;

__device__ inline u16 f2bf(float f) {
  uint32_t u = __float_as_uint(f);
  u = u + 0x7FFFu + ((u >> 16) & 1u);
  return (u16)(u >> 16);
}

// T12 primitive: single-instr packed f32x2 -> bf16x2 (RNE), no builtin on
// gfx950 (m240) -> inline asm.
__device__ inline uint32_t pk_bf16(float lo, float hi) {
  uint32_t r;
  asm("v_cvt_pk_bf16_f32 %0, %1, %2" : "=v"(r) : "v"(lo), "v"(hi));
  return r;
}

__device__ inline void gload_lds16(const void* g, void* l) {
  __builtin_amdgcn_global_load_lds((as1_cvp)g, (as3_vp)l, 16, 0, 0);
}

// ---------------- ALL fp32 -> bf16 converts in ONE dispatch ----------------
// 16 chunks of 1M elements: X(4) | Wq Wk Wv(3) | Wo(1) | Wup(4) | Wdown(4).
__global__ __launch_bounds__(256) void k_f2bf_all(
    const float* __restrict__ X, const float* __restrict__ Wq,
    const float* __restrict__ Wk, const float* __restrict__ Wv,
    const float* __restrict__ Wo, const float* __restrict__ Wup,
    const float* __restrict__ Wdown, u16* __restrict__ dX,
    u16* __restrict__ dqkv, u16* __restrict__ dwo, u16* __restrict__ dup,
    u16* __restrict__ ddown) {
  const int c = blockIdx.y;  // 0..15
  const size_t CH = 1024 * 1024;
  const float* src;
  u16* dst;
  if (c < 4) {
    src = X + c * CH; dst = dX + c * CH;
  } else if (c < 7) {
    src = (c == 4 ? Wq : c == 5 ? Wk : Wv) ; dst = dqkv + (size_t)(c - 4) * CH;
  } else if (c == 7) {
    src = Wo; dst = dwo;
  } else if (c < 12) {
    src = Wup + (size_t)(c - 8) * CH; dst = dup + (size_t)(c - 8) * CH;
  } else {
    src = Wdown + (size_t)(c - 12) * CH; dst = ddown + (size_t)(c - 12) * CH;
  }
  const int n4 = (int)(CH / 4);
  int i = blockIdx.x * 256 + threadIdx.x;
  const int stride = gridDim.x * 256;
  for (; i < n4; i += stride) {
    f32x4 v = ((const f32x4*)src)[i];
    u16x4 o;
    o[0] = f2bf(v[0]); o[1] = f2bf(v[1]); o[2] = f2bf(v[2]); o[3] = f2bf(v[3]);
    ((u16x4*)dst)[i] = o;
  }
}

// ============ 256-col-tile 8-wave GEMM: C[M,N] = A @ B^T + bias ============
// BN=256, BM = MH*128, BK=64, 512 threads = 8 waves (2M x 4N). T2 swizzle
// (linear LDS dest + pre-permuted global source chunk, reads XOR chunk^(row&7)
// -> conflict-free b128), T4 staggered counted vmcnt (A at iter top, B mid),
// T5 setprio. Proven R12: -34 us on the three projection/FFN GEMMs.
// MODE: 0 = f32 split-K partial out (kz=0 -> Cv+bias, kz=1 -> Cv1),
//       2 = bf16+relu out via Sg LDS stage (overlaid on staging LDS).
template <int MODE, int KSPL, int MH>
__global__ __launch_bounds__(512, 2) void k_gemm256(
    const u16* __restrict__ A, const u16* __restrict__ B,
    const float* __restrict__ bias, void* __restrict__ Cv,
    void* __restrict__ Cv1, int M, int N, int K) {
  constexpr int HALVES = MH + 2;  // MH A-halves + 2 B-halves, 16KB each
  __shared__ alignas(16) u16 lds[2 * HALVES * 8192];
  const int t = threadIdx.x;
  const int w = t >> 6;        // 0..7
  const int l = t & 63;
  const int wr = w >> 2;       // 0..1 (M half)
  const int wc = w & 3;        // 0..3 (N quarter)
  const int lr = l & 15, lg = l >> 4;
  const int r7 = lr & 7;
  const int lrow8 = l >> 3;

  // bijective XCD swizzle on (bx,by); nwg % 8 == 0 for all our grids
  const int gx = gridDim.x;
  int lin = blockIdx.y * gx + blockIdx.x;
  const int nwg = gx * gridDim.y;
  lin = (lin & 7) * (nwg >> 3) + (lin >> 3);
  const int bx = lin % gx, by = lin / gx;
  const int kz = KSPL > 1 ? blockIdx.z : 0;
  const int Kc = K / KSPL, kbeg = kz * Kc;
  const int brow = by * (MH * 128), bcol = bx * 256;

  constexpr int MF = MH * 4;  // m-frags per wave
  const f32x4 Z4 = {0.f, 0.f, 0.f, 0.f};
  f32x4 acc[MF][4];
#pragma unroll
  for (int m = 0; m < MF; m++)
#pragma unroll
    for (int n = 0; n < 4; n++) acc[m][n] = Z4;

  const u16* Ag = A + (size_t)brow * K + kbeg;
  const u16* Bg = B + (size_t)bcol * K + kbeg;
  const int swz_src = ((l & 7) ^ ((l >> 3) & 7)) << 3;  // element offset

  auto ldsH = [&](int buf, int half) { return lds + (buf * HALVES + half) * 8192; };
  auto stageA = [&](int kt, int buf) {
#pragma unroll
    for (int h = 0; h < MH; h++) {
      u16* lb = ldsH(buf, h);
      const int rb = h * 128;
      gload_lds16(Ag + (size_t)(rb + w * 8 + lrow8) * K + kt * 64 + swz_src,
                  lb + w * 512);
      gload_lds16(Ag + (size_t)(rb + 64 + w * 8 + lrow8) * K + kt * 64 + swz_src,
                  lb + (8 + w) * 512);
    }
  };
  auto stageB = [&](int kt, int buf) {
#pragma unroll
    for (int h = 0; h < 2; h++) {
      u16* lb = ldsH(buf, MH + h);
      const int rb = h * 128;
      gload_lds16(Bg + (size_t)(rb + w * 8 + lrow8) * K + kt * 64 + swz_src,
                  lb + w * 512);
      gload_lds16(Bg + (size_t)(rb + 64 + w * 8 + lrow8) * K + kt * 64 + swz_src,
                  lb + (8 + w) * 512);
    }
  };

  stageA(0, 0);
  stageB(0, 0);

  const int nkt = Kc >> 6;
  const int arb = (MH == 2) ? 0 : wr * 64;  // A row base within half
  const int brb = (wc & 1) * 64;            // B row base within half
  for (int kt = 0; kt < nkt; ++kt) {
    const int cur = kt & 1, nx = cur ^ 1;
    if (kt + 1 < nkt) {
      stageA(kt + 1, nx);
      if (MH == 2)
        asm volatile("s_waitcnt vmcnt(4)" ::: "memory");
      else
        asm volatile("s_waitcnt vmcnt(2)" ::: "memory");
    } else {
      asm volatile("s_waitcnt vmcnt(0)" ::: "memory");
    }
    __builtin_amdgcn_s_barrier();
    __builtin_amdgcn_sched_barrier(0);
    const u16* Ah = ldsH(cur, (MH == 2) ? wr : 0);
    const u16* Bh = ldsH(cur, MH + (wc >> 1));
#pragma unroll
    for (int kk = 0; kk < 2; kk++) {
      s16x8 bfr[4];
#pragma unroll
      for (int nf = 0; nf < 4; nf++)
        bfr[nf] = *(const s16x8*)(Bh + (brb + nf * 16 + lr) * 64 +
                                  (((kk * 4 + lg) ^ r7) << 3));
#pragma unroll
      for (int mh = 0; mh < MH; mh++) {
        s16x8 afr[4];
#pragma unroll
        for (int i = 0; i < 4; i++)
          afr[i] = *(const s16x8*)(Ah + (arb + (mh * 4 + i) * 16 + lr) * 64 +
                                   (((kk * 4 + lg) ^ r7) << 3));
        __builtin_amdgcn_s_setprio(1);
#pragma unroll
        for (int i = 0; i < 4; i++)
#pragma unroll
          for (int nf = 0; nf < 4; nf++)
            acc[mh * 4 + i][nf] = __builtin_amdgcn_mfma_f32_16x16x32_bf16(
                afr[i], bfr[nf], acc[mh * 4 + i][nf], 0, 0, 0);
        __builtin_amdgcn_s_setprio(0);
      }
      if (kk == 0 && kt + 1 < nkt) stageB(kt + 1, nx);  // mid-iter issue
    }
    __builtin_amdgcn_sched_barrier(0);
    __builtin_amdgcn_s_barrier();
  }

  const int lg4 = lg * 4;
  const int wrb = wr * (MH == 2 ? 128 : 64);
  if (MODE == 0) {
    float* Co = (kz == 0) ? (float*)Cv : (float*)Cv1;
#pragma unroll
    for (int nf = 0; nf < 4; nf++) {
      const int col = bcol + wc * 64 + nf * 16 + lr;
      const float bvv = (kz == 0) ? bias[col] : 0.0f;
#pragma unroll
      for (int mf = 0; mf < MF; mf++) {
        const int row0 = brow + wrb + mf * 16 + lg4;
#pragma unroll
        for (int r = 0; r < 4; r++)
          Co[(size_t)(row0 + r) * N + col] = acc[mf][nf][r] + bvv;
      }
    }
  } else {
    u16* Sgw = lds + w * 2176;
    float bn[4];
#pragma unroll
    for (int nf = 0; nf < 4; nf++) bn[nf] = bias[bcol + wc * 64 + nf * 16 + lr];
    const int ch = l & 7;
#pragma unroll
    for (int hh = 0; hh < MH * 2; hh++) {  // 32-row groups
#pragma unroll
      for (int mm = 0; mm < 2; mm++) {
        const int mf = hh * 2 + mm;
#pragma unroll
        for (int nf = 0; nf < 4; nf++)
#pragma unroll
          for (int r = 0; r < 4; r++) {
            float vv = acc[mf][nf][r] + bn[nf];
            if (MODE == 2) vv = vv > 0.f ? vv : 0.f;
            Sgw[(mm * 16 + lg4 + r) * 68 + nf * 16 + lr] = f2bf(vv);
          }
      }
#pragma unroll
      for (int i = 0; i < 4; i++) {
        const int rr = i * 8 + (l >> 3);
        u16x4 a0 = *(const u16x4*)(Sgw + rr * 68 + ch * 8);
        u16x4 a1 = *(const u16x4*)(Sgw + rr * 68 + ch * 8 + 4);
        s16x8 v8;
#pragma unroll
        for (int j = 0; j < 4; j++) { v8[j] = (short)a0[j]; v8[4 + j] = (short)a1[j]; }
        *(s16x8*)((u16*)Cv + (size_t)(brow + wrb + hh * 32 + rr) * N +
                  (bcol + wc * 64 + ch * 8)) = v8;
      }
    }
  }
}

// ============ fused QKV GEMM: 256x256 tile (MH=2), grid (12,16)=192 ========
// One dispatch round (192 < 256 CUs), K-loop identical to k_gemm256<MH=2>.
// Wave tile = 128 rows x 64 cols -> wave-uniform region routing.
// R21: attn now reads K and V^T DIRECTLY from global (L1/L2-served) -> all
// epilogue swizzles removed; K and V^T written PLAIN:
//  Q: qbf[tok][ck] plain, PRE-SCALED by 0.125 (bf16-exact)
//  K: kbf[tok][ck] plain
//  V: vtbf[b][h][d][s] plain transposed via 2x2 Sg passes
__global__ __launch_bounds__(512, 2) void k_gemm256_qkv(
    const u16* __restrict__ A, const u16* __restrict__ B,
    const float* __restrict__ bq, const float* __restrict__ bk,
    const float* __restrict__ bv, u16* __restrict__ qbf, u16* __restrict__ kbf,
    u16* __restrict__ vtbf, int M, int N, int K) {
  __shared__ alignas(16) u16 lds[2 * 4 * 8192];  // 128 KB
  const int t = threadIdx.x;
  const int w = t >> 6, l = t & 63;
  const int wr = w >> 2, wc = w & 3;
  const int lr = l & 15, lg = l >> 4;
  const int r7 = lr & 7;
  const int lrow8 = l >> 3;

  const int gx = gridDim.x;
  int lin = blockIdx.y * gx + blockIdx.x;
  const int nwg = gx * gridDim.y;
  lin = (lin & 7) * (nwg >> 3) + (lin >> 3);
  const int bx = lin % gx, by = lin / gx;
  const int brow = by * 256, bcol = bx * 256;

  const f32x4 Z4 = {0.f, 0.f, 0.f, 0.f};
  f32x4 acc[8][4];
#pragma unroll
  for (int m = 0; m < 8; m++)
#pragma unroll
    for (int n = 0; n < 4; n++) acc[m][n] = Z4;

  const u16* Ag = A + (size_t)brow * K;
  const u16* Bg = B + (size_t)bcol * K;
  const int swz_src = ((l & 7) ^ ((l >> 3) & 7)) << 3;

  auto ldsH = [&](int buf, int half) { return lds + (buf * 4 + half) * 8192; };
  auto stageA = [&](int kt, int buf) {
#pragma unroll
    for (int h = 0; h < 2; h++) {
      u16* lb = ldsH(buf, h);
      const int rb = h * 128;
      gload_lds16(Ag + (size_t)(rb + w * 8 + lrow8) * K + kt * 64 + swz_src,
                  lb + w * 512);
      gload_lds16(Ag + (size_t)(rb + 64 + w * 8 + lrow8) * K + kt * 64 + swz_src,
                  lb + (8 + w) * 512);
    }
  };
  auto stageB = [&](int kt, int buf) {
#pragma unroll
    for (int h = 0; h < 2; h++) {
      u16* lb = ldsH(buf, 2 + h);
      const int rb = h * 128;
      gload_lds16(Bg + (size_t)(rb + w * 8 + lrow8) * K + kt * 64 + swz_src,
                  lb + w * 512);
      gload_lds16(Bg + (size_t)(rb + 64 + w * 8 + lrow8) * K + kt * 64 + swz_src,
                  lb + (8 + w) * 512);
    }
  };

  stageA(0, 0);
  stageB(0, 0);

  const int nkt = K >> 6;
  const int brb = (wc & 1) * 64;
  for (int kt = 0; kt < nkt; ++kt) {
    const int cur = kt & 1, nx = cur ^ 1;
    if (kt + 1 < nkt) {
      stageA(kt + 1, nx);
      asm volatile("s_waitcnt vmcnt(4)" ::: "memory");
    } else {
      asm volatile("s_waitcnt vmcnt(0)" ::: "memory");
    }
    __builtin_amdgcn_s_barrier();
    __builtin_amdgcn_sched_barrier(0);
    const u16* Ah = ldsH(cur, wr);
    const u16* Bh = ldsH(cur, 2 + (wc >> 1));
#pragma unroll
    for (int kk = 0; kk < 2; kk++) {
      s16x8 bfr[4];
#pragma unroll
      for (int nf = 0; nf < 4; nf++)
        bfr[nf] = *(const s16x8*)(Bh + (brb + nf * 16 + lr) * 64 +
                                  (((kk * 4 + lg) ^ r7) << 3));
#pragma unroll
      for (int mh = 0; mh < 2; mh++) {
        s16x8 afr[4];
#pragma unroll
        for (int i = 0; i < 4; i++)
          afr[i] = *(const s16x8*)(Ah + ((mh * 4 + i) * 16 + lr) * 64 +
                                   (((kk * 4 + lg) ^ r7) << 3));
        __builtin_amdgcn_s_setprio(1);
#pragma unroll
        for (int i = 0; i < 4; i++)
#pragma unroll
          for (int nf = 0; nf < 4; nf++)
            acc[mh * 4 + i][nf] = __builtin_amdgcn_mfma_f32_16x16x32_bf16(
                afr[i], bfr[nf], acc[mh * 4 + i][nf], 0, 0, 0);
        __builtin_amdgcn_s_setprio(0);
      }
      if (kk == 0 && kt + 1 < nkt) stageB(kt + 1, nx);
    }
    __builtin_amdgcn_sched_barrier(0);
    __builtin_amdgcn_s_barrier();
  }

  // epilogue: wave tile = 128 rows x 64 cols, region routing (wave-uniform)
  const int lg4 = lg * 4;
  const int wrb = wr * 128;
  u16* Sgw = lds + w * 2176;  // wave-private [32][68] stage
  const int colw = bcol + wc * 64;
  const int region = colw >> 10;
  const int ck0 = colw & 1023;  // 64-aligned in-region col base
  float bn[4];
  {
    const float* bb = region == 0 ? bq : region == 1 ? bk : bv;
#pragma unroll
    for (int nf = 0; nf < 4; nf++) bn[nf] = bb[ck0 + nf * 16 + lr];
  }
  const int ch = l & 7;
  if (region <= 1) {
#pragma unroll
    for (int hh = 0; hh < 4; hh++) {  // 32-row groups over 128 rows
#pragma unroll
      for (int mm = 0; mm < 2; mm++) {
        const int mf = hh * 2 + mm;
#pragma unroll
        for (int nf = 0; nf < 4; nf++)
#pragma unroll
          for (int r = 0; r < 4; r++) {
            float vv = acc[mf][nf][r] + bn[nf];
            if (region == 0) vv *= 0.125f;
            Sgw[(mm * 16 + lg4 + r) * 68 + nf * 16 + lr] = f2bf(vv);
          }
      }
#pragma unroll
      for (int i = 0; i < 4; i++) {
        const int rr = i * 8 + (l >> 3);
        u16x4 a0 = *(const u16x4*)(Sgw + rr * 68 + ch * 8);
        u16x4 a1 = *(const u16x4*)(Sgw + rr * 68 + ch * 8 + 4);
        s16x8 v8;
#pragma unroll
        for (int j = 0; j < 4; j++) { v8[j] = (short)a0[j]; v8[4 + j] = (short)a1[j]; }
        const int tok = brow + wrb + hh * 32 + rr;
        u16* dstp = (region == 0) ? qbf : kbf;
        *(s16x8*)(dstp + (size_t)tok * 1024 + ck0 + ch * 8) = v8;
      }
    }
  } else {
    // V transposed (PLAIN): 2x2 passes (d-half x tok-half) through Sg stage
    const int hcol = ck0 >> 6;  // head index
#pragma unroll
    for (int dh = 0; dh < 2; dh++)
#pragma unroll
      for (int th = 0; th < 2; th++) {
#pragma unroll
        for (int nn = 0; nn < 2; nn++) {
          const int nf = dh * 2 + nn;
#pragma unroll
          for (int mi = 0; mi < 4; mi++) {
            const int mf = th * 4 + mi;
#pragma unroll
            for (int r = 0; r < 4; r++)
              Sgw[(nn * 16 + lr) * 68 + mi * 16 + lg4 + r] =
                  f2bf(acc[mf][nf][r] + bn[nf]);
          }
        }
#pragma unroll
        for (int i = 0; i < 4; i++) {
          const int rr = i * 8 + (l >> 3);
          u16x4 a0 = *(const u16x4*)(Sgw + rr * 68 + ch * 8);
          u16x4 a1 = *(const u16x4*)(Sgw + rr * 68 + ch * 8 + 4);
          s16x8 v8;
#pragma unroll
          for (int j = 0; j < 4; j++) { v8[j] = (short)a0[j]; v8[4 + j] = (short)a1[j]; }
          const int d = dh * 32 + rr;
          const int tokb = brow + wrb + th * 64 + ch * 8;
          const int b = tokb >> 11, s64b = tokb & 2047;
          *(s16x8*)(vtbf + ((size_t)((b << 4) + hcol) * 64 + d) * 2048 + s64b) =
              v8;
        }
      }
  }
}

// ---------------- causal flash attention (BARRIER-FREE, L2-direct K/V) ------
// R21 hypothesis test (catalog common-mistake #7): K/V per (b,h) = 256KB each
// -> L1/L2-fit; LDS staging (and its barriers/vmcnt/dbuf) was pure overhead.
// Each wave reads K and V^T frags DIRECTLY from global as b128 lane loads;
// 4 waves/block read the same tile data -> L1 absorbs duplication. ZERO
// barriers: waves fully independent, 16 waves/CU TLP hides the serial
// softmax chain. P exchange via wave-private LDS (2KB/wave), swizzle decoded
// to plain chunks (pos = lg^key -> content lg, matching plain global A-frags;
// k-permutation consistent on both MFMA operands). Blocks: 256 thr (4 waves),
// grid 1024 = 4/CU, balanced-mod-256 qt map (66 tiles/CU flat, R9-proven).
__global__ __launch_bounds__(256, 4) void k_attn(const u16* __restrict__ q,
                                                 const u16* __restrict__ kk,
                                                 const u16* __restrict__ vt,
                                                 u16* __restrict__ o) {
  __shared__ alignas(16) u16 Ps[4][16 * 64];  // wave-private P (8KB total)
  const int t = threadIdx.x;
  const int w = t >> 6;
  const int l = t & 63;
  const int idx = blockIdx.x;
  const int bh = idx & 31;  // head-batch in LOW bits
  const int p = idx >> 5;   // 0..31
  const int pm = p >> 3, pj = p & 7;
  const int qt = pm * 8 + ((pm & 1) ? (7 - pj) : pj);  // balanced-mod-256 map
  const int nt = qt + 1;
  const int b = bh >> 4, h = bh & 15;
  const u16* qb = q + (size_t)b * SEQ * DMODEL + h * HDIM;
  const u16* kb = kk + (size_t)b * SEQ * DMODEL + h * HDIM;
  const u16* vb = vt + (size_t)(bh * 64) * SEQ;
  const int lr = l & 15, lg = l >> 4;
  const int key = lr & 7;
  const f32x4 Z4 = {0.f, 0.f, 0.f, 0.f};
  u16* PsW = &Ps[w][0];

  // Q frags direct from global (lane owns q-row qrow)
  const int qrow = qt * 64 + w * 16 + lr;
  const u16* qrp = qb + (size_t)qrow * DMODEL + lg * 8;
  s16x8 bq0 = *(const s16x8*)(qrp);
  s16x8 bq1 = *(const s16x8*)(qrp + 32);

  float m_l = -3.0e38f, l_l = 0.f;
  f32x4 oacc[4];
#pragma unroll
  for (int m = 0; m < 4; m++) oacc[m] = Z4;

  for (int jt = 0; jt < nt; jt++) {
    // S^T = K @ Q^T : K-frags direct from global (plain chunks)
    f32x4 sacc[4];
#pragma unroll
    for (int m = 0; m < 4; m++) sacc[m] = Z4;
#pragma unroll
    for (int m = 0; m < 4; m++) {
      const u16* kr = kb + (size_t)(jt * 64 + m * 16 + lr) * DMODEL + lg * 8;
      s16x8 ak0 = *(const s16x8*)(kr);
      s16x8 ak1 = *(const s16x8*)(kr + 32);
      sacc[m] = __builtin_amdgcn_mfma_f32_16x16x32_bf16(ak0, bq0, sacc[m], 0, 0, 0);
      sacc[m] = __builtin_amdgcn_mfma_f32_16x16x32_bf16(ak1, bq1, sacc[m], 0, 0, 0);
    }
    // mask on diagonal tile
    if (jt == qt) {
      const int q_rel = w * 16 + lr;
#pragma unroll
      for (int m = 0; m < 4; m++)
#pragma unroll
        for (int r = 0; r < 4; r++)
          if (m * 16 + lg * 4 + r > q_rel) sacc[m][r] = -3.0e38f;
    }
    // tree max + cross-lane + defer-max (T13)
    float mx[4];
#pragma unroll
    for (int m = 0; m < 4; m++)
      mx[m] = fmaxf(fmaxf(sacc[m][0], sacc[m][1]),
                    fmaxf(sacc[m][2], sacc[m][3]));
    float pmax = fmaxf(fmaxf(mx[0], mx[1]), fmaxf(mx[2], mx[3]));
    pmax = fmaxf(pmax, __shfl_xor(pmax, 16, 64));
    pmax = fmaxf(pmax, __shfl_xor(pmax, 32, 64));
    if (!__all(pmax - m_l <= 8.0f)) {
      const float m_new = fmaxf(m_l, pmax);
      const float alpha = __expf(m_l - m_new);
      m_l = m_new;
      l_l *= alpha;
#pragma unroll
      for (int m = 0; m < 4; m++)
#pragma unroll
        for (int r = 0; r < 4; r++) oacc[m][r] *= alpha;
    }
    float p_[4][4], sm[4];
#pragma unroll
    for (int m = 0; m < 4; m++) {
#pragma unroll
      for (int r = 0; r < 4; r++) p_[m][r] = __expf(sacc[m][r] - m_l);
      sm[m] = (p_[m][0] + p_[m][1]) + (p_[m][2] + p_[m][3]);
    }
    float rs = (sm[0] + sm[1]) + (sm[2] + sm[3]);
    rs += __shfl_xor(rs, 16, 64);
    rs += __shfl_xor(rs, 32, 64);
    l_l += rs;
    // P pack -> wave-private LDS (chunk-swizzled by q-row for bank spread)
#pragma unroll
    for (int m = 0; m < 4; m++)
#pragma unroll
      for (int pr = 0; pr < 2; pr++) {
        const uint32_t pk = pk_bf16(p_[m][2 * pr], p_[m][2 * pr + 1]);
        const int kv0 = m * 16 + lg * 4 + 2 * pr;
        ((uint32_t*)PsW)[lr * 32 + (((kv0 >> 3) ^ key) << 2) +
                         ((kv0 >> 1) & 3)] = pk;
      }
    __builtin_amdgcn_sched_barrier(0);
    // PV: P B-frags swizzle-decoded (content = plain chunk lg / 4+lg);
    //     V^T A-frags direct from global (plain chunks)
    s16x8 bp0 = *(const s16x8*)(PsW + lr * 64 + ((lg ^ key) << 3));
    s16x8 bp1 = *(const s16x8*)(PsW + lr * 64 + (((4 | lg) ^ key) << 3));
#pragma unroll
    for (int m = 0; m < 4; m++) {
      const u16* vr = vb + (size_t)(m * 16 + lr) * SEQ + jt * 64 + lg * 8;
      s16x8 av0 = *(const s16x8*)(vr);
      s16x8 av1 = *(const s16x8*)(vr + 32);
      oacc[m] = __builtin_amdgcn_mfma_f32_16x16x32_bf16(av0, bp0, oacc[m], 0, 0, 0);
      oacc[m] = __builtin_amdgcn_mfma_f32_16x16x32_bf16(av1, bp1, oacc[m], 0, 0, 0);
    }
    __builtin_amdgcn_sched_barrier(0);
  }
  // epilogue: lane holds O[q=qrow][d=m*16+lg*4+r]
  const float rl = 1.0f / l_l;
  u16* orow = o + (size_t)(b * SEQ + qrow) * DMODEL + h * HDIM;
#pragma unroll
  for (int m = 0; m < 4; m++)
#pragma unroll
    for (int pr = 0; pr < 2; pr++) {
      const uint32_t pk =
          pk_bf16(oacc[m][2 * pr] * rl, oacc[m][2 * pr + 1] * rl);
      *(uint32_t*)(orow + m * 16 + lg * 4 + 2 * pr) = pk;
    }
}

// ---------------- fused residual add + LayerNorm ----------------
// vv = X + Y (+ Y1 if non-null). XBF: X input is bf16 (the residual path
// reuses the bf16 xbf that the FFN consumed -- consistent semantics).
template <int XBF>
__global__ __launch_bounds__(256) void k_add_ln(const void* __restrict__ Xv,
                                                const float* __restrict__ Y,
                                                const float* __restrict__ Y1,
                                                const float* __restrict__ w,
                                                const float* __restrict__ bias,
                                                float* __restrict__ of32,
                                                u16* __restrict__ obf) {
  __shared__ float sred[4];
  const int t = threadIdx.x;
  const size_t row = blockIdx.x;
  f32x4 xv;
  if (XBF) {
    u16x4 xu = ((const u16x4*)((const u16*)Xv + row * DMODEL))[t];
    for (int i = 0; i < 4; i++)
      xv[i] = __uint_as_float((uint32_t)xu[i] << 16);
  } else {
    xv = ((const f32x4*)((const float*)Xv + row * DMODEL))[t];
  }
  f32x4 yv = ((const f32x4*)(Y + row * DMODEL))[t];
  f32x4 vv;
  for (int i = 0; i < 4; i++) vv[i] = xv[i] + yv[i];
  if (Y1) {
    f32x4 y1 = ((const f32x4*)(Y1 + row * DMODEL))[t];
    for (int i = 0; i < 4; i++) vv[i] += y1[i];
  }
  float s = vv[0] + vv[1] + vv[2] + vv[3];
  for (int off = 32; off >= 1; off >>= 1) s += __shfl_xor(s, off, 64);
  if ((t & 63) == 0) sred[t >> 6] = s;
  __syncthreads();
  s = sred[0] + sred[1] + sred[2] + sred[3];
  const float mean = s * (1.0f / DMODEL);
  f32x4 dv;
  for (int i = 0; i < 4; i++) dv[i] = vv[i] - mean;
  float ss = dv[0] * dv[0] + dv[1] * dv[1] + dv[2] * dv[2] + dv[3] * dv[3];
  __syncthreads();
  for (int off = 32; off >= 1; off >>= 1) ss += __shfl_xor(ss, off, 64);
  if ((t & 63) == 0) sred[t >> 6] = ss;
  __syncthreads();
  ss = sred[0] + sred[1] + sred[2] + sred[3];
  const float rs = rsqrtf(ss * (1.0f / DMODEL) + 1e-5f);
  f32x4 wv = ((const f32x4*)w)[t];
  f32x4 bv = ((const f32x4*)bias)[t];
  f32x4 ov;
  for (int i = 0; i < 4; i++) ov[i] = dv[i] * rs * wv[i] + bv[i];
  if (of32) ((f32x4*)(of32 + row * DMODEL))[t] = ov;
  if (obf) {
    u16x4 ob;
    for (int i = 0; i < 4; i++) ob[i] = f2bf(ov[i]);
    ((u16x4*)(obf + row * DMODEL))[t] = ob;
  }
}

extern "C" void kernel_launch(void* const* d_in, const int* in_sizes, int n_in,
                              void* d_out, int out_size, void* d_ws,
                              size_t ws_size, hipStream_t stream) {
  const float* X = (const float*)d_in[0];
  const float* Wq = (const float*)d_in[1];
  const float* bq = (const float*)d_in[2];
  const float* Wk = (const float*)d_in[3];
  const float* bk = (const float*)d_in[4];
  const float* Wv = (const float*)d_in[5];
  const float* bvp = (const float*)d_in[6];
  const float* Wo = (const float*)d_in[7];
  const float* bo = (const float*)d_in[8];
  const float* ln1w = (const float*)d_in[9];
  const float* ln1b = (const float*)d_in[10];
  const float* Wup = (const float*)d_in[11];
  const float* bup = (const float*)d_in[12];
  const float* Wdown = (const float*)d_in[13];
  const float* bdown = (const float*)d_in[14];
  const float* ln2w = (const float*)d_in[15];
  const float* ln2b = (const float*)d_in[16];

  char* ws = (char*)d_ws;
  const size_t MB = 1024 * 1024;
  u16* Xbf = (u16*)(ws + 0);          // 8MB, dead after QKV GEMM
  u16* qbf = (u16*)(ws + 8 * MB);     // 8MB (pre-scaled by 0.125)
  u16* kbf = (u16*)(ws + 16 * MB);    // 8MB (plain)
  u16* vtbf = (u16*)(ws + 24 * MB);   // 8MB (plain transposed)
  u16* wqkv = (u16*)(ws + 32 * MB);   // 6MB concat [Wq;Wk;Wv] bf16
  u16* wo = (u16*)(ws + 38 * MB);     // 2MB
  u16* attnb = (u16*)(ws + 40 * MB);  // 8MB
  float* Ybuf = (float*)(ws + 48 * MB);  // 16MB (split-K partial z=0)
  u16* wbig = (u16*)(ws + 64 * MB);      // 8MB (Wup bf16)
  u16* wdownbf = (u16*)(ws + 72 * MB);   // 8MB (Wdown bf16)
  u16* xbf = (u16*)(ws + 80 * MB);       // 8MB (LN1 out, also LN2 residual)
  u16* upbf = (u16*)(ws + 0);            // 32MB reuse (0..32MB)
  float* Ypart = (float*)d_out;  // 16MB f32: free scratch until final LN

  const dim3 blk(256);
  // ALL converts in one dispatch: X + Wq/Wk/Wv + Wo + Wup + Wdown
  k_f2bf_all<<<dim3(128, 16), blk, 0, stream>>>(
      X, Wq, Wk, Wv, Wo, Wup, Wdown, Xbf, wqkv, wo, wbig, wdownbf);

  // QKV: 256x256 tile (MH=2) -> grid (12,16) = 192 blocks, single round
  k_gemm256_qkv<<<dim3(12, 16), dim3(512), 0, stream>>>(
      Xbf, wqkv, bq, bk, bvp, qbf, kbf, vtbf, MTOK, 3 * DMODEL, DMODEL);
  // attn: barrier-free L2-direct, 1024 blocks of 256 threads (4/CU balanced)
  k_attn<<<32 * NBATCH * NHEAD, blk, 0, stream>>>(qbf, kbf, vtbf, attnb);
  // Wo-proj: 256-col tile, BM=128, split-K=2 -> grid (4,32,2) = 256 blocks
  k_gemm256<0, 2, 1><<<dim3(4, 32, 2), dim3(512), 0, stream>>>(
      attnb, wo, bo, Ybuf, Ypart, MTOK, DMODEL, DMODEL);
  k_add_ln<0><<<MTOK, blk, 0, stream>>>(X, Ybuf, Ypart, ln1w, ln1b,
                                        (float*)nullptr, xbf);

  // up-proj: 256x256 tile -> grid (16,16) = 256 blocks, bf16+relu out
  k_gemm256<2, 1, 2><<<dim3(16, 16), dim3(512), 0, stream>>>(
      xbf, wbig, bup, upbf, nullptr, MTOK, 4 * DMODEL, DMODEL);
  // down-proj: 256-col tile, BM=128, split-K=2 -> grid (4,32,2)
  k_gemm256<0, 2, 1><<<dim3(4, 32, 2), dim3(512), 0, stream>>>(
      upbf, wdownbf, bdown, Ybuf, Ypart, MTOK, DMODEL, 4 * DMODEL);
  k_add_ln<1><<<MTOK, blk, 0, stream>>>(xbf, Ybuf, Ypart, ln2w, ln2b,
                                        (float*)d_out, (u16*)nullptr);
}

// Round 23
// 194.663 us; speedup vs baseline: 1.4287x; 1.4287x over previous
//
#include <hip/hip_runtime.h>
#include <stdint.h>

#define DMODEL 1024
#define NHEAD 16
#define HDIM 64
#define SEQ 2048
#define NBATCH 2
#define MTOK 4096  // NBATCH*SEQ

typedef float f32x4 __attribute__((ext_vector_type(4)));
typedef short s16x8 __attribute__((ext_vector_type(8)));
typedef unsigned short u16;
typedef u16 u16x4 __attribute__((ext_vector_type(4)));

typedef __attribute__((address_space(1))) const void* as1_cvp;
typedef __attribute__((address_space(3))) void* as3_vp;

__device__ inline u16 f2bf(float f) {
  uint32_t u = __float_as_uint(f);
  u = u + 0x7FFFu + ((u >> 16) & 1u);
  return (u16)(u >> 16);
}

// T12 primitive: single-instr packed f32x2 -> bf16x2 (RNE), no builtin on
// gfx950 (m240) -> inline asm.
__device__ inline uint32_t pk_bf16(float lo, float hi) {
  uint32_t r;
  asm("v_cvt_pk_bf16_f32 %0, %1, %2" : "=v"(r) : "v"(lo), "v"(hi));
  return r;
}

__device__ inline void gload_lds16(const void* g, void* l) {
  __builtin_amdgcn_global_load_lds((as1_cvp)g, (as3_vp)l, 16, 0, 0);
}

// ---------------- ALL fp32 -> bf16 converts in ONE dispatch ----------------
// 16 chunks of 1M elements: X(4) | Wq Wk Wv(3) | Wo(1) | Wup(4) | Wdown(4).
__global__ __launch_bounds__(256) void k_f2bf_all(
    const float* __restrict__ X, const float* __restrict__ Wq,
    const float* __restrict__ Wk, const float* __restrict__ Wv,
    const float* __restrict__ Wo, const float* __restrict__ Wup,
    const float* __restrict__ Wdown, u16* __restrict__ dX,
    u16* __restrict__ dqkv, u16* __restrict__ dwo, u16* __restrict__ dup,
    u16* __restrict__ ddown) {
  const int c = blockIdx.y;  // 0..15
  const size_t CH = 1024 * 1024;
  const float* src;
  u16* dst;
  if (c < 4) {
    src = X + c * CH; dst = dX + c * CH;
  } else if (c < 7) {
    src = (c == 4 ? Wq : c == 5 ? Wk : Wv) ; dst = dqkv + (size_t)(c - 4) * CH;
  } else if (c == 7) {
    src = Wo; dst = dwo;
  } else if (c < 12) {
    src = Wup + (size_t)(c - 8) * CH; dst = dup + (size_t)(c - 8) * CH;
  } else {
    src = Wdown + (size_t)(c - 12) * CH; dst = ddown + (size_t)(c - 12) * CH;
  }
  const int n4 = (int)(CH / 4);
  int i = blockIdx.x * 256 + threadIdx.x;
  const int stride = gridDim.x * 256;
  for (; i < n4; i += stride) {
    f32x4 v = ((const f32x4*)src)[i];
    u16x4 o;
    o[0] = f2bf(v[0]); o[1] = f2bf(v[1]); o[2] = f2bf(v[2]); o[3] = f2bf(v[3]);
    ((u16x4*)dst)[i] = o;
  }
}

// ============ 256-col-tile 8-wave GEMM: C[M,N] = A @ B^T + bias ============
// BN=256, BM = MH*128, BK=64, 512 threads = 8 waves (2M x 4N). T2 swizzle
// (linear LDS dest + pre-permuted global source chunk, reads XOR chunk^(row&7)
// -> conflict-free b128), T4 staggered counted vmcnt (A at iter top, B mid),
// T5 setprio. Proven R12: -34 us on the three projection/FFN GEMMs.
// MODE: 0 = f32 split-K partial out (kz=0 -> Cv+bias, kz=1 -> Cv1),
//       2 = bf16+relu out via Sg LDS stage (overlaid on staging LDS).
template <int MODE, int KSPL, int MH>
__global__ __launch_bounds__(512, 2) void k_gemm256(
    const u16* __restrict__ A, const u16* __restrict__ B,
    const float* __restrict__ bias, void* __restrict__ Cv,
    void* __restrict__ Cv1, int M, int N, int K) {
  constexpr int HALVES = MH + 2;  // MH A-halves + 2 B-halves, 16KB each
  __shared__ alignas(16) u16 lds[2 * HALVES * 8192];
  const int t = threadIdx.x;
  const int w = t >> 6;        // 0..7
  const int l = t & 63;
  const int wr = w >> 2;       // 0..1 (M half)
  const int wc = w & 3;        // 0..3 (N quarter)
  const int lr = l & 15, lg = l >> 4;
  const int r7 = lr & 7;
  const int lrow8 = l >> 3;

  // bijective XCD swizzle on (bx,by); nwg % 8 == 0 for all our grids
  const int gx = gridDim.x;
  int lin = blockIdx.y * gx + blockIdx.x;
  const int nwg = gx * gridDim.y;
  lin = (lin & 7) * (nwg >> 3) + (lin >> 3);
  const int bx = lin % gx, by = lin / gx;
  const int kz = KSPL > 1 ? blockIdx.z : 0;
  const int Kc = K / KSPL, kbeg = kz * Kc;
  const int brow = by * (MH * 128), bcol = bx * 256;

  constexpr int MF = MH * 4;  // m-frags per wave
  const f32x4 Z4 = {0.f, 0.f, 0.f, 0.f};
  f32x4 acc[MF][4];
#pragma unroll
  for (int m = 0; m < MF; m++)
#pragma unroll
    for (int n = 0; n < 4; n++) acc[m][n] = Z4;

  const u16* Ag = A + (size_t)brow * K + kbeg;
  const u16* Bg = B + (size_t)bcol * K + kbeg;
  const int swz_src = ((l & 7) ^ ((l >> 3) & 7)) << 3;  // element offset

  auto ldsH = [&](int buf, int half) { return lds + (buf * HALVES + half) * 8192; };
  auto stageA = [&](int kt, int buf) {
#pragma unroll
    for (int h = 0; h < MH; h++) {
      u16* lb = ldsH(buf, h);
      const int rb = h * 128;
      gload_lds16(Ag + (size_t)(rb + w * 8 + lrow8) * K + kt * 64 + swz_src,
                  lb + w * 512);
      gload_lds16(Ag + (size_t)(rb + 64 + w * 8 + lrow8) * K + kt * 64 + swz_src,
                  lb + (8 + w) * 512);
    }
  };
  auto stageB = [&](int kt, int buf) {
#pragma unroll
    for (int h = 0; h < 2; h++) {
      u16* lb = ldsH(buf, MH + h);
      const int rb = h * 128;
      gload_lds16(Bg + (size_t)(rb + w * 8 + lrow8) * K + kt * 64 + swz_src,
                  lb + w * 512);
      gload_lds16(Bg + (size_t)(rb + 64 + w * 8 + lrow8) * K + kt * 64 + swz_src,
                  lb + (8 + w) * 512);
    }
  };

  stageA(0, 0);
  stageB(0, 0);

  const int nkt = Kc >> 6;
  const int arb = (MH == 2) ? 0 : wr * 64;  // A row base within half
  const int brb = (wc & 1) * 64;            // B row base within half
  for (int kt = 0; kt < nkt; ++kt) {
    const int cur = kt & 1, nx = cur ^ 1;
    if (kt + 1 < nkt) {
      stageA(kt + 1, nx);
      if (MH == 2)
        asm volatile("s_waitcnt vmcnt(4)" ::: "memory");
      else
        asm volatile("s_waitcnt vmcnt(2)" ::: "memory");
    } else {
      asm volatile("s_waitcnt vmcnt(0)" ::: "memory");
    }
    __builtin_amdgcn_s_barrier();
    __builtin_amdgcn_sched_barrier(0);
    const u16* Ah = ldsH(cur, (MH == 2) ? wr : 0);
    const u16* Bh = ldsH(cur, MH + (wc >> 1));
#pragma unroll
    for (int kk = 0; kk < 2; kk++) {
      s16x8 bfr[4];
#pragma unroll
      for (int nf = 0; nf < 4; nf++)
        bfr[nf] = *(const s16x8*)(Bh + (brb + nf * 16 + lr) * 64 +
                                  (((kk * 4 + lg) ^ r7) << 3));
#pragma unroll
      for (int mh = 0; mh < MH; mh++) {
        s16x8 afr[4];
#pragma unroll
        for (int i = 0; i < 4; i++)
          afr[i] = *(const s16x8*)(Ah + (arb + (mh * 4 + i) * 16 + lr) * 64 +
                                   (((kk * 4 + lg) ^ r7) << 3));
        __builtin_amdgcn_s_setprio(1);
#pragma unroll
        for (int i = 0; i < 4; i++)
#pragma unroll
          for (int nf = 0; nf < 4; nf++)
            acc[mh * 4 + i][nf] = __builtin_amdgcn_mfma_f32_16x16x32_bf16(
                afr[i], bfr[nf], acc[mh * 4 + i][nf], 0, 0, 0);
        __builtin_amdgcn_s_setprio(0);
      }
      if (kk == 0 && kt + 1 < nkt) stageB(kt + 1, nx);  // mid-iter issue
    }
    __builtin_amdgcn_sched_barrier(0);
    __builtin_amdgcn_s_barrier();
  }

  const int lg4 = lg * 4;
  const int wrb = wr * (MH == 2 ? 128 : 64);
  if (MODE == 0) {
    float* Co = (kz == 0) ? (float*)Cv : (float*)Cv1;
#pragma unroll
    for (int nf = 0; nf < 4; nf++) {
      const int col = bcol + wc * 64 + nf * 16 + lr;
      const float bvv = (kz == 0) ? bias[col] : 0.0f;
#pragma unroll
      for (int mf = 0; mf < MF; mf++) {
        const int row0 = brow + wrb + mf * 16 + lg4;
#pragma unroll
        for (int r = 0; r < 4; r++)
          Co[(size_t)(row0 + r) * N + col] = acc[mf][nf][r] + bvv;
      }
    }
  } else {
    u16* Sgw = lds + w * 2176;
    float bn[4];
#pragma unroll
    for (int nf = 0; nf < 4; nf++) bn[nf] = bias[bcol + wc * 64 + nf * 16 + lr];
    const int ch = l & 7;
#pragma unroll
    for (int hh = 0; hh < MH * 2; hh++) {  // 32-row groups
#pragma unroll
      for (int mm = 0; mm < 2; mm++) {
        const int mf = hh * 2 + mm;
#pragma unroll
        for (int nf = 0; nf < 4; nf++)
#pragma unroll
          for (int r = 0; r < 4; r++) {
            float vv = acc[mf][nf][r] + bn[nf];
            if (MODE == 2) vv = vv > 0.f ? vv : 0.f;
            Sgw[(mm * 16 + lg4 + r) * 68 + nf * 16 + lr] = f2bf(vv);
          }
      }
#pragma unroll
      for (int i = 0; i < 4; i++) {
        const int rr = i * 8 + (l >> 3);
        u16x4 a0 = *(const u16x4*)(Sgw + rr * 68 + ch * 8);
        u16x4 a1 = *(const u16x4*)(Sgw + rr * 68 + ch * 8 + 4);
        s16x8 v8;
#pragma unroll
        for (int j = 0; j < 4; j++) { v8[j] = (short)a0[j]; v8[4 + j] = (short)a1[j]; }
        *(s16x8*)((u16*)Cv + (size_t)(brow + wrb + hh * 32 + rr) * N +
                  (bcol + wc * 64 + ch * 8)) = v8;
      }
    }
  }
}

// ============ fused QKV GEMM: 256x256 tile (MH=2), grid (12,16)=192 ========
// One dispatch round (192 < 256 CUs), K-loop identical to k_gemm256<MH=2>.
// Wave tile = 128 rows x 64 cols -> wave-uniform region routing:
//  Q: qbf[tok][ck] plain, PRE-SCALED by 0.125 (bf16-exact)
//  K: kbf[tok][h*64 + dswz]  (d-chunk XOR tok&7)
//  V: vtbf[b][h][d][s_swz]   (s-chunk XOR d&7), transposed via 2x2 Sg passes
__global__ __launch_bounds__(512, 2) void k_gemm256_qkv(
    const u16* __restrict__ A, const u16* __restrict__ B,
    const float* __restrict__ bq, const float* __restrict__ bk,
    const float* __restrict__ bv, u16* __restrict__ qbf, u16* __restrict__ kbf,
    u16* __restrict__ vtbf, int M, int N, int K) {
  __shared__ alignas(16) u16 lds[2 * 4 * 8192];  // 128 KB
  const int t = threadIdx.x;
  const int w = t >> 6, l = t & 63;
  const int wr = w >> 2, wc = w & 3;
  const int lr = l & 15, lg = l >> 4;
  const int r7 = lr & 7;
  const int lrow8 = l >> 3;

  const int gx = gridDim.x;
  int lin = blockIdx.y * gx + blockIdx.x;
  const int nwg = gx * gridDim.y;
  lin = (lin & 7) * (nwg >> 3) + (lin >> 3);
  const int bx = lin % gx, by = lin / gx;
  const int brow = by * 256, bcol = bx * 256;

  const f32x4 Z4 = {0.f, 0.f, 0.f, 0.f};
  f32x4 acc[8][4];
#pragma unroll
  for (int m = 0; m < 8; m++)
#pragma unroll
    for (int n = 0; n < 4; n++) acc[m][n] = Z4;

  const u16* Ag = A + (size_t)brow * K;
  const u16* Bg = B + (size_t)bcol * K;
  const int swz_src = ((l & 7) ^ ((l >> 3) & 7)) << 3;

  auto ldsH = [&](int buf, int half) { return lds + (buf * 4 + half) * 8192; };
  auto stageA = [&](int kt, int buf) {
#pragma unroll
    for (int h = 0; h < 2; h++) {
      u16* lb = ldsH(buf, h);
      const int rb = h * 128;
      gload_lds16(Ag + (size_t)(rb + w * 8 + lrow8) * K + kt * 64 + swz_src,
                  lb + w * 512);
      gload_lds16(Ag + (size_t)(rb + 64 + w * 8 + lrow8) * K + kt * 64 + swz_src,
                  lb + (8 + w) * 512);
    }
  };
  auto stageB = [&](int kt, int buf) {
#pragma unroll
    for (int h = 0; h < 2; h++) {
      u16* lb = ldsH(buf, 2 + h);
      const int rb = h * 128;
      gload_lds16(Bg + (size_t)(rb + w * 8 + lrow8) * K + kt * 64 + swz_src,
                  lb + w * 512);
      gload_lds16(Bg + (size_t)(rb + 64 + w * 8 + lrow8) * K + kt * 64 + swz_src,
                  lb + (8 + w) * 512);
    }
  };

  stageA(0, 0);
  stageB(0, 0);

  const int nkt = K >> 6;
  const int brb = (wc & 1) * 64;
  for (int kt = 0; kt < nkt; ++kt) {
    const int cur = kt & 1, nx = cur ^ 1;
    if (kt + 1 < nkt) {
      stageA(kt + 1, nx);
      asm volatile("s_waitcnt vmcnt(4)" ::: "memory");
    } else {
      asm volatile("s_waitcnt vmcnt(0)" ::: "memory");
    }
    __builtin_amdgcn_s_barrier();
    __builtin_amdgcn_sched_barrier(0);
    const u16* Ah = ldsH(cur, wr);
    const u16* Bh = ldsH(cur, 2 + (wc >> 1));
#pragma unroll
    for (int kk = 0; kk < 2; kk++) {
      s16x8 bfr[4];
#pragma unroll
      for (int nf = 0; nf < 4; nf++)
        bfr[nf] = *(const s16x8*)(Bh + (brb + nf * 16 + lr) * 64 +
                                  (((kk * 4 + lg) ^ r7) << 3));
#pragma unroll
      for (int mh = 0; mh < 2; mh++) {
        s16x8 afr[4];
#pragma unroll
        for (int i = 0; i < 4; i++)
          afr[i] = *(const s16x8*)(Ah + ((mh * 4 + i) * 16 + lr) * 64 +
                                   (((kk * 4 + lg) ^ r7) << 3));
        __builtin_amdgcn_s_setprio(1);
#pragma unroll
        for (int i = 0; i < 4; i++)
#pragma unroll
          for (int nf = 0; nf < 4; nf++)
            acc[mh * 4 + i][nf] = __builtin_amdgcn_mfma_f32_16x16x32_bf16(
                afr[i], bfr[nf], acc[mh * 4 + i][nf], 0, 0, 0);
        __builtin_amdgcn_s_setprio(0);
      }
      if (kk == 0 && kt + 1 < nkt) stageB(kt + 1, nx);
    }
    __builtin_amdgcn_sched_barrier(0);
    __builtin_amdgcn_s_barrier();
  }

  // epilogue: wave tile = 128 rows x 64 cols, region routing (wave-uniform)
  const int lg4 = lg * 4;
  const int wrb = wr * 128;
  u16* Sgw = lds + w * 2176;  // wave-private [32][68] stage
  const int colw = bcol + wc * 64;
  const int region = colw >> 10;
  const int ck0 = colw & 1023;  // 64-aligned in-region col base
  float bn[4];
  {
    const float* bb = region == 0 ? bq : region == 1 ? bk : bv;
#pragma unroll
    for (int nf = 0; nf < 4; nf++) bn[nf] = bb[ck0 + nf * 16 + lr];
  }
  const int ch = l & 7;
  if (region <= 1) {
#pragma unroll
    for (int hh = 0; hh < 4; hh++) {  // 32-row groups over 128 rows
#pragma unroll
      for (int mm = 0; mm < 2; mm++) {
        const int mf = hh * 2 + mm;
#pragma unroll
        for (int nf = 0; nf < 4; nf++)
#pragma unroll
          for (int r = 0; r < 4; r++) {
            float vv = acc[mf][nf][r] + bn[nf];
            if (region == 0) vv *= 0.125f;
            Sgw[(mm * 16 + lg4 + r) * 68 + nf * 16 + lr] = f2bf(vv);
          }
      }
#pragma unroll
      for (int i = 0; i < 4; i++) {
        const int rr = i * 8 + (l >> 3);
        u16x4 a0 = *(const u16x4*)(Sgw + rr * 68 + ch * 8);
        u16x4 a1 = *(const u16x4*)(Sgw + rr * 68 + ch * 8 + 4);
        s16x8 v8;
#pragma unroll
        for (int j = 0; j < 4; j++) { v8[j] = (short)a0[j]; v8[4 + j] = (short)a1[j]; }
        const int tok = brow + wrb + hh * 32 + rr;
        if (region == 0)
          *(s16x8*)(qbf + (size_t)tok * 1024 + ck0 + ch * 8) = v8;
        else
          *(s16x8*)(kbf + (size_t)tok * 1024 + ck0 + (((ch ^ tok) & 7) << 3)) =
              v8;
      }
    }
  } else {
    // V transposed: 2x2 passes (d-half x tok-half) through the [32][68] stage
    const int hcol = ck0 >> 6;  // head index
#pragma unroll
    for (int dh = 0; dh < 2; dh++)
#pragma unroll
      for (int th = 0; th < 2; th++) {
#pragma unroll
        for (int nn = 0; nn < 2; nn++) {
          const int nf = dh * 2 + nn;
#pragma unroll
          for (int mi = 0; mi < 4; mi++) {
            const int mf = th * 4 + mi;
#pragma unroll
            for (int r = 0; r < 4; r++)
              Sgw[(nn * 16 + lr) * 68 + mi * 16 + lg4 + r] =
                  f2bf(acc[mf][nf][r] + bn[nf]);
          }
        }
#pragma unroll
        for (int i = 0; i < 4; i++) {
          const int rr = i * 8 + (l >> 3);
          u16x4 a0 = *(const u16x4*)(Sgw + rr * 68 + ch * 8);
          u16x4 a1 = *(const u16x4*)(Sgw + rr * 68 + ch * 8 + 4);
          s16x8 v8;
#pragma unroll
          for (int j = 0; j < 4; j++) { v8[j] = (short)a0[j]; v8[4 + j] = (short)a1[j]; }
          const int d = dh * 32 + rr;
          const int tokb = brow + wrb + th * 64 + ch * 8;
          const int b = tokb >> 11, s64b = tokb & 2047;
          const int ssb = (s64b & ~63) + ((((s64b >> 3) ^ d) & 7) << 3);
          *(s16x8*)(vtbf + ((size_t)((b << 4) + hcol) * 64 + d) * 2048 + ssb) =
              v8;
        }
      }
  }
}

// ---------------- causal flash attention (8-wave, QBLK=128, 2 blocks/CU) ----
// R22 post-mortem: L2-direct K/V reads regressed 3x (row-stride-2048B frag
// loads = 16 cache lines per instruction -> VMEM issue-rate bound; LDS
// staging converts strided gathers into coalesced line loads -- that's its
// real job here, not reuse). REVERTED to R21-current measured best (43.7us):
// ONE 128-row q-tile per block, grid 16x32 = 512 blocks; CU-pairing map
// qt = pp<8 ? pp : 23-pp (co-resident blocks sum to 17 rounds/CU flat).
// P buffer single-sub (pack/PV in two sub-phases). LDS 80KB = 2 blocks/CU.
__global__ __launch_bounds__(512, 2) void k_attn(const u16* __restrict__ q,
                                                 const u16* __restrict__ kk,
                                                 const u16* __restrict__ vt,
                                                 u16* __restrict__ o) {
  __shared__ alignas(16) u16 Ks[2][2][64 * 64];  // [dbuf][sub] 32KB
  __shared__ alignas(16) u16 Vs[2][2][64 * 64];  // 32KB
  __shared__ alignas(16) u16 Ps[8][16 * 64];     // [wave] 16KB; Q overlay
  const int t = threadIdx.x;
  const int w = t >> 6;   // 0..7
  const int l = t & 63;
  const int idx = blockIdx.x;
  const int bh = idx & 31;  // head-batch in LOW bits
  const int pp = idx >> 5;  // 0..15
  const int qt = (pp < 8) ? pp : (23 - pp);  // co-resident qt's sum to 15
  const int nt = qt + 1;                     // 128-wide kv tiles
  const int b = bh >> 4, h = bh & 15;
  const u16* qb = q + (size_t)b * SEQ * DMODEL + h * HDIM;
  const u16* kb = kk + (size_t)b * SEQ * DMODEL + h * HDIM;
  const u16* vb = vt + (size_t)((b * 16 + h) * 64) * SEQ;

  const int sr = t >> 3;        // 0..63 (full 64-row tile per call)
  const int sc = (t & 7) * 8;   // chunk col
  const int lr = l & 15, lg = l >> 4;
  const int key = lr & 7;
  const f32x4 Z4 = {0.f, 0.f, 0.f, 0.f};
  u16* PsW = &Ps[0][0] + w * 1024;  // wave-private [16][64]

  // stage Q: wave w's 16 rows into its OWN P region (2 calls, 8 rows each)
  gload_lds16(
      qb + (size_t)(qt * 128 + w * 16 + (l >> 3)) * DMODEL + (l & 7) * 8, PsW);
  gload_lds16(
      qb + (size_t)(qt * 128 + w * 16 + 8 + (l >> 3)) * DMODEL + (l & 7) * 8,
      PsW + 512);
  // stage K/V tile 0 (both subs): one call per 64x64 sub-tile
#pragma unroll
  for (int s = 0; s < 2; s++) {
    gload_lds16(kb + (size_t)(s * 64 + sr) * DMODEL + sc,
                &Ks[0][s][0] + w * 512);
    gload_lds16(vb + (size_t)sr * SEQ + s * 64 + sc, &Vs[0][s][0] + w * 512);
  }

  float m_l = -3.0e38f, l_l = 0.f;
  f32x4 oacc[4];
#pragma unroll
  for (int m = 0; m < 4; m++) oacc[m] = Z4;
  s16x8 bq0, bq1;

  for (int jt = 0; jt < nt; jt++) {
    const int cur = jt & 1;
    if (jt + 1 < nt) {
      const int nx = cur ^ 1;
      const int kvb = (jt + 1) * 128;
#pragma unroll
      for (int s = 0; s < 2; s++) {
        gload_lds16(kb + (size_t)(kvb + s * 64 + sr) * DMODEL + sc,
                    &Ks[nx][s][0] + w * 512);
        gload_lds16(vb + (size_t)sr * SEQ + kvb + s * 64 + sc,
                    &Vs[nx][s][0] + w * 512);
      }
      asm volatile("s_waitcnt vmcnt(4)" ::: "memory");
    } else {
      asm volatile("s_waitcnt vmcnt(0)" ::: "memory");
    }
    __builtin_amdgcn_s_barrier();
    __builtin_amdgcn_sched_barrier(0);
    if (jt == 0) {  // Q frags from this wave's P-region overlay
      bq0 = *(const s16x8*)(PsW + lr * 64 + lg * 8);
      bq1 = *(const s16x8*)(PsW + lr * 64 + 32 + lg * 8);
    }
    // S^T = K @ Q^T : 8 kv-frags over 2 subs (kv' = m*16 + lg*4 + r)
    f32x4 sacc[8];
#pragma unroll
    for (int m = 0; m < 8; m++) sacc[m] = Z4;
#pragma unroll
    for (int m = 0; m < 8; m++) {
      const u16* Kc = &Ks[cur][m >> 2][0];
      const int rr = (m & 3) * 16 + lr;
      s16x8 ak0 = *(const s16x8*)(Kc + rr * 64 + ((lg ^ key) << 3));
      s16x8 ak1 = *(const s16x8*)(Kc + rr * 64 + (((4 | lg) ^ key) << 3));
      sacc[m] = __builtin_amdgcn_mfma_f32_16x16x32_bf16(ak0, bq0, sacc[m], 0, 0, 0);
      sacc[m] = __builtin_amdgcn_mfma_f32_16x16x32_bf16(ak1, bq1, sacc[m], 0, 0, 0);
    }
    // mask on last tile: tile-local kv' > qg
    if (jt == nt - 1) {
      const int qg = w * 16 + lr;  // q - jt*128 when jt == qt
#pragma unroll
      for (int m = 0; m < 8; m++)
#pragma unroll
        for (int r = 0; r < 4; r++)
          if (m * 16 + lg * 4 + r > qg) sacc[m][r] = -3.0e38f;
    }
    // tree max over 8 frags + cross-lane, defer-max (T13)
    float mx[8];
#pragma unroll
    for (int m = 0; m < 8; m++)
      mx[m] = fmaxf(fmaxf(sacc[m][0], sacc[m][1]),
                    fmaxf(sacc[m][2], sacc[m][3]));
    float pmax = fmaxf(fmaxf(fmaxf(mx[0], mx[1]), fmaxf(mx[2], mx[3])),
                       fmaxf(fmaxf(mx[4], mx[5]), fmaxf(mx[6], mx[7])));
    pmax = fmaxf(pmax, __shfl_xor(pmax, 16, 64));
    pmax = fmaxf(pmax, __shfl_xor(pmax, 32, 64));
    if (!__all(pmax - m_l <= 8.0f)) {
      const float m_new = fmaxf(m_l, pmax);
      const float alpha = __expf(m_l - m_new);
      m_l = m_new;
      l_l *= alpha;
#pragma unroll
      for (int m = 0; m < 4; m++)
#pragma unroll
        for (int r = 0; r < 4; r++) oacc[m][r] *= alpha;
    }
    float p_[8][4], sm[8];
#pragma unroll
    for (int m = 0; m < 8; m++) {
#pragma unroll
      for (int r = 0; r < 4; r++) p_[m][r] = __expf(sacc[m][r] - m_l);
      sm[m] = (p_[m][0] + p_[m][1]) + (p_[m][2] + p_[m][3]);
    }
    float rs = ((sm[0] + sm[1]) + (sm[2] + sm[3])) +
               ((sm[4] + sm[5]) + (sm[6] + sm[7]));
    rs += __shfl_xor(rs, 16, 64);
    rs += __shfl_xor(rs, 32, 64);
    l_l += rs;
    // pack + PV in TWO sub-phases reusing the single wave-private P region
#pragma unroll
    for (int sub = 0; sub < 2; sub++) {
#pragma unroll
      for (int mi = 0; mi < 4; mi++) {
        const int m = sub * 4 + mi;
#pragma unroll
        for (int pr = 0; pr < 2; pr++) {
          const uint32_t pk = pk_bf16(p_[m][2 * pr], p_[m][2 * pr + 1]);
          const int kvp = mi * 16 + lg * 4 + 2 * pr;  // 0..63 within sub
          ((uint32_t*)PsW)[lr * 32 + (((kvp >> 3) ^ key) << 2) +
                           ((kvp >> 1) & 3)] = pk;
        }
      }
      __builtin_amdgcn_sched_barrier(0);
      const u16* Vc = &Vs[cur][sub][0];
#pragma unroll
      for (int ki = 0; ki < 2; ki++) {
        const int c = ki * 4 + lg;
        s16x8 bp = *(const s16x8*)(PsW + lr * 64 + ((c ^ key) << 3));
#pragma unroll
        for (int m = 0; m < 4; m++) {
          s16x8 av =
              *(const s16x8*)(Vc + (m * 16 + lr) * 64 + ((c ^ key) << 3));
          oacc[m] = __builtin_amdgcn_mfma_f32_16x16x32_bf16(av, bp, oacc[m], 0, 0, 0);
        }
      }
      __builtin_amdgcn_sched_barrier(0);
    }
    __builtin_amdgcn_s_barrier();
  }
  // epilogue: lane holds O[q=lr][d=m*16+lg*4+r]
  const float rl = 1.0f / l_l;
  const int tok = qt * 128 + w * 16 + lr;
  u16* orow = o + (size_t)(b * SEQ + tok) * DMODEL + h * HDIM;
#pragma unroll
  for (int m = 0; m < 4; m++)
#pragma unroll
    for (int pr = 0; pr < 2; pr++) {
      const uint32_t pk =
          pk_bf16(oacc[m][2 * pr] * rl, oacc[m][2 * pr + 1] * rl);
      *(uint32_t*)(orow + m * 16 + lg * 4 + 2 * pr) = pk;
    }
}

// ---------------- fused residual add + LayerNorm ----------------
// vv = X + Y (+ Y1 if non-null). XBF: X input is bf16 (the residual path
// reuses the bf16 xbf that the FFN consumed -- consistent semantics).
template <int XBF>
__global__ __launch_bounds__(256) void k_add_ln(const void* __restrict__ Xv,
                                                const float* __restrict__ Y,
                                                const float* __restrict__ Y1,
                                                const float* __restrict__ w,
                                                const float* __restrict__ bias,
                                                float* __restrict__ of32,
                                                u16* __restrict__ obf) {
  __shared__ float sred[4];
  const int t = threadIdx.x;
  const size_t row = blockIdx.x;
  f32x4 xv;
  if (XBF) {
    u16x4 xu = ((const u16x4*)((const u16*)Xv + row * DMODEL))[t];
    for (int i = 0; i < 4; i++)
      xv[i] = __uint_as_float((uint32_t)xu[i] << 16);
  } else {
    xv = ((const f32x4*)((const float*)Xv + row * DMODEL))[t];
  }
  f32x4 yv = ((const f32x4*)(Y + row * DMODEL))[t];
  f32x4 vv;
  for (int i = 0; i < 4; i++) vv[i] = xv[i] + yv[i];
  if (Y1) {
    f32x4 y1 = ((const f32x4*)(Y1 + row * DMODEL))[t];
    for (int i = 0; i < 4; i++) vv[i] += y1[i];
  }
  float s = vv[0] + vv[1] + vv[2] + vv[3];
  for (int off = 32; off >= 1; off >>= 1) s += __shfl_xor(s, off, 64);
  if ((t & 63) == 0) sred[t >> 6] = s;
  __syncthreads();
  s = sred[0] + sred[1] + sred[2] + sred[3];
  const float mean = s * (1.0f / DMODEL);
  f32x4 dv;
  for (int i = 0; i < 4; i++) dv[i] = vv[i] - mean;
  float ss = dv[0] * dv[0] + dv[1] * dv[1] + dv[2] * dv[2] + dv[3] * dv[3];
  __syncthreads();
  for (int off = 32; off >= 1; off >>= 1) ss += __shfl_xor(ss, off, 64);
  if ((t & 63) == 0) sred[t >> 6] = ss;
  __syncthreads();
  ss = sred[0] + sred[1] + sred[2] + sred[3];
  const float rs = rsqrtf(ss * (1.0f / DMODEL) + 1e-5f);
  f32x4 wv = ((const f32x4*)w)[t];
  f32x4 bv = ((const f32x4*)bias)[t];
  f32x4 ov;
  for (int i = 0; i < 4; i++) ov[i] = dv[i] * rs * wv[i] + bv[i];
  if (of32) ((f32x4*)(of32 + row * DMODEL))[t] = ov;
  if (obf) {
    u16x4 ob;
    for (int i = 0; i < 4; i++) ob[i] = f2bf(ov[i]);
    ((u16x4*)(obf + row * DMODEL))[t] = ob;
  }
}

extern "C" void kernel_launch(void* const* d_in, const int* in_sizes, int n_in,
                              void* d_out, int out_size, void* d_ws,
                              size_t ws_size, hipStream_t stream) {
  const float* X = (const float*)d_in[0];
  const float* Wq = (const float*)d_in[1];
  const float* bq = (const float*)d_in[2];
  const float* Wk = (const float*)d_in[3];
  const float* bk = (const float*)d_in[4];
  const float* Wv = (const float*)d_in[5];
  const float* bvp = (const float*)d_in[6];
  const float* Wo = (const float*)d_in[7];
  const float* bo = (const float*)d_in[8];
  const float* ln1w = (const float*)d_in[9];
  const float* ln1b = (const float*)d_in[10];
  const float* Wup = (const float*)d_in[11];
  const float* bup = (const float*)d_in[12];
  const float* Wdown = (const float*)d_in[13];
  const float* bdown = (const float*)d_in[14];
  const float* ln2w = (const float*)d_in[15];
  const float* ln2b = (const float*)d_in[16];

  char* ws = (char*)d_ws;
  const size_t MB = 1024 * 1024;
  u16* Xbf = (u16*)(ws + 0);          // 8MB, dead after QKV GEMM
  u16* qbf = (u16*)(ws + 8 * MB);     // 8MB (pre-scaled by 0.125)
  u16* kbf = (u16*)(ws + 16 * MB);    // 8MB (d-swizzled)
  u16* vtbf = (u16*)(ws + 24 * MB);   // 8MB (transposed + s-swizzled)
  u16* wqkv = (u16*)(ws + 32 * MB);   // 6MB concat [Wq;Wk;Wv] bf16
  u16* wo = (u16*)(ws + 38 * MB);     // 2MB
  u16* attnb = (u16*)(ws + 40 * MB);  // 8MB
  float* Ybuf = (float*)(ws + 48 * MB);  // 16MB (split-K partial z=0)
  u16* wbig = (u16*)(ws + 64 * MB);      // 8MB (Wup bf16)
  u16* wdownbf = (u16*)(ws + 72 * MB);   // 8MB (Wdown bf16)
  u16* xbf = (u16*)(ws + 80 * MB);       // 8MB (LN1 out, also LN2 residual)
  u16* upbf = (u16*)(ws + 0);            // 32MB reuse (0..32MB)
  float* Ypart = (float*)d_out;  // 16MB f32: free scratch until final LN

  const dim3 blk(256);
  // ALL converts in one dispatch: X + Wq/Wk/Wv + Wo + Wup + Wdown
  k_f2bf_all<<<dim3(128, 16), blk, 0, stream>>>(
      X, Wq, Wk, Wv, Wo, Wup, Wdown, Xbf, wqkv, wo, wbig, wdownbf);

  // QKV: 256x256 tile (MH=2) -> grid (12,16) = 192 blocks, single round
  k_gemm256_qkv<<<dim3(12, 16), dim3(512), 0, stream>>>(
      Xbf, wqkv, bq, bk, bvp, qbf, kbf, vtbf, MTOK, 3 * DMODEL, DMODEL);
  // attn: single 128-row q-tile/block, CU-paired map -> 512 blocks, 2/CU
  k_attn<<<16 * NBATCH * NHEAD, dim3(512), 0, stream>>>(qbf, kbf, vtbf, attnb);
  // Wo-proj: 256-col tile, BM=128, split-K=2 -> grid (4,32,2) = 256 blocks
  k_gemm256<0, 2, 1><<<dim3(4, 32, 2), dim3(512), 0, stream>>>(
      attnb, wo, bo, Ybuf, Ypart, MTOK, DMODEL, DMODEL);
  k_add_ln<0><<<MTOK, blk, 0, stream>>>(X, Ybuf, Ypart, ln1w, ln1b,
                                        (float*)nullptr, xbf);

  // up-proj: 256x256 tile -> grid (16,16) = 256 blocks, bf16+relu out
  k_gemm256<2, 1, 2><<<dim3(16, 16), dim3(512), 0, stream>>>(
      xbf, wbig, bup, upbf, nullptr, MTOK, 4 * DMODEL, DMODEL);
  // down-proj: 256-col tile, BM=128, split-K=2 -> grid (4,32,2)
  k_gemm256<0, 2, 1><<<dim3(4, 32, 2), dim3(512), 0, stream>>>(
      upbf, wdownbf, bdown, Ybuf, Ypart, MTOK, DMODEL, 4 * DMODEL);
  k_add_ln<1><<<MTOK, blk, 0, stream>>>(xbf, Ybuf, Ypart, ln2w, ln2b,
                                        (float*)d_out, (u16*)nullptr);
}

// Round 24
// 194.253 us; speedup vs baseline: 1.4317x; 1.0021x over previous
//
#include <hip/hip_runtime.h>
#include <stdint.h>

#define DMODEL 1024
#define NHEAD 16
#define HDIM 64
#define SEQ 2048
#define NBATCH 2
#define MTOK 4096  // NBATCH*SEQ

typedef float f32x4 __attribute__((ext_vector_type(4)));
typedef short s16x8 __attribute__((ext_vector_type(8)));
typedef unsigned short u16;
typedef u16 u16x4 __attribute__((ext_vector_type(4)));

typedef __attribute__((address_space(1))) const void* as1_cvp;
typedef __attribute__((address_space(3))) void* as3_vp;

__device__ inline u16 f2bf(float f) {
  uint32_t u = __float_as_uint(f);
  u = u + 0x7FFFu + ((u >> 16) & 1u);
  return (u16)(u >> 16);
}

// T12 primitive: single-instr packed f32x2 -> bf16x2 (RNE), no builtin on
// gfx950 (m240) -> inline asm.
__device__ inline uint32_t pk_bf16(float lo, float hi) {
  uint32_t r;
  asm("v_cvt_pk_bf16_f32 %0, %1, %2" : "=v"(r) : "v"(lo), "v"(hi));
  return r;
}

__device__ inline void gload_lds16(const void* g, void* l) {
  __builtin_amdgcn_global_load_lds((as1_cvp)g, (as3_vp)l, 16, 0, 0);
}

// ---------------- ALL fp32 -> bf16 converts in ONE dispatch ----------------
// 16 chunks of 1M elements: X(4) | Wq Wk Wv(3) | Wo(1) | Wup(4) | Wdown(4).
__global__ __launch_bounds__(256) void k_f2bf_all(
    const float* __restrict__ X, const float* __restrict__ Wq,
    const float* __restrict__ Wk, const float* __restrict__ Wv,
    const float* __restrict__ Wo, const float* __restrict__ Wup,
    const float* __restrict__ Wdown, u16* __restrict__ dX,
    u16* __restrict__ dqkv, u16* __restrict__ dwo, u16* __restrict__ dup,
    u16* __restrict__ ddown) {
  const int c = blockIdx.y;  // 0..15
  const size_t CH = 1024 * 1024;
  const float* src;
  u16* dst;
  if (c < 4) {
    src = X + c * CH; dst = dX + c * CH;
  } else if (c < 7) {
    src = (c == 4 ? Wq : c == 5 ? Wk : Wv) ; dst = dqkv + (size_t)(c - 4) * CH;
  } else if (c == 7) {
    src = Wo; dst = dwo;
  } else if (c < 12) {
    src = Wup + (size_t)(c - 8) * CH; dst = dup + (size_t)(c - 8) * CH;
  } else {
    src = Wdown + (size_t)(c - 12) * CH; dst = ddown + (size_t)(c - 12) * CH;
  }
  const int n4 = (int)(CH / 4);
  int i = blockIdx.x * 256 + threadIdx.x;
  const int stride = gridDim.x * 256;
  for (; i < n4; i += stride) {
    f32x4 v = ((const f32x4*)src)[i];
    u16x4 o;
    o[0] = f2bf(v[0]); o[1] = f2bf(v[1]); o[2] = f2bf(v[2]); o[3] = f2bf(v[3]);
    ((u16x4*)dst)[i] = o;
  }
}

// ============ 256-col-tile 8-wave GEMM: C[M,N] = A @ B^T + bias ============
// BN=256, BM = MH*128, BK=64, 512 threads = 8 waves (2M x 4N). T2 swizzle
// (linear LDS dest + pre-permuted global source chunk, reads XOR chunk^(row&7)
// -> conflict-free b128), T4 staggered counted vmcnt (A at iter top, B mid),
// T5 setprio. Proven R12: -34 us on the three projection/FFN GEMMs.
// MODE: 0 = f32 split-K partial out (kz=0 -> Cv+bias, kz=1 -> Cv1),
//       2 = bf16+relu out via Sg LDS stage (overlaid on staging LDS).
template <int MODE, int KSPL, int MH>
__global__ __launch_bounds__(512, 2) void k_gemm256(
    const u16* __restrict__ A, const u16* __restrict__ B,
    const float* __restrict__ bias, void* __restrict__ Cv,
    void* __restrict__ Cv1, int M, int N, int K) {
  constexpr int HALVES = MH + 2;  // MH A-halves + 2 B-halves, 16KB each
  __shared__ alignas(16) u16 lds[2 * HALVES * 8192];
  const int t = threadIdx.x;
  const int w = t >> 6;        // 0..7
  const int l = t & 63;
  const int wr = w >> 2;       // 0..1 (M half)
  const int wc = w & 3;        // 0..3 (N quarter)
  const int lr = l & 15, lg = l >> 4;
  const int r7 = lr & 7;
  const int lrow8 = l >> 3;

  // bijective XCD swizzle on (bx,by); nwg % 8 == 0 for all our grids
  const int gx = gridDim.x;
  int lin = blockIdx.y * gx + blockIdx.x;
  const int nwg = gx * gridDim.y;
  lin = (lin & 7) * (nwg >> 3) + (lin >> 3);
  const int bx = lin % gx, by = lin / gx;
  const int kz = KSPL > 1 ? blockIdx.z : 0;
  const int Kc = K / KSPL, kbeg = kz * Kc;
  const int brow = by * (MH * 128), bcol = bx * 256;

  constexpr int MF = MH * 4;  // m-frags per wave
  const f32x4 Z4 = {0.f, 0.f, 0.f, 0.f};
  f32x4 acc[MF][4];
#pragma unroll
  for (int m = 0; m < MF; m++)
#pragma unroll
    for (int n = 0; n < 4; n++) acc[m][n] = Z4;

  const u16* Ag = A + (size_t)brow * K + kbeg;
  const u16* Bg = B + (size_t)bcol * K + kbeg;
  const int swz_src = ((l & 7) ^ ((l >> 3) & 7)) << 3;  // element offset

  auto ldsH = [&](int buf, int half) { return lds + (buf * HALVES + half) * 8192; };
  auto stageA = [&](int kt, int buf) {
#pragma unroll
    for (int h = 0; h < MH; h++) {
      u16* lb = ldsH(buf, h);
      const int rb = h * 128;
      gload_lds16(Ag + (size_t)(rb + w * 8 + lrow8) * K + kt * 64 + swz_src,
                  lb + w * 512);
      gload_lds16(Ag + (size_t)(rb + 64 + w * 8 + lrow8) * K + kt * 64 + swz_src,
                  lb + (8 + w) * 512);
    }
  };
  auto stageB = [&](int kt, int buf) {
#pragma unroll
    for (int h = 0; h < 2; h++) {
      u16* lb = ldsH(buf, MH + h);
      const int rb = h * 128;
      gload_lds16(Bg + (size_t)(rb + w * 8 + lrow8) * K + kt * 64 + swz_src,
                  lb + w * 512);
      gload_lds16(Bg + (size_t)(rb + 64 + w * 8 + lrow8) * K + kt * 64 + swz_src,
                  lb + (8 + w) * 512);
    }
  };

  stageA(0, 0);
  stageB(0, 0);

  const int nkt = Kc >> 6;
  const int arb = (MH == 2) ? 0 : wr * 64;  // A row base within half
  const int brb = (wc & 1) * 64;            // B row base within half
  for (int kt = 0; kt < nkt; ++kt) {
    const int cur = kt & 1, nx = cur ^ 1;
    if (kt + 1 < nkt) {
      stageA(kt + 1, nx);
      if (MH == 2)
        asm volatile("s_waitcnt vmcnt(4)" ::: "memory");
      else
        asm volatile("s_waitcnt vmcnt(2)" ::: "memory");
    } else {
      asm volatile("s_waitcnt vmcnt(0)" ::: "memory");
    }
    __builtin_amdgcn_s_barrier();
    __builtin_amdgcn_sched_barrier(0);
    const u16* Ah = ldsH(cur, (MH == 2) ? wr : 0);
    const u16* Bh = ldsH(cur, MH + (wc >> 1));
#pragma unroll
    for (int kk = 0; kk < 2; kk++) {
      s16x8 bfr[4];
#pragma unroll
      for (int nf = 0; nf < 4; nf++)
        bfr[nf] = *(const s16x8*)(Bh + (brb + nf * 16 + lr) * 64 +
                                  (((kk * 4 + lg) ^ r7) << 3));
#pragma unroll
      for (int mh = 0; mh < MH; mh++) {
        s16x8 afr[4];
#pragma unroll
        for (int i = 0; i < 4; i++)
          afr[i] = *(const s16x8*)(Ah + (arb + (mh * 4 + i) * 16 + lr) * 64 +
                                   (((kk * 4 + lg) ^ r7) << 3));
        __builtin_amdgcn_s_setprio(1);
#pragma unroll
        for (int i = 0; i < 4; i++)
#pragma unroll
          for (int nf = 0; nf < 4; nf++)
            acc[mh * 4 + i][nf] = __builtin_amdgcn_mfma_f32_16x16x32_bf16(
                afr[i], bfr[nf], acc[mh * 4 + i][nf], 0, 0, 0);
        __builtin_amdgcn_s_setprio(0);
      }
      if (kk == 0 && kt + 1 < nkt) stageB(kt + 1, nx);  // mid-iter issue
    }
    __builtin_amdgcn_sched_barrier(0);
    __builtin_amdgcn_s_barrier();
  }

  const int lg4 = lg * 4;
  const int wrb = wr * (MH == 2 ? 128 : 64);
  if (MODE == 0) {
    float* Co = (kz == 0) ? (float*)Cv : (float*)Cv1;
#pragma unroll
    for (int nf = 0; nf < 4; nf++) {
      const int col = bcol + wc * 64 + nf * 16 + lr;
      const float bvv = (kz == 0) ? bias[col] : 0.0f;
#pragma unroll
      for (int mf = 0; mf < MF; mf++) {
        const int row0 = brow + wrb + mf * 16 + lg4;
#pragma unroll
        for (int r = 0; r < 4; r++)
          Co[(size_t)(row0 + r) * N + col] = acc[mf][nf][r] + bvv;
      }
    }
  } else {
    u16* Sgw = lds + w * 2176;
    float bn[4];
#pragma unroll
    for (int nf = 0; nf < 4; nf++) bn[nf] = bias[bcol + wc * 64 + nf * 16 + lr];
    const int ch = l & 7;
#pragma unroll
    for (int hh = 0; hh < MH * 2; hh++) {  // 32-row groups
#pragma unroll
      for (int mm = 0; mm < 2; mm++) {
        const int mf = hh * 2 + mm;
#pragma unroll
        for (int nf = 0; nf < 4; nf++)
#pragma unroll
          for (int r = 0; r < 4; r++) {
            float vv = acc[mf][nf][r] + bn[nf];
            if (MODE == 2) vv = vv > 0.f ? vv : 0.f;
            Sgw[(mm * 16 + lg4 + r) * 68 + nf * 16 + lr] = f2bf(vv);
          }
      }
#pragma unroll
      for (int i = 0; i < 4; i++) {
        const int rr = i * 8 + (l >> 3);
        u16x4 a0 = *(const u16x4*)(Sgw + rr * 68 + ch * 8);
        u16x4 a1 = *(const u16x4*)(Sgw + rr * 68 + ch * 8 + 4);
        s16x8 v8;
#pragma unroll
        for (int j = 0; j < 4; j++) { v8[j] = (short)a0[j]; v8[4 + j] = (short)a1[j]; }
        *(s16x8*)((u16*)Cv + (size_t)(brow + wrb + hh * 32 + rr) * N +
                  (bcol + wc * 64 + ch * 8)) = v8;
      }
    }
  }
}

// ============ fused QKV GEMM: 256x256 tile (MH=2), grid (12,16)=192 ========
// One dispatch round (192 < 256 CUs), K-loop identical to k_gemm256<MH=2>.
// Wave tile = 128 rows x 64 cols -> wave-uniform region routing:
//  Q: qbf[tok][ck] plain, PRE-SCALED by 0.125 (bf16-exact)
//  K: kbf[tok][h*64 + dswz]  (d-chunk XOR tok&7)
//  V: vtbf[b][h][d][s_swz]   (s-chunk XOR d&7), transposed via 2x2 Sg passes
__global__ __launch_bounds__(512, 2) void k_gemm256_qkv(
    const u16* __restrict__ A, const u16* __restrict__ B,
    const float* __restrict__ bq, const float* __restrict__ bk,
    const float* __restrict__ bv, u16* __restrict__ qbf, u16* __restrict__ kbf,
    u16* __restrict__ vtbf, int M, int N, int K) {
  __shared__ alignas(16) u16 lds[2 * 4 * 8192];  // 128 KB
  const int t = threadIdx.x;
  const int w = t >> 6, l = t & 63;
  const int wr = w >> 2, wc = w & 3;
  const int lr = l & 15, lg = l >> 4;
  const int r7 = lr & 7;
  const int lrow8 = l >> 3;

  const int gx = gridDim.x;
  int lin = blockIdx.y * gx + blockIdx.x;
  const int nwg = gx * gridDim.y;
  lin = (lin & 7) * (nwg >> 3) + (lin >> 3);
  const int bx = lin % gx, by = lin / gx;
  const int brow = by * 256, bcol = bx * 256;

  const f32x4 Z4 = {0.f, 0.f, 0.f, 0.f};
  f32x4 acc[8][4];
#pragma unroll
  for (int m = 0; m < 8; m++)
#pragma unroll
    for (int n = 0; n < 4; n++) acc[m][n] = Z4;

  const u16* Ag = A + (size_t)brow * K;
  const u16* Bg = B + (size_t)bcol * K;
  const int swz_src = ((l & 7) ^ ((l >> 3) & 7)) << 3;

  auto ldsH = [&](int buf, int half) { return lds + (buf * 4 + half) * 8192; };
  auto stageA = [&](int kt, int buf) {
#pragma unroll
    for (int h = 0; h < 2; h++) {
      u16* lb = ldsH(buf, h);
      const int rb = h * 128;
      gload_lds16(Ag + (size_t)(rb + w * 8 + lrow8) * K + kt * 64 + swz_src,
                  lb + w * 512);
      gload_lds16(Ag + (size_t)(rb + 64 + w * 8 + lrow8) * K + kt * 64 + swz_src,
                  lb + (8 + w) * 512);
    }
  };
  auto stageB = [&](int kt, int buf) {
#pragma unroll
    for (int h = 0; h < 2; h++) {
      u16* lb = ldsH(buf, 2 + h);
      const int rb = h * 128;
      gload_lds16(Bg + (size_t)(rb + w * 8 + lrow8) * K + kt * 64 + swz_src,
                  lb + w * 512);
      gload_lds16(Bg + (size_t)(rb + 64 + w * 8 + lrow8) * K + kt * 64 + swz_src,
                  lb + (8 + w) * 512);
    }
  };

  stageA(0, 0);
  stageB(0, 0);

  const int nkt = K >> 6;
  const int brb = (wc & 1) * 64;
  for (int kt = 0; kt < nkt; ++kt) {
    const int cur = kt & 1, nx = cur ^ 1;
    if (kt + 1 < nkt) {
      stageA(kt + 1, nx);
      asm volatile("s_waitcnt vmcnt(4)" ::: "memory");
    } else {
      asm volatile("s_waitcnt vmcnt(0)" ::: "memory");
    }
    __builtin_amdgcn_s_barrier();
    __builtin_amdgcn_sched_barrier(0);
    const u16* Ah = ldsH(cur, wr);
    const u16* Bh = ldsH(cur, 2 + (wc >> 1));
#pragma unroll
    for (int kk = 0; kk < 2; kk++) {
      s16x8 bfr[4];
#pragma unroll
      for (int nf = 0; nf < 4; nf++)
        bfr[nf] = *(const s16x8*)(Bh + (brb + nf * 16 + lr) * 64 +
                                  (((kk * 4 + lg) ^ r7) << 3));
#pragma unroll
      for (int mh = 0; mh < 2; mh++) {
        s16x8 afr[4];
#pragma unroll
        for (int i = 0; i < 4; i++)
          afr[i] = *(const s16x8*)(Ah + ((mh * 4 + i) * 16 + lr) * 64 +
                                   (((kk * 4 + lg) ^ r7) << 3));
        __builtin_amdgcn_s_setprio(1);
#pragma unroll
        for (int i = 0; i < 4; i++)
#pragma unroll
          for (int nf = 0; nf < 4; nf++)
            acc[mh * 4 + i][nf] = __builtin_amdgcn_mfma_f32_16x16x32_bf16(
                afr[i], bfr[nf], acc[mh * 4 + i][nf], 0, 0, 0);
        __builtin_amdgcn_s_setprio(0);
      }
      if (kk == 0 && kt + 1 < nkt) stageB(kt + 1, nx);
    }
    __builtin_amdgcn_sched_barrier(0);
    __builtin_amdgcn_s_barrier();
  }

  // epilogue: wave tile = 128 rows x 64 cols, region routing (wave-uniform)
  const int lg4 = lg * 4;
  const int wrb = wr * 128;
  u16* Sgw = lds + w * 2176;  // wave-private [32][68] stage
  const int colw = bcol + wc * 64;
  const int region = colw >> 10;
  const int ck0 = colw & 1023;  // 64-aligned in-region col base
  float bn[4];
  {
    const float* bb = region == 0 ? bq : region == 1 ? bk : bv;
#pragma unroll
    for (int nf = 0; nf < 4; nf++) bn[nf] = bb[ck0 + nf * 16 + lr];
  }
  const int ch = l & 7;
  if (region <= 1) {
#pragma unroll
    for (int hh = 0; hh < 4; hh++) {  // 32-row groups over 128 rows
#pragma unroll
      for (int mm = 0; mm < 2; mm++) {
        const int mf = hh * 2 + mm;
#pragma unroll
        for (int nf = 0; nf < 4; nf++)
#pragma unroll
          for (int r = 0; r < 4; r++) {
            float vv = acc[mf][nf][r] + bn[nf];
            if (region == 0) vv *= 0.125f;
            Sgw[(mm * 16 + lg4 + r) * 68 + nf * 16 + lr] = f2bf(vv);
          }
      }
#pragma unroll
      for (int i = 0; i < 4; i++) {
        const int rr = i * 8 + (l >> 3);
        u16x4 a0 = *(const u16x4*)(Sgw + rr * 68 + ch * 8);
        u16x4 a1 = *(const u16x4*)(Sgw + rr * 68 + ch * 8 + 4);
        s16x8 v8;
#pragma unroll
        for (int j = 0; j < 4; j++) { v8[j] = (short)a0[j]; v8[4 + j] = (short)a1[j]; }
        const int tok = brow + wrb + hh * 32 + rr;
        if (region == 0)
          *(s16x8*)(qbf + (size_t)tok * 1024 + ck0 + ch * 8) = v8;
        else
          *(s16x8*)(kbf + (size_t)tok * 1024 + ck0 + (((ch ^ tok) & 7) << 3)) =
              v8;
      }
    }
  } else {
    // V transposed: 2x2 passes (d-half x tok-half) through the [32][68] stage
    const int hcol = ck0 >> 6;  // head index
#pragma unroll
    for (int dh = 0; dh < 2; dh++)
#pragma unroll
      for (int th = 0; th < 2; th++) {
#pragma unroll
        for (int nn = 0; nn < 2; nn++) {
          const int nf = dh * 2 + nn;
#pragma unroll
          for (int mi = 0; mi < 4; mi++) {
            const int mf = th * 4 + mi;
#pragma unroll
            for (int r = 0; r < 4; r++)
              Sgw[(nn * 16 + lr) * 68 + mi * 16 + lg4 + r] =
                  f2bf(acc[mf][nf][r] + bn[nf]);
          }
        }
#pragma unroll
        for (int i = 0; i < 4; i++) {
          const int rr = i * 8 + (l >> 3);
          u16x4 a0 = *(const u16x4*)(Sgw + rr * 68 + ch * 8);
          u16x4 a1 = *(const u16x4*)(Sgw + rr * 68 + ch * 8 + 4);
          s16x8 v8;
#pragma unroll
          for (int j = 0; j < 4; j++) { v8[j] = (short)a0[j]; v8[4 + j] = (short)a1[j]; }
          const int d = dh * 32 + rr;
          const int tokb = brow + wrb + th * 64 + ch * 8;
          const int b = tokb >> 11, s64b = tokb & 2047;
          const int ssb = (s64b & ~63) + ((((s64b >> 3) ^ d) & 7) << 3);
          *(s16x8*)(vtbf + ((size_t)((b << 4) + hcol) * 64 + d) * 2048 + ssb) =
              v8;
        }
      }
  }
}

// ---------------- causal flash attention (8-wave, QBLK=128, 2 blocks/CU) ----
// Measured best (43.7us, 13 variants bracketed): ONE 128-row q-tile per
// block, grid 16x32 = 512 blocks; CU-pairing map qt = pp<8 ? pp : 23-pp
// (co-resident blocks sum to 17 rounds/CU flat). P buffer single-sub
// (pack/PV in two sub-phases). LDS 80KB = 2 blocks/CU.
__global__ __launch_bounds__(512, 2) void k_attn(const u16* __restrict__ q,
                                                 const u16* __restrict__ kk,
                                                 const u16* __restrict__ vt,
                                                 u16* __restrict__ o) {
  __shared__ alignas(16) u16 Ks[2][2][64 * 64];  // [dbuf][sub] 32KB
  __shared__ alignas(16) u16 Vs[2][2][64 * 64];  // 32KB
  __shared__ alignas(16) u16 Ps[8][16 * 64];     // [wave] 16KB; Q overlay
  const int t = threadIdx.x;
  const int w = t >> 6;   // 0..7
  const int l = t & 63;
  const int idx = blockIdx.x;
  const int bh = idx & 31;  // head-batch in LOW bits
  const int pp = idx >> 5;  // 0..15
  const int qt = (pp < 8) ? pp : (23 - pp);  // co-resident qt's sum to 15
  const int nt = qt + 1;                     // 128-wide kv tiles
  const int b = bh >> 4, h = bh & 15;
  const u16* qb = q + (size_t)b * SEQ * DMODEL + h * HDIM;
  const u16* kb = kk + (size_t)b * SEQ * DMODEL + h * HDIM;
  const u16* vb = vt + (size_t)((b * 16 + h) * 64) * SEQ;

  const int sr = t >> 3;        // 0..63 (full 64-row tile per call)
  const int sc = (t & 7) * 8;   // chunk col
  const int lr = l & 15, lg = l >> 4;
  const int key = lr & 7;
  const f32x4 Z4 = {0.f, 0.f, 0.f, 0.f};
  u16* PsW = &Ps[0][0] + w * 1024;  // wave-private [16][64]

  // stage Q: wave w's 16 rows into its OWN P region (2 calls, 8 rows each)
  gload_lds16(
      qb + (size_t)(qt * 128 + w * 16 + (l >> 3)) * DMODEL + (l & 7) * 8, PsW);
  gload_lds16(
      qb + (size_t)(qt * 128 + w * 16 + 8 + (l >> 3)) * DMODEL + (l & 7) * 8,
      PsW + 512);
  // stage K/V tile 0 (both subs): one call per 64x64 sub-tile
#pragma unroll
  for (int s = 0; s < 2; s++) {
    gload_lds16(kb + (size_t)(s * 64 + sr) * DMODEL + sc,
                &Ks[0][s][0] + w * 512);
    gload_lds16(vb + (size_t)sr * SEQ + s * 64 + sc, &Vs[0][s][0] + w * 512);
  }

  float m_l = -3.0e38f, l_l = 0.f;
  f32x4 oacc[4];
#pragma unroll
  for (int m = 0; m < 4; m++) oacc[m] = Z4;
  s16x8 bq0, bq1;

  for (int jt = 0; jt < nt; jt++) {
    const int cur = jt & 1;
    if (jt + 1 < nt) {
      const int nx = cur ^ 1;
      const int kvb = (jt + 1) * 128;
#pragma unroll
      for (int s = 0; s < 2; s++) {
        gload_lds16(kb + (size_t)(kvb + s * 64 + sr) * DMODEL + sc,
                    &Ks[nx][s][0] + w * 512);
        gload_lds16(vb + (size_t)sr * SEQ + kvb + s * 64 + sc,
                    &Vs[nx][s][0] + w * 512);
      }
      asm volatile("s_waitcnt vmcnt(4)" ::: "memory");
    } else {
      asm volatile("s_waitcnt vmcnt(0)" ::: "memory");
    }
    __builtin_amdgcn_s_barrier();
    __builtin_amdgcn_sched_barrier(0);
    if (jt == 0) {  // Q frags from this wave's P-region overlay
      bq0 = *(const s16x8*)(PsW + lr * 64 + lg * 8);
      bq1 = *(const s16x8*)(PsW + lr * 64 + 32 + lg * 8);
    }
    // S^T = K @ Q^T : 8 kv-frags over 2 subs (kv' = m*16 + lg*4 + r)
    f32x4 sacc[8];
#pragma unroll
    for (int m = 0; m < 8; m++) sacc[m] = Z4;
#pragma unroll
    for (int m = 0; m < 8; m++) {
      const u16* Kc = &Ks[cur][m >> 2][0];
      const int rr = (m & 3) * 16 + lr;
      s16x8 ak0 = *(const s16x8*)(Kc + rr * 64 + ((lg ^ key) << 3));
      s16x8 ak1 = *(const s16x8*)(Kc + rr * 64 + (((4 | lg) ^ key) << 3));
      sacc[m] = __builtin_amdgcn_mfma_f32_16x16x32_bf16(ak0, bq0, sacc[m], 0, 0, 0);
      sacc[m] = __builtin_amdgcn_mfma_f32_16x16x32_bf16(ak1, bq1, sacc[m], 0, 0, 0);
    }
    // mask on last tile: tile-local kv' > qg
    if (jt == nt - 1) {
      const int qg = w * 16 + lr;  // q - jt*128 when jt == qt
#pragma unroll
      for (int m = 0; m < 8; m++)
#pragma unroll
        for (int r = 0; r < 4; r++)
          if (m * 16 + lg * 4 + r > qg) sacc[m][r] = -3.0e38f;
    }
    // tree max over 8 frags + cross-lane, defer-max (T13)
    float mx[8];
#pragma unroll
    for (int m = 0; m < 8; m++)
      mx[m] = fmaxf(fmaxf(sacc[m][0], sacc[m][1]),
                    fmaxf(sacc[m][2], sacc[m][3]));
    float pmax = fmaxf(fmaxf(fmaxf(mx[0], mx[1]), fmaxf(mx[2], mx[3])),
                       fmaxf(fmaxf(mx[4], mx[5]), fmaxf(mx[6], mx[7])));
    pmax = fmaxf(pmax, __shfl_xor(pmax, 16, 64));
    pmax = fmaxf(pmax, __shfl_xor(pmax, 32, 64));
    if (!__all(pmax - m_l <= 8.0f)) {
      const float m_new = fmaxf(m_l, pmax);
      const float alpha = __expf(m_l - m_new);
      m_l = m_new;
      l_l *= alpha;
#pragma unroll
      for (int m = 0; m < 4; m++)
#pragma unroll
        for (int r = 0; r < 4; r++) oacc[m][r] *= alpha;
    }
    float p_[8][4], sm[8];
#pragma unroll
    for (int m = 0; m < 8; m++) {
#pragma unroll
      for (int r = 0; r < 4; r++) p_[m][r] = __expf(sacc[m][r] - m_l);
      sm[m] = (p_[m][0] + p_[m][1]) + (p_[m][2] + p_[m][3]);
    }
    float rs = ((sm[0] + sm[1]) + (sm[2] + sm[3])) +
               ((sm[4] + sm[5]) + (sm[6] + sm[7]));
    rs += __shfl_xor(rs, 16, 64);
    rs += __shfl_xor(rs, 32, 64);
    l_l += rs;
    // pack + PV in TWO sub-phases reusing the single wave-private P region
#pragma unroll
    for (int sub = 0; sub < 2; sub++) {
#pragma unroll
      for (int mi = 0; mi < 4; mi++) {
        const int m = sub * 4 + mi;
#pragma unroll
        for (int pr = 0; pr < 2; pr++) {
          const uint32_t pk = pk_bf16(p_[m][2 * pr], p_[m][2 * pr + 1]);
          const int kvp = mi * 16 + lg * 4 + 2 * pr;  // 0..63 within sub
          ((uint32_t*)PsW)[lr * 32 + (((kvp >> 3) ^ key) << 2) +
                           ((kvp >> 1) & 3)] = pk;
        }
      }
      __builtin_amdgcn_sched_barrier(0);
      const u16* Vc = &Vs[cur][sub][0];
#pragma unroll
      for (int ki = 0; ki < 2; ki++) {
        const int c = ki * 4 + lg;
        s16x8 bp = *(const s16x8*)(PsW + lr * 64 + ((c ^ key) << 3));
#pragma unroll
        for (int m = 0; m < 4; m++) {
          s16x8 av =
              *(const s16x8*)(Vc + (m * 16 + lr) * 64 + ((c ^ key) << 3));
          oacc[m] = __builtin_amdgcn_mfma_f32_16x16x32_bf16(av, bp, oacc[m], 0, 0, 0);
        }
      }
      __builtin_amdgcn_sched_barrier(0);
    }
    __builtin_amdgcn_s_barrier();
  }
  // epilogue: lane holds O[q=lr][d=m*16+lg*4+r]
  const float rl = 1.0f / l_l;
  const int tok = qt * 128 + w * 16 + lr;
  u16* orow = o + (size_t)(b * SEQ + tok) * DMODEL + h * HDIM;
#pragma unroll
  for (int m = 0; m < 4; m++)
#pragma unroll
    for (int pr = 0; pr < 2; pr++) {
      const uint32_t pk =
          pk_bf16(oacc[m][2 * pr] * rl, oacc[m][2 * pr + 1] * rl);
      *(uint32_t*)(orow + m * 16 + lg * 4 + 2 * pr) = pk;
    }
}

// ---------------- fused residual add + LayerNorm ----------------
// vv = X + Y (+ Y1 if non-null). X input is ALWAYS bf16 now (R23: LN1 also
// uses Xbf -- saves the 16MB f32 X read; bf16 rounding of the residual adds
// ~0.008 abs error, far under the 0.104 threshold; same trick validated on
// LN2 since R18).
__global__ __launch_bounds__(256) void k_add_ln(const u16* __restrict__ Xv,
                                                const float* __restrict__ Y,
                                                const float* __restrict__ Y1,
                                                const float* __restrict__ w,
                                                const float* __restrict__ bias,
                                                float* __restrict__ of32,
                                                u16* __restrict__ obf) {
  __shared__ float sred[4];
  const int t = threadIdx.x;
  const size_t row = blockIdx.x;
  f32x4 xv;
  {
    u16x4 xu = ((const u16x4*)(Xv + row * DMODEL))[t];
    for (int i = 0; i < 4; i++)
      xv[i] = __uint_as_float((uint32_t)xu[i] << 16);
  }
  f32x4 yv = ((const f32x4*)(Y + row * DMODEL))[t];
  f32x4 vv;
  for (int i = 0; i < 4; i++) vv[i] = xv[i] + yv[i];
  if (Y1) {
    f32x4 y1 = ((const f32x4*)(Y1 + row * DMODEL))[t];
    for (int i = 0; i < 4; i++) vv[i] += y1[i];
  }
  float s = vv[0] + vv[1] + vv[2] + vv[3];
  for (int off = 32; off >= 1; off >>= 1) s += __shfl_xor(s, off, 64);
  if ((t & 63) == 0) sred[t >> 6] = s;
  __syncthreads();
  s = sred[0] + sred[1] + sred[2] + sred[3];
  const float mean = s * (1.0f / DMODEL);
  f32x4 dv;
  for (int i = 0; i < 4; i++) dv[i] = vv[i] - mean;
  float ss = dv[0] * dv[0] + dv[1] * dv[1] + dv[2] * dv[2] + dv[3] * dv[3];
  __syncthreads();
  for (int off = 32; off >= 1; off >>= 1) ss += __shfl_xor(ss, off, 64);
  if ((t & 63) == 0) sred[t >> 6] = ss;
  __syncthreads();
  ss = sred[0] + sred[1] + sred[2] + sred[3];
  const float rs = rsqrtf(ss * (1.0f / DMODEL) + 1e-5f);
  f32x4 wv = ((const f32x4*)w)[t];
  f32x4 bv = ((const f32x4*)bias)[t];
  f32x4 ov;
  for (int i = 0; i < 4; i++) ov[i] = dv[i] * rs * wv[i] + bv[i];
  if (of32) ((f32x4*)(of32 + row * DMODEL))[t] = ov;
  if (obf) {
    u16x4 ob;
    for (int i = 0; i < 4; i++) ob[i] = f2bf(ov[i]);
    ((u16x4*)(obf + row * DMODEL))[t] = ob;
  }
}

extern "C" void kernel_launch(void* const* d_in, const int* in_sizes, int n_in,
                              void* d_out, int out_size, void* d_ws,
                              size_t ws_size, hipStream_t stream) {
  const float* X = (const float*)d_in[0];
  const float* Wq = (const float*)d_in[1];
  const float* bq = (const float*)d_in[2];
  const float* Wk = (const float*)d_in[3];
  const float* bk = (const float*)d_in[4];
  const float* Wv = (const float*)d_in[5];
  const float* bvp = (const float*)d_in[6];
  const float* Wo = (const float*)d_in[7];
  const float* bo = (const float*)d_in[8];
  const float* ln1w = (const float*)d_in[9];
  const float* ln1b = (const float*)d_in[10];
  const float* Wup = (const float*)d_in[11];
  const float* bup = (const float*)d_in[12];
  const float* Wdown = (const float*)d_in[13];
  const float* bdown = (const float*)d_in[14];
  const float* ln2w = (const float*)d_in[15];
  const float* ln2b = (const float*)d_in[16];

  char* ws = (char*)d_ws;
  const size_t MB = 1024 * 1024;
  u16* Xbf = (u16*)(ws + 0);          // 8MB; also LN1's bf16 residual input
  u16* qbf = (u16*)(ws + 8 * MB);     // 8MB (pre-scaled by 0.125)
  u16* kbf = (u16*)(ws + 16 * MB);    // 8MB (d-swizzled)
  u16* vtbf = (u16*)(ws + 24 * MB);   // 8MB (transposed + s-swizzled)
  u16* wqkv = (u16*)(ws + 32 * MB);   // 6MB concat [Wq;Wk;Wv] bf16
  u16* wo = (u16*)(ws + 38 * MB);     // 2MB
  u16* attnb = (u16*)(ws + 40 * MB);  // 8MB
  float* Ybuf = (float*)(ws + 48 * MB);  // 16MB (split-K partial z=0)
  u16* wbig = (u16*)(ws + 64 * MB);      // 8MB (Wup bf16)
  u16* wdownbf = (u16*)(ws + 72 * MB);   // 8MB (Wdown bf16)
  u16* xbf = (u16*)(ws + 80 * MB);       // 8MB (LN1 out, also LN2 residual)
  u16* upbf = (u16*)(ws + 88 * MB);      // 32MB (up activations)
  float* Ypart = (float*)d_out;  // 16MB f32: free scratch until final LN

  const dim3 blk(256);
  // ALL converts in one dispatch: X + Wq/Wk/Wv + Wo + Wup + Wdown
  k_f2bf_all<<<dim3(128, 16), blk, 0, stream>>>(
      X, Wq, Wk, Wv, Wo, Wup, Wdown, Xbf, wqkv, wo, wbig, wdownbf);

  // QKV: 256x256 tile (MH=2) -> grid (12,16) = 192 blocks, single round
  k_gemm256_qkv<<<dim3(12, 16), dim3(512), 0, stream>>>(
      Xbf, wqkv, bq, bk, bvp, qbf, kbf, vtbf, MTOK, 3 * DMODEL, DMODEL);
  // attn: single 128-row q-tile/block, CU-paired map -> 512 blocks, 2/CU
  k_attn<<<16 * NBATCH * NHEAD, dim3(512), 0, stream>>>(qbf, kbf, vtbf, attnb);
  // Wo-proj: 256-col tile, BM=128, split-K=2 -> grid (4,32,2) = 256 blocks
  k_gemm256<0, 2, 1><<<dim3(4, 32, 2), dim3(512), 0, stream>>>(
      attnb, wo, bo, Ybuf, Ypart, MTOK, DMODEL, DMODEL);
  // LN1: residual from Xbf (bf16) -- Xbf stays live (upbf moved to 88MB)
  k_add_ln<<<MTOK, blk, 0, stream>>>(Xbf, Ybuf, Ypart, ln1w, ln1b,
                                     (float*)nullptr, xbf);

  // up-proj: 256x256 tile -> grid (16,16) = 256 blocks, bf16+relu out
  k_gemm256<2, 1, 2><<<dim3(16, 16), dim3(512), 0, stream>>>(
      xbf, wbig, bup, upbf, nullptr, MTOK, 4 * DMODEL, DMODEL);
  // down-proj: 256-col tile, BM=128, split-K=2 -> grid (4,32,2)
  k_gemm256<0, 2, 1><<<dim3(4, 32, 2), dim3(512), 0, stream>>>(
      upbf, wdownbf, bdown, Ybuf, Ypart, MTOK, DMODEL, 4 * DMODEL);
  k_add_ln<<<MTOK, blk, 0, stream>>>(xbf, Ybuf, Ypart, ln2w, ln2b,
                                     (float*)d_out, (u16*)nullptr);
}

// Round 25
// 186.612 us; speedup vs baseline: 1.4903x; 1.0409x over previous
//
#include <hip/hip_runtime.h>
#include <stdint.h>

#define DMODEL 1024
#define NHEAD 16
#define HDIM 64
#define SEQ 2048
#define NBATCH 2
#define MTOK 4096  // NBATCH*SEQ

typedef float f32x4 __attribute__((ext_vector_type(4)));
typedef short s16x8 __attribute__((ext_vector_type(8)));
typedef unsigned short u16;
typedef u16 u16x4 __attribute__((ext_vector_type(4)));

typedef __attribute__((address_space(1))) const void* as1_cvp;
typedef __attribute__((address_space(3))) void* as3_vp;

__device__ inline u16 f2bf(float f) {
  uint32_t u = __float_as_uint(f);
  u = u + 0x7FFFu + ((u >> 16) & 1u);
  return (u16)(u >> 16);
}

// T12 primitive: single-instr packed f32x2 -> bf16x2 (RNE), no builtin on
// gfx950 (m240) -> inline asm.
__device__ inline uint32_t pk_bf16(float lo, float hi) {
  uint32_t r;
  asm("v_cvt_pk_bf16_f32 %0, %1, %2" : "=v"(r) : "v"(lo), "v"(hi));
  return r;
}

__device__ inline void gload_lds16(const void* g, void* l) {
  __builtin_amdgcn_global_load_lds((as1_cvp)g, (as3_vp)l, 16, 0, 0);
}

// ---------------- ALL fp32 -> bf16 converts in ONE dispatch ----------------
// 16 chunks of 1M elements: X(4) | Wq Wk Wv(3) | Wo(1) | Wup(4) | Wdown(4).
__global__ __launch_bounds__(256) void k_f2bf_all(
    const float* __restrict__ X, const float* __restrict__ Wq,
    const float* __restrict__ Wk, const float* __restrict__ Wv,
    const float* __restrict__ Wo, const float* __restrict__ Wup,
    const float* __restrict__ Wdown, u16* __restrict__ dX,
    u16* __restrict__ dqkv, u16* __restrict__ dwo, u16* __restrict__ dup,
    u16* __restrict__ ddown) {
  const int c = blockIdx.y;  // 0..15
  const size_t CH = 1024 * 1024;
  const float* src;
  u16* dst;
  if (c < 4) {
    src = X + c * CH; dst = dX + c * CH;
  } else if (c < 7) {
    src = (c == 4 ? Wq : c == 5 ? Wk : Wv) ; dst = dqkv + (size_t)(c - 4) * CH;
  } else if (c == 7) {
    src = Wo; dst = dwo;
  } else if (c < 12) {
    src = Wup + (size_t)(c - 8) * CH; dst = dup + (size_t)(c - 8) * CH;
  } else {
    src = Wdown + (size_t)(c - 12) * CH; dst = ddown + (size_t)(c - 12) * CH;
  }
  const int n4 = (int)(CH / 4);
  int i = blockIdx.x * 256 + threadIdx.x;
  const int stride = gridDim.x * 256;
  for (; i < n4; i += stride) {
    f32x4 v = ((const f32x4*)src)[i];
    u16x4 o;
    o[0] = f2bf(v[0]); o[1] = f2bf(v[1]); o[2] = f2bf(v[2]); o[3] = f2bf(v[3]);
    ((u16x4*)dst)[i] = o;
  }
}

// ============ 256-col-tile 8-wave GEMM: C[M,N] = A @ B^T + bias ============
// BN=256, BM = MH*128, BK=64, 512 threads = 8 waves (2M x 4N). T2 swizzle
// (linear LDS dest + pre-permuted global source chunk, reads XOR chunk^(row&7)
// -> conflict-free b128), T4 staggered counted vmcnt (A at iter top, B mid),
// T5 setprio. Proven R12.
// MODE: 0 = f32 split-K partial out (kz=0 -> Cv+bias, kz=1 -> Cv1),
//       1 = bf16 out via Sg LDS stage (R25: kz-gated split-K partials --
//           bf16 partials halve the 128MB f32 partial round-trip; values
//           O(1-10), bf16 rounding ~0.008/partial, margin 3.3x),
//       2 = bf16+relu out (no split-K).
template <int MODE, int KSPL, int MH>
__global__ __launch_bounds__(512, 2) void k_gemm256(
    const u16* __restrict__ A, const u16* __restrict__ B,
    const float* __restrict__ bias, void* __restrict__ Cv,
    void* __restrict__ Cv1, int M, int N, int K) {
  constexpr int HALVES = MH + 2;  // MH A-halves + 2 B-halves, 16KB each
  __shared__ alignas(16) u16 lds[2 * HALVES * 8192];
  const int t = threadIdx.x;
  const int w = t >> 6;        // 0..7
  const int l = t & 63;
  const int wr = w >> 2;       // 0..1 (M half)
  const int wc = w & 3;        // 0..3 (N quarter)
  const int lr = l & 15, lg = l >> 4;
  const int r7 = lr & 7;
  const int lrow8 = l >> 3;

  // bijective XCD swizzle on (bx,by); nwg % 8 == 0 for all our grids
  const int gx = gridDim.x;
  int lin = blockIdx.y * gx + blockIdx.x;
  const int nwg = gx * gridDim.y;
  lin = (lin & 7) * (nwg >> 3) + (lin >> 3);
  const int bx = lin % gx, by = lin / gx;
  const int kz = KSPL > 1 ? blockIdx.z : 0;
  const int Kc = K / KSPL, kbeg = kz * Kc;
  const int brow = by * (MH * 128), bcol = bx * 256;

  constexpr int MF = MH * 4;  // m-frags per wave
  const f32x4 Z4 = {0.f, 0.f, 0.f, 0.f};
  f32x4 acc[MF][4];
#pragma unroll
  for (int m = 0; m < MF; m++)
#pragma unroll
    for (int n = 0; n < 4; n++) acc[m][n] = Z4;

  const u16* Ag = A + (size_t)brow * K + kbeg;
  const u16* Bg = B + (size_t)bcol * K + kbeg;
  const int swz_src = ((l & 7) ^ ((l >> 3) & 7)) << 3;  // element offset

  auto ldsH = [&](int buf, int half) { return lds + (buf * HALVES + half) * 8192; };
  auto stageA = [&](int kt, int buf) {
#pragma unroll
    for (int h = 0; h < MH; h++) {
      u16* lb = ldsH(buf, h);
      const int rb = h * 128;
      gload_lds16(Ag + (size_t)(rb + w * 8 + lrow8) * K + kt * 64 + swz_src,
                  lb + w * 512);
      gload_lds16(Ag + (size_t)(rb + 64 + w * 8 + lrow8) * K + kt * 64 + swz_src,
                  lb + (8 + w) * 512);
    }
  };
  auto stageB = [&](int kt, int buf) {
#pragma unroll
    for (int h = 0; h < 2; h++) {
      u16* lb = ldsH(buf, MH + h);
      const int rb = h * 128;
      gload_lds16(Bg + (size_t)(rb + w * 8 + lrow8) * K + kt * 64 + swz_src,
                  lb + w * 512);
      gload_lds16(Bg + (size_t)(rb + 64 + w * 8 + lrow8) * K + kt * 64 + swz_src,
                  lb + (8 + w) * 512);
    }
  };

  stageA(0, 0);
  stageB(0, 0);

  const int nkt = Kc >> 6;
  const int arb = (MH == 2) ? 0 : wr * 64;  // A row base within half
  const int brb = (wc & 1) * 64;            // B row base within half
  for (int kt = 0; kt < nkt; ++kt) {
    const int cur = kt & 1, nx = cur ^ 1;
    if (kt + 1 < nkt) {
      stageA(kt + 1, nx);
      if (MH == 2)
        asm volatile("s_waitcnt vmcnt(4)" ::: "memory");
      else
        asm volatile("s_waitcnt vmcnt(2)" ::: "memory");
    } else {
      asm volatile("s_waitcnt vmcnt(0)" ::: "memory");
    }
    __builtin_amdgcn_s_barrier();
    __builtin_amdgcn_sched_barrier(0);
    const u16* Ah = ldsH(cur, (MH == 2) ? wr : 0);
    const u16* Bh = ldsH(cur, MH + (wc >> 1));
#pragma unroll
    for (int kk = 0; kk < 2; kk++) {
      s16x8 bfr[4];
#pragma unroll
      for (int nf = 0; nf < 4; nf++)
        bfr[nf] = *(const s16x8*)(Bh + (brb + nf * 16 + lr) * 64 +
                                  (((kk * 4 + lg) ^ r7) << 3));
#pragma unroll
      for (int mh = 0; mh < MH; mh++) {
        s16x8 afr[4];
#pragma unroll
        for (int i = 0; i < 4; i++)
          afr[i] = *(const s16x8*)(Ah + (arb + (mh * 4 + i) * 16 + lr) * 64 +
                                   (((kk * 4 + lg) ^ r7) << 3));
        __builtin_amdgcn_s_setprio(1);
#pragma unroll
        for (int i = 0; i < 4; i++)
#pragma unroll
          for (int nf = 0; nf < 4; nf++)
            acc[mh * 4 + i][nf] = __builtin_amdgcn_mfma_f32_16x16x32_bf16(
                afr[i], bfr[nf], acc[mh * 4 + i][nf], 0, 0, 0);
        __builtin_amdgcn_s_setprio(0);
      }
      if (kk == 0 && kt + 1 < nkt) stageB(kt + 1, nx);  // mid-iter issue
    }
    __builtin_amdgcn_sched_barrier(0);
    __builtin_amdgcn_s_barrier();
  }

  const int lg4 = lg * 4;
  const int wrb = wr * (MH == 2 ? 128 : 64);
  if (MODE == 0) {
    float* Co = (kz == 0) ? (float*)Cv : (float*)Cv1;
#pragma unroll
    for (int nf = 0; nf < 4; nf++) {
      const int col = bcol + wc * 64 + nf * 16 + lr;
      const float bvv = (kz == 0) ? bias[col] : 0.0f;
#pragma unroll
      for (int mf = 0; mf < MF; mf++) {
        const int row0 = brow + wrb + mf * 16 + lg4;
#pragma unroll
        for (int r = 0; r < 4; r++)
          Co[(size_t)(row0 + r) * N + col] = acc[mf][nf][r] + bvv;
      }
    }
  } else {
    u16* Sgw = lds + w * 2176;
    u16* Cout = (kz == 0) ? (u16*)Cv : (u16*)Cv1;
    float bn[4];
#pragma unroll
    for (int nf = 0; nf < 4; nf++)
      bn[nf] = (kz == 0) ? bias[bcol + wc * 64 + nf * 16 + lr] : 0.0f;
    const int ch = l & 7;
#pragma unroll
    for (int hh = 0; hh < MH * 2; hh++) {  // 32-row groups
#pragma unroll
      for (int mm = 0; mm < 2; mm++) {
        const int mf = hh * 2 + mm;
#pragma unroll
        for (int nf = 0; nf < 4; nf++)
#pragma unroll
          for (int r = 0; r < 4; r++) {
            float vv = acc[mf][nf][r] + bn[nf];
            if (MODE == 2) vv = vv > 0.f ? vv : 0.f;
            Sgw[(mm * 16 + lg4 + r) * 68 + nf * 16 + lr] = f2bf(vv);
          }
      }
#pragma unroll
      for (int i = 0; i < 4; i++) {
        const int rr = i * 8 + (l >> 3);
        u16x4 a0 = *(const u16x4*)(Sgw + rr * 68 + ch * 8);
        u16x4 a1 = *(const u16x4*)(Sgw + rr * 68 + ch * 8 + 4);
        s16x8 v8;
#pragma unroll
        for (int j = 0; j < 4; j++) { v8[j] = (short)a0[j]; v8[4 + j] = (short)a1[j]; }
        *(s16x8*)(Cout + (size_t)(brow + wrb + hh * 32 + rr) * N +
                  (bcol + wc * 64 + ch * 8)) = v8;
      }
    }
  }
}

// ============ fused QKV GEMM: 256x256 tile (MH=2), grid (12,16)=192 ========
// One dispatch round (192 < 256 CUs), K-loop identical to k_gemm256<MH=2>.
// Wave tile = 128 rows x 64 cols -> wave-uniform region routing:
//  Q: qbf[tok][ck] plain, PRE-SCALED by 0.125 (bf16-exact)
//  K: kbf[tok][h*64 + dswz]  (d-chunk XOR tok&7)
//  V: vtbf[b][h][d][s_swz]   (s-chunk XOR d&7), transposed via 2x2 Sg passes
__global__ __launch_bounds__(512, 2) void k_gemm256_qkv(
    const u16* __restrict__ A, const u16* __restrict__ B,
    const float* __restrict__ bq, const float* __restrict__ bk,
    const float* __restrict__ bv, u16* __restrict__ qbf, u16* __restrict__ kbf,
    u16* __restrict__ vtbf, int M, int N, int K) {
  __shared__ alignas(16) u16 lds[2 * 4 * 8192];  // 128 KB
  const int t = threadIdx.x;
  const int w = t >> 6, l = t & 63;
  const int wr = w >> 2, wc = w & 3;
  const int lr = l & 15, lg = l >> 4;
  const int r7 = lr & 7;
  const int lrow8 = l >> 3;

  const int gx = gridDim.x;
  int lin = blockIdx.y * gx + blockIdx.x;
  const int nwg = gx * gridDim.y;
  lin = (lin & 7) * (nwg >> 3) + (lin >> 3);
  const int bx = lin % gx, by = lin / gx;
  const int brow = by * 256, bcol = bx * 256;

  const f32x4 Z4 = {0.f, 0.f, 0.f, 0.f};
  f32x4 acc[8][4];
#pragma unroll
  for (int m = 0; m < 8; m++)
#pragma unroll
    for (int n = 0; n < 4; n++) acc[m][n] = Z4;

  const u16* Ag = A + (size_t)brow * K;
  const u16* Bg = B + (size_t)bcol * K;
  const int swz_src = ((l & 7) ^ ((l >> 3) & 7)) << 3;

  auto ldsH = [&](int buf, int half) { return lds + (buf * 4 + half) * 8192; };
  auto stageA = [&](int kt, int buf) {
#pragma unroll
    for (int h = 0; h < 2; h++) {
      u16* lb = ldsH(buf, h);
      const int rb = h * 128;
      gload_lds16(Ag + (size_t)(rb + w * 8 + lrow8) * K + kt * 64 + swz_src,
                  lb + w * 512);
      gload_lds16(Ag + (size_t)(rb + 64 + w * 8 + lrow8) * K + kt * 64 + swz_src,
                  lb + (8 + w) * 512);
    }
  };
  auto stageB = [&](int kt, int buf) {
#pragma unroll
    for (int h = 0; h < 2; h++) {
      u16* lb = ldsH(buf, 2 + h);
      const int rb = h * 128;
      gload_lds16(Bg + (size_t)(rb + w * 8 + lrow8) * K + kt * 64 + swz_src,
                  lb + w * 512);
      gload_lds16(Bg + (size_t)(rb + 64 + w * 8 + lrow8) * K + kt * 64 + swz_src,
                  lb + (8 + w) * 512);
    }
  };

  stageA(0, 0);
  stageB(0, 0);

  const int nkt = K >> 6;
  const int brb = (wc & 1) * 64;
  for (int kt = 0; kt < nkt; ++kt) {
    const int cur = kt & 1, nx = cur ^ 1;
    if (kt + 1 < nkt) {
      stageA(kt + 1, nx);
      asm volatile("s_waitcnt vmcnt(4)" ::: "memory");
    } else {
      asm volatile("s_waitcnt vmcnt(0)" ::: "memory");
    }
    __builtin_amdgcn_s_barrier();
    __builtin_amdgcn_sched_barrier(0);
    const u16* Ah = ldsH(cur, wr);
    const u16* Bh = ldsH(cur, 2 + (wc >> 1));
#pragma unroll
    for (int kk = 0; kk < 2; kk++) {
      s16x8 bfr[4];
#pragma unroll
      for (int nf = 0; nf < 4; nf++)
        bfr[nf] = *(const s16x8*)(Bh + (brb + nf * 16 + lr) * 64 +
                                  (((kk * 4 + lg) ^ r7) << 3));
#pragma unroll
      for (int mh = 0; mh < 2; mh++) {
        s16x8 afr[4];
#pragma unroll
        for (int i = 0; i < 4; i++)
          afr[i] = *(const s16x8*)(Ah + ((mh * 4 + i) * 16 + lr) * 64 +
                                   (((kk * 4 + lg) ^ r7) << 3));
        __builtin_amdgcn_s_setprio(1);
#pragma unroll
        for (int i = 0; i < 4; i++)
#pragma unroll
          for (int nf = 0; nf < 4; nf++)
            acc[mh * 4 + i][nf] = __builtin_amdgcn_mfma_f32_16x16x32_bf16(
                afr[i], bfr[nf], acc[mh * 4 + i][nf], 0, 0, 0);
        __builtin_amdgcn_s_setprio(0);
      }
      if (kk == 0 && kt + 1 < nkt) stageB(kt + 1, nx);
    }
    __builtin_amdgcn_sched_barrier(0);
    __builtin_amdgcn_s_barrier();
  }

  // epilogue: wave tile = 128 rows x 64 cols, region routing (wave-uniform)
  const int lg4 = lg * 4;
  const int wrb = wr * 128;
  u16* Sgw = lds + w * 2176;  // wave-private [32][68] stage
  const int colw = bcol + wc * 64;
  const int region = colw >> 10;
  const int ck0 = colw & 1023;  // 64-aligned in-region col base
  float bn[4];
  {
    const float* bb = region == 0 ? bq : region == 1 ? bk : bv;
#pragma unroll
    for (int nf = 0; nf < 4; nf++) bn[nf] = bb[ck0 + nf * 16 + lr];
  }
  const int ch = l & 7;
  if (region <= 1) {
#pragma unroll
    for (int hh = 0; hh < 4; hh++) {  // 32-row groups over 128 rows
#pragma unroll
      for (int mm = 0; mm < 2; mm++) {
        const int mf = hh * 2 + mm;
#pragma unroll
        for (int nf = 0; nf < 4; nf++)
#pragma unroll
          for (int r = 0; r < 4; r++) {
            float vv = acc[mf][nf][r] + bn[nf];
            if (region == 0) vv *= 0.125f;
            Sgw[(mm * 16 + lg4 + r) * 68 + nf * 16 + lr] = f2bf(vv);
          }
      }
#pragma unroll
      for (int i = 0; i < 4; i++) {
        const int rr = i * 8 + (l >> 3);
        u16x4 a0 = *(const u16x4*)(Sgw + rr * 68 + ch * 8);
        u16x4 a1 = *(const u16x4*)(Sgw + rr * 68 + ch * 8 + 4);
        s16x8 v8;
#pragma unroll
        for (int j = 0; j < 4; j++) { v8[j] = (short)a0[j]; v8[4 + j] = (short)a1[j]; }
        const int tok = brow + wrb + hh * 32 + rr;
        if (region == 0)
          *(s16x8*)(qbf + (size_t)tok * 1024 + ck0 + ch * 8) = v8;
        else
          *(s16x8*)(kbf + (size_t)tok * 1024 + ck0 + (((ch ^ tok) & 7) << 3)) =
              v8;
      }
    }
  } else {
    // V transposed: 2x2 passes (d-half x tok-half) through the [32][68] stage
    const int hcol = ck0 >> 6;  // head index
#pragma unroll
    for (int dh = 0; dh < 2; dh++)
#pragma unroll
      for (int th = 0; th < 2; th++) {
#pragma unroll
        for (int nn = 0; nn < 2; nn++) {
          const int nf = dh * 2 + nn;
#pragma unroll
          for (int mi = 0; mi < 4; mi++) {
            const int mf = th * 4 + mi;
#pragma unroll
            for (int r = 0; r < 4; r++)
              Sgw[(nn * 16 + lr) * 68 + mi * 16 + lg4 + r] =
                  f2bf(acc[mf][nf][r] + bn[nf]);
          }
        }
#pragma unroll
        for (int i = 0; i < 4; i++) {
          const int rr = i * 8 + (l >> 3);
          u16x4 a0 = *(const u16x4*)(Sgw + rr * 68 + ch * 8);
          u16x4 a1 = *(const u16x4*)(Sgw + rr * 68 + ch * 8 + 4);
          s16x8 v8;
#pragma unroll
          for (int j = 0; j < 4; j++) { v8[j] = (short)a0[j]; v8[4 + j] = (short)a1[j]; }
          const int d = dh * 32 + rr;
          const int tokb = brow + wrb + th * 64 + ch * 8;
          const int b = tokb >> 11, s64b = tokb & 2047;
          const int ssb = (s64b & ~63) + ((((s64b >> 3) ^ d) & 7) << 3);
          *(s16x8*)(vtbf + ((size_t)((b << 4) + hcol) * 64 + d) * 2048 + ssb) =
              v8;
        }
      }
  }
}

// ---------------- causal flash attention (8-wave, QBLK=128, 2 blocks/CU) ----
// Measured best (43.7us, 13 variants bracketed): ONE 128-row q-tile per
// block, grid 16x32 = 512 blocks; CU-pairing map qt = pp<8 ? pp : 23-pp
// (co-resident blocks sum to 17 rounds/CU flat). P buffer single-sub
// (pack/PV in two sub-phases). LDS 80KB = 2 blocks/CU.
__global__ __launch_bounds__(512, 2) void k_attn(const u16* __restrict__ q,
                                                 const u16* __restrict__ kk,
                                                 const u16* __restrict__ vt,
                                                 u16* __restrict__ o) {
  __shared__ alignas(16) u16 Ks[2][2][64 * 64];  // [dbuf][sub] 32KB
  __shared__ alignas(16) u16 Vs[2][2][64 * 64];  // 32KB
  __shared__ alignas(16) u16 Ps[8][16 * 64];     // [wave] 16KB; Q overlay
  const int t = threadIdx.x;
  const int w = t >> 6;   // 0..7
  const int l = t & 63;
  const int idx = blockIdx.x;
  const int bh = idx & 31;  // head-batch in LOW bits
  const int pp = idx >> 5;  // 0..15
  const int qt = (pp < 8) ? pp : (23 - pp);  // co-resident qt's sum to 15
  const int nt = qt + 1;                     // 128-wide kv tiles
  const int b = bh >> 4, h = bh & 15;
  const u16* qb = q + (size_t)b * SEQ * DMODEL + h * HDIM;
  const u16* kb = kk + (size_t)b * SEQ * DMODEL + h * HDIM;
  const u16* vb = vt + (size_t)((b * 16 + h) * 64) * SEQ;

  const int sr = t >> 3;        // 0..63 (full 64-row tile per call)
  const int sc = (t & 7) * 8;   // chunk col
  const int lr = l & 15, lg = l >> 4;
  const int key = lr & 7;
  const f32x4 Z4 = {0.f, 0.f, 0.f, 0.f};
  u16* PsW = &Ps[0][0] + w * 1024;  // wave-private [16][64]

  // stage Q: wave w's 16 rows into its OWN P region (2 calls, 8 rows each)
  gload_lds16(
      qb + (size_t)(qt * 128 + w * 16 + (l >> 3)) * DMODEL + (l & 7) * 8, PsW);
  gload_lds16(
      qb + (size_t)(qt * 128 + w * 16 + 8 + (l >> 3)) * DMODEL + (l & 7) * 8,
      PsW + 512);
  // stage K/V tile 0 (both subs): one call per 64x64 sub-tile
#pragma unroll
  for (int s = 0; s < 2; s++) {
    gload_lds16(kb + (size_t)(s * 64 + sr) * DMODEL + sc,
                &Ks[0][s][0] + w * 512);
    gload_lds16(vb + (size_t)sr * SEQ + s * 64 + sc, &Vs[0][s][0] + w * 512);
  }

  float m_l = -3.0e38f, l_l = 0.f;
  f32x4 oacc[4];
#pragma unroll
  for (int m = 0; m < 4; m++) oacc[m] = Z4;
  s16x8 bq0, bq1;

  for (int jt = 0; jt < nt; jt++) {
    const int cur = jt & 1;
    if (jt + 1 < nt) {
      const int nx = cur ^ 1;
      const int kvb = (jt + 1) * 128;
#pragma unroll
      for (int s = 0; s < 2; s++) {
        gload_lds16(kb + (size_t)(kvb + s * 64 + sr) * DMODEL + sc,
                    &Ks[nx][s][0] + w * 512);
        gload_lds16(vb + (size_t)sr * SEQ + kvb + s * 64 + sc,
                    &Vs[nx][s][0] + w * 512);
      }
      asm volatile("s_waitcnt vmcnt(4)" ::: "memory");
    } else {
      asm volatile("s_waitcnt vmcnt(0)" ::: "memory");
    }
    __builtin_amdgcn_s_barrier();
    __builtin_amdgcn_sched_barrier(0);
    if (jt == 0) {  // Q frags from this wave's P-region overlay
      bq0 = *(const s16x8*)(PsW + lr * 64 + lg * 8);
      bq1 = *(const s16x8*)(PsW + lr * 64 + 32 + lg * 8);
    }
    // S^T = K @ Q^T : 8 kv-frags over 2 subs (kv' = m*16 + lg*4 + r)
    f32x4 sacc[8];
#pragma unroll
    for (int m = 0; m < 8; m++) sacc[m] = Z4;
#pragma unroll
    for (int m = 0; m < 8; m++) {
      const u16* Kc = &Ks[cur][m >> 2][0];
      const int rr = (m & 3) * 16 + lr;
      s16x8 ak0 = *(const s16x8*)(Kc + rr * 64 + ((lg ^ key) << 3));
      s16x8 ak1 = *(const s16x8*)(Kc + rr * 64 + (((4 | lg) ^ key) << 3));
      sacc[m] = __builtin_amdgcn_mfma_f32_16x16x32_bf16(ak0, bq0, sacc[m], 0, 0, 0);
      sacc[m] = __builtin_amdgcn_mfma_f32_16x16x32_bf16(ak1, bq1, sacc[m], 0, 0, 0);
    }
    // mask on last tile: tile-local kv' > qg
    if (jt == nt - 1) {
      const int qg = w * 16 + lr;  // q - jt*128 when jt == qt
#pragma unroll
      for (int m = 0; m < 8; m++)
#pragma unroll
        for (int r = 0; r < 4; r++)
          if (m * 16 + lg * 4 + r > qg) sacc[m][r] = -3.0e38f;
    }
    // tree max over 8 frags + cross-lane, defer-max (T13)
    float mx[8];
#pragma unroll
    for (int m = 0; m < 8; m++)
      mx[m] = fmaxf(fmaxf(sacc[m][0], sacc[m][1]),
                    fmaxf(sacc[m][2], sacc[m][3]));
    float pmax = fmaxf(fmaxf(fmaxf(mx[0], mx[1]), fmaxf(mx[2], mx[3])),
                       fmaxf(fmaxf(mx[4], mx[5]), fmaxf(mx[6], mx[7])));
    pmax = fmaxf(pmax, __shfl_xor(pmax, 16, 64));
    pmax = fmaxf(pmax, __shfl_xor(pmax, 32, 64));
    if (!__all(pmax - m_l <= 8.0f)) {
      const float m_new = fmaxf(m_l, pmax);
      const float alpha = __expf(m_l - m_new);
      m_l = m_new;
      l_l *= alpha;
#pragma unroll
      for (int m = 0; m < 4; m++)
#pragma unroll
        for (int r = 0; r < 4; r++) oacc[m][r] *= alpha;
    }
    float p_[8][4], sm[8];
#pragma unroll
    for (int m = 0; m < 8; m++) {
#pragma unroll
      for (int r = 0; r < 4; r++) p_[m][r] = __expf(sacc[m][r] - m_l);
      sm[m] = (p_[m][0] + p_[m][1]) + (p_[m][2] + p_[m][3]);
    }
    float rs = ((sm[0] + sm[1]) + (sm[2] + sm[3])) +
               ((sm[4] + sm[5]) + (sm[6] + sm[7]));
    rs += __shfl_xor(rs, 16, 64);
    rs += __shfl_xor(rs, 32, 64);
    l_l += rs;
    // pack + PV in TWO sub-phases reusing the single wave-private P region
#pragma unroll
    for (int sub = 0; sub < 2; sub++) {
#pragma unroll
      for (int mi = 0; mi < 4; mi++) {
        const int m = sub * 4 + mi;
#pragma unroll
        for (int pr = 0; pr < 2; pr++) {
          const uint32_t pk = pk_bf16(p_[m][2 * pr], p_[m][2 * pr + 1]);
          const int kvp = mi * 16 + lg * 4 + 2 * pr;  // 0..63 within sub
          ((uint32_t*)PsW)[lr * 32 + (((kvp >> 3) ^ key) << 2) +
                           ((kvp >> 1) & 3)] = pk;
        }
      }
      __builtin_amdgcn_sched_barrier(0);
      const u16* Vc = &Vs[cur][sub][0];
#pragma unroll
      for (int ki = 0; ki < 2; ki++) {
        const int c = ki * 4 + lg;
        s16x8 bp = *(const s16x8*)(PsW + lr * 64 + ((c ^ key) << 3));
#pragma unroll
        for (int m = 0; m < 4; m++) {
          s16x8 av =
              *(const s16x8*)(Vc + (m * 16 + lr) * 64 + ((c ^ key) << 3));
          oacc[m] = __builtin_amdgcn_mfma_f32_16x16x32_bf16(av, bp, oacc[m], 0, 0, 0);
        }
      }
      __builtin_amdgcn_sched_barrier(0);
    }
    __builtin_amdgcn_s_barrier();
  }
  // epilogue: lane holds O[q=lr][d=m*16+lg*4+r]
  const float rl = 1.0f / l_l;
  const int tok = qt * 128 + w * 16 + lr;
  u16* orow = o + (size_t)(b * SEQ + tok) * DMODEL + h * HDIM;
#pragma unroll
  for (int m = 0; m < 4; m++)
#pragma unroll
    for (int pr = 0; pr < 2; pr++) {
      const uint32_t pk =
          pk_bf16(oacc[m][2 * pr] * rl, oacc[m][2 * pr + 1] * rl);
      *(uint32_t*)(orow + m * 16 + lg * 4 + 2 * pr) = pk;
    }
}

// ---------------- fused residual add + LayerNorm ----------------
// vv = X + Y + Y1. ALL bf16 inputs now (R25: split-K partials also bf16 --
// halves the partial round-trip; validated error class, margin 3.3x).
__global__ __launch_bounds__(256) void k_add_ln(const u16* __restrict__ Xv,
                                                const u16* __restrict__ Y,
                                                const u16* __restrict__ Y1,
                                                const float* __restrict__ w,
                                                const float* __restrict__ bias,
                                                float* __restrict__ of32,
                                                u16* __restrict__ obf) {
  __shared__ float sred[4];
  const int t = threadIdx.x;
  const size_t row = blockIdx.x;
  f32x4 xv, yv, y1v;
  {
    u16x4 xu = ((const u16x4*)(Xv + row * DMODEL))[t];
    u16x4 yu = ((const u16x4*)(Y + row * DMODEL))[t];
    u16x4 y1u = ((const u16x4*)(Y1 + row * DMODEL))[t];
    for (int i = 0; i < 4; i++) {
      xv[i] = __uint_as_float((uint32_t)xu[i] << 16);
      yv[i] = __uint_as_float((uint32_t)yu[i] << 16);
      y1v[i] = __uint_as_float((uint32_t)y1u[i] << 16);
    }
  }
  f32x4 vv;
  for (int i = 0; i < 4; i++) vv[i] = xv[i] + yv[i] + y1v[i];
  float s = vv[0] + vv[1] + vv[2] + vv[3];
  for (int off = 32; off >= 1; off >>= 1) s += __shfl_xor(s, off, 64);
  if ((t & 63) == 0) sred[t >> 6] = s;
  __syncthreads();
  s = sred[0] + sred[1] + sred[2] + sred[3];
  const float mean = s * (1.0f / DMODEL);
  f32x4 dv;
  for (int i = 0; i < 4; i++) dv[i] = vv[i] - mean;
  float ss = dv[0] * dv[0] + dv[1] * dv[1] + dv[2] * dv[2] + dv[3] * dv[3];
  __syncthreads();
  for (int off = 32; off >= 1; off >>= 1) ss += __shfl_xor(ss, off, 64);
  if ((t & 63) == 0) sred[t >> 6] = ss;
  __syncthreads();
  ss = sred[0] + sred[1] + sred[2] + sred[3];
  const float rs = rsqrtf(ss * (1.0f / DMODEL) + 1e-5f);
  f32x4 wv = ((const f32x4*)w)[t];
  f32x4 bv = ((const f32x4*)bias)[t];
  f32x4 ov;
  for (int i = 0; i < 4; i++) ov[i] = dv[i] * rs * wv[i] + bv[i];
  if (of32) ((f32x4*)(of32 + row * DMODEL))[t] = ov;
  if (obf) {
    u16x4 ob;
    for (int i = 0; i < 4; i++) ob[i] = f2bf(ov[i]);
    ((u16x4*)(obf + row * DMODEL))[t] = ob;
  }
}

extern "C" void kernel_launch(void* const* d_in, const int* in_sizes, int n_in,
                              void* d_out, int out_size, void* d_ws,
                              size_t ws_size, hipStream_t stream) {
  const float* X = (const float*)d_in[0];
  const float* Wq = (const float*)d_in[1];
  const float* bq = (const float*)d_in[2];
  const float* Wk = (const float*)d_in[3];
  const float* bk = (const float*)d_in[4];
  const float* Wv = (const float*)d_in[5];
  const float* bvp = (const float*)d_in[6];
  const float* Wo = (const float*)d_in[7];
  const float* bo = (const float*)d_in[8];
  const float* ln1w = (const float*)d_in[9];
  const float* ln1b = (const float*)d_in[10];
  const float* Wup = (const float*)d_in[11];
  const float* bup = (const float*)d_in[12];
  const float* Wdown = (const float*)d_in[13];
  const float* bdown = (const float*)d_in[14];
  const float* ln2w = (const float*)d_in[15];
  const float* ln2b = (const float*)d_in[16];

  char* ws = (char*)d_ws;
  const size_t MB = 1024 * 1024;
  u16* Xbf = (u16*)(ws + 0);          // 8MB; also LN1's bf16 residual input
  u16* qbf = (u16*)(ws + 8 * MB);     // 8MB (pre-scaled by 0.125)
  u16* kbf = (u16*)(ws + 16 * MB);    // 8MB (d-swizzled)
  u16* vtbf = (u16*)(ws + 24 * MB);   // 8MB (transposed + s-swizzled)
  u16* wqkv = (u16*)(ws + 32 * MB);   // 6MB concat [Wq;Wk;Wv] bf16
  u16* wo = (u16*)(ws + 38 * MB);     // 2MB
  u16* attnb = (u16*)(ws + 40 * MB);  // 8MB
  u16* Yb0 = (u16*)(ws + 48 * MB);    // 8MB (split-K partial z=0, bf16)
  u16* Yb1 = (u16*)(ws + 56 * MB);    // 8MB (split-K partial z=1, bf16)
  u16* wbig = (u16*)(ws + 64 * MB);      // 8MB (Wup bf16)
  u16* wdownbf = (u16*)(ws + 72 * MB);   // 8MB (Wdown bf16)
  u16* xbf = (u16*)(ws + 80 * MB);       // 8MB (LN1 out, also LN2 residual)
  u16* upbf = (u16*)(ws + 88 * MB);      // 32MB (up activations)

  const dim3 blk(256);
  // ALL converts in one dispatch: X + Wq/Wk/Wv + Wo + Wup + Wdown
  k_f2bf_all<<<dim3(128, 16), blk, 0, stream>>>(
      X, Wq, Wk, Wv, Wo, Wup, Wdown, Xbf, wqkv, wo, wbig, wdownbf);

  // QKV: 256x256 tile (MH=2) -> grid (12,16) = 192 blocks, single round
  k_gemm256_qkv<<<dim3(12, 16), dim3(512), 0, stream>>>(
      Xbf, wqkv, bq, bk, bvp, qbf, kbf, vtbf, MTOK, 3 * DMODEL, DMODEL);
  // attn: single 128-row q-tile/block, CU-paired map -> 512 blocks, 2/CU
  k_attn<<<16 * NBATCH * NHEAD, dim3(512), 0, stream>>>(qbf, kbf, vtbf, attnb);
  // Wo-proj: bf16 split-K partials -> Yb0/Yb1 (grid (4,32,2) = 256 blocks)
  k_gemm256<1, 2, 1><<<dim3(4, 32, 2), dim3(512), 0, stream>>>(
      attnb, wo, bo, Yb0, Yb1, MTOK, DMODEL, DMODEL);
  // LN1: all-bf16 inputs (Xbf + Yb0 + Yb1)
  k_add_ln<<<MTOK, blk, 0, stream>>>(Xbf, Yb0, Yb1, ln1w, ln1b,
                                     (float*)nullptr, xbf);

  // up-proj: 256x256 tile -> grid (16,16) = 256 blocks, bf16+relu out
  k_gemm256<2, 1, 2><<<dim3(16, 16), dim3(512), 0, stream>>>(
      xbf, wbig, bup, upbf, nullptr, MTOK, 4 * DMODEL, DMODEL);
  // down-proj: bf16 split-K partials -> Yb0/Yb1
  k_gemm256<1, 2, 1><<<dim3(4, 32, 2), dim3(512), 0, stream>>>(
      upbf, wdownbf, bdown, Yb0, Yb1, MTOK, DMODEL, 4 * DMODEL);
  k_add_ln<<<MTOK, blk, 0, stream>>>(xbf, Yb0, Yb1, ln2w, ln2b,
                                     (float*)d_out, (u16*)nullptr);
}

// Round 26
// 184.653 us; speedup vs baseline: 1.5061x; 1.0106x over previous
//
#include <hip/hip_runtime.h>
#include <stdint.h>

#define DMODEL 1024
#define NHEAD 16
#define HDIM 64
#define SEQ 2048
#define NBATCH 2
#define MTOK 4096  // NBATCH*SEQ

typedef float f32x4 __attribute__((ext_vector_type(4)));
typedef short s16x8 __attribute__((ext_vector_type(8)));
typedef unsigned short u16;
typedef u16 u16x4 __attribute__((ext_vector_type(4)));
typedef u16 u16x8 __attribute__((ext_vector_type(8)));

typedef __attribute__((address_space(1))) const void* as1_cvp;
typedef __attribute__((address_space(3))) void* as3_vp;

__device__ inline u16 f2bf(float f) {
  uint32_t u = __float_as_uint(f);
  u = u + 0x7FFFu + ((u >> 16) & 1u);
  return (u16)(u >> 16);
}

__device__ inline float b2f(u16 x) {
  return __uint_as_float((uint32_t)x << 16);
}

// T12 primitive: single-instr packed f32x2 -> bf16x2 (RNE), no builtin on
// gfx950 (m240) -> inline asm.
__device__ inline uint32_t pk_bf16(float lo, float hi) {
  uint32_t r;
  asm("v_cvt_pk_bf16_f32 %0, %1, %2" : "=v"(r) : "v"(lo), "v"(hi));
  return r;
}

__device__ inline void gload_lds16(const void* g, void* l) {
  __builtin_amdgcn_global_load_lds((as1_cvp)g, (as3_vp)l, 16, 0, 0);
}

// ---------------- ALL fp32 -> bf16 converts in ONE dispatch ----------------
// 16 chunks of 1M elements: X(4) | Wq Wk Wv(3) | Wo(1) | Wup(4) | Wdown(4).
__global__ __launch_bounds__(256) void k_f2bf_all(
    const float* __restrict__ X, const float* __restrict__ Wq,
    const float* __restrict__ Wk, const float* __restrict__ Wv,
    const float* __restrict__ Wo, const float* __restrict__ Wup,
    const float* __restrict__ Wdown, u16* __restrict__ dX,
    u16* __restrict__ dqkv, u16* __restrict__ dwo, u16* __restrict__ dup,
    u16* __restrict__ ddown) {
  const int c = blockIdx.y;  // 0..15
  const size_t CH = 1024 * 1024;
  const float* src;
  u16* dst;
  if (c < 4) {
    src = X + c * CH; dst = dX + c * CH;
  } else if (c < 7) {
    src = (c == 4 ? Wq : c == 5 ? Wk : Wv) ; dst = dqkv + (size_t)(c - 4) * CH;
  } else if (c == 7) {
    src = Wo; dst = dwo;
  } else if (c < 12) {
    src = Wup + (size_t)(c - 8) * CH; dst = dup + (size_t)(c - 8) * CH;
  } else {
    src = Wdown + (size_t)(c - 12) * CH; dst = ddown + (size_t)(c - 12) * CH;
  }
  const int n4 = (int)(CH / 4);
  int i = blockIdx.x * 256 + threadIdx.x;
  const int stride = gridDim.x * 256;
  for (; i < n4; i += stride) {
    f32x4 v = ((const f32x4*)src)[i];
    u16x4 o;
    o[0] = f2bf(v[0]); o[1] = f2bf(v[1]); o[2] = f2bf(v[2]); o[3] = f2bf(v[3]);
    ((u16x4*)dst)[i] = o;
  }
}

// ============ 256-col-tile 8-wave GEMM: C[M,N] = A @ B^T + bias ============
// BN=256, BM = MH*128, BK=64, 512 threads = 8 waves (2M x 4N). T2 swizzle
// (linear LDS dest + pre-permuted global source chunk, reads XOR chunk^(row&7)
// -> conflict-free b128), T4 staggered counted vmcnt (A at iter top, B mid),
// T5 setprio. Proven R12.
// MODE: 0 = f32 split-K partial out, 1 = bf16 split-K partials via Sg stage
// (kz-gated; bf16 partials halve the partial round-trip, margin 3.3x),
// 2 = bf16+relu out (no split-K).
template <int MODE, int KSPL, int MH>
__global__ __launch_bounds__(512, 2) void k_gemm256(
    const u16* __restrict__ A, const u16* __restrict__ B,
    const float* __restrict__ bias, void* __restrict__ Cv,
    void* __restrict__ Cv1, int M, int N, int K) {
  constexpr int HALVES = MH + 2;  // MH A-halves + 2 B-halves, 16KB each
  __shared__ alignas(16) u16 lds[2 * HALVES * 8192];
  const int t = threadIdx.x;
  const int w = t >> 6;        // 0..7
  const int l = t & 63;
  const int wr = w >> 2;       // 0..1 (M half)
  const int wc = w & 3;        // 0..3 (N quarter)
  const int lr = l & 15, lg = l >> 4;
  const int r7 = lr & 7;
  const int lrow8 = l >> 3;

  // bijective XCD swizzle on (bx,by); nwg % 8 == 0 for all our grids
  const int gx = gridDim.x;
  int lin = blockIdx.y * gx + blockIdx.x;
  const int nwg = gx * gridDim.y;
  lin = (lin & 7) * (nwg >> 3) + (lin >> 3);
  const int bx = lin % gx, by = lin / gx;
  const int kz = KSPL > 1 ? blockIdx.z : 0;
  const int Kc = K / KSPL, kbeg = kz * Kc;
  const int brow = by * (MH * 128), bcol = bx * 256;

  constexpr int MF = MH * 4;  // m-frags per wave
  const f32x4 Z4 = {0.f, 0.f, 0.f, 0.f};
  f32x4 acc[MF][4];
#pragma unroll
  for (int m = 0; m < MF; m++)
#pragma unroll
    for (int n = 0; n < 4; n++) acc[m][n] = Z4;

  const u16* Ag = A + (size_t)brow * K + kbeg;
  const u16* Bg = B + (size_t)bcol * K + kbeg;
  const int swz_src = ((l & 7) ^ ((l >> 3) & 7)) << 3;  // element offset

  auto ldsH = [&](int buf, int half) { return lds + (buf * HALVES + half) * 8192; };
  auto stageA = [&](int kt, int buf) {
#pragma unroll
    for (int h = 0; h < MH; h++) {
      u16* lb = ldsH(buf, h);
      const int rb = h * 128;
      gload_lds16(Ag + (size_t)(rb + w * 8 + lrow8) * K + kt * 64 + swz_src,
                  lb + w * 512);
      gload_lds16(Ag + (size_t)(rb + 64 + w * 8 + lrow8) * K + kt * 64 + swz_src,
                  lb + (8 + w) * 512);
    }
  };
  auto stageB = [&](int kt, int buf) {
#pragma unroll
    for (int h = 0; h < 2; h++) {
      u16* lb = ldsH(buf, MH + h);
      const int rb = h * 128;
      gload_lds16(Bg + (size_t)(rb + w * 8 + lrow8) * K + kt * 64 + swz_src,
                  lb + w * 512);
      gload_lds16(Bg + (size_t)(rb + 64 + w * 8 + lrow8) * K + kt * 64 + swz_src,
                  lb + (8 + w) * 512);
    }
  };

  stageA(0, 0);
  stageB(0, 0);

  const int nkt = Kc >> 6;
  const int arb = (MH == 2) ? 0 : wr * 64;  // A row base within half
  const int brb = (wc & 1) * 64;            // B row base within half
  for (int kt = 0; kt < nkt; ++kt) {
    const int cur = kt & 1, nx = cur ^ 1;
    if (kt + 1 < nkt) {
      stageA(kt + 1, nx);
      if (MH == 2)
        asm volatile("s_waitcnt vmcnt(4)" ::: "memory");
      else
        asm volatile("s_waitcnt vmcnt(2)" ::: "memory");
    } else {
      asm volatile("s_waitcnt vmcnt(0)" ::: "memory");
    }
    __builtin_amdgcn_s_barrier();
    __builtin_amdgcn_sched_barrier(0);
    const u16* Ah = ldsH(cur, (MH == 2) ? wr : 0);
    const u16* Bh = ldsH(cur, MH + (wc >> 1));
#pragma unroll
    for (int kk = 0; kk < 2; kk++) {
      s16x8 bfr[4];
#pragma unroll
      for (int nf = 0; nf < 4; nf++)
        bfr[nf] = *(const s16x8*)(Bh + (brb + nf * 16 + lr) * 64 +
                                  (((kk * 4 + lg) ^ r7) << 3));
#pragma unroll
      for (int mh = 0; mh < MH; mh++) {
        s16x8 afr[4];
#pragma unroll
        for (int i = 0; i < 4; i++)
          afr[i] = *(const s16x8*)(Ah + (arb + (mh * 4 + i) * 16 + lr) * 64 +
                                   (((kk * 4 + lg) ^ r7) << 3));
        __builtin_amdgcn_s_setprio(1);
#pragma unroll
        for (int i = 0; i < 4; i++)
#pragma unroll
          for (int nf = 0; nf < 4; nf++)
            acc[mh * 4 + i][nf] = __builtin_amdgcn_mfma_f32_16x16x32_bf16(
                afr[i], bfr[nf], acc[mh * 4 + i][nf], 0, 0, 0);
        __builtin_amdgcn_s_setprio(0);
      }
      if (kk == 0 && kt + 1 < nkt) stageB(kt + 1, nx);  // mid-iter issue
    }
    __builtin_amdgcn_sched_barrier(0);
    __builtin_amdgcn_s_barrier();
  }

  const int lg4 = lg * 4;
  const int wrb = wr * (MH == 2 ? 128 : 64);
  if (MODE == 0) {
    float* Co = (kz == 0) ? (float*)Cv : (float*)Cv1;
#pragma unroll
    for (int nf = 0; nf < 4; nf++) {
      const int col = bcol + wc * 64 + nf * 16 + lr;
      const float bvv = (kz == 0) ? bias[col] : 0.0f;
#pragma unroll
      for (int mf = 0; mf < MF; mf++) {
        const int row0 = brow + wrb + mf * 16 + lg4;
#pragma unroll
        for (int r = 0; r < 4; r++)
          Co[(size_t)(row0 + r) * N + col] = acc[mf][nf][r] + bvv;
      }
    }
  } else {
    u16* Sgw = lds + w * 2176;
    u16* Cout = (kz == 0) ? (u16*)Cv : (u16*)Cv1;
    float bn[4];
#pragma unroll
    for (int nf = 0; nf < 4; nf++)
      bn[nf] = (kz == 0) ? bias[bcol + wc * 64 + nf * 16 + lr] : 0.0f;
    const int ch = l & 7;
#pragma unroll
    for (int hh = 0; hh < MH * 2; hh++) {  // 32-row groups
#pragma unroll
      for (int mm = 0; mm < 2; mm++) {
        const int mf = hh * 2 + mm;
#pragma unroll
        for (int nf = 0; nf < 4; nf++)
#pragma unroll
          for (int r = 0; r < 4; r++) {
            float vv = acc[mf][nf][r] + bn[nf];
            if (MODE == 2) vv = vv > 0.f ? vv : 0.f;
            Sgw[(mm * 16 + lg4 + r) * 68 + nf * 16 + lr] = f2bf(vv);
          }
      }
#pragma unroll
      for (int i = 0; i < 4; i++) {
        const int rr = i * 8 + (l >> 3);
        u16x4 a0 = *(const u16x4*)(Sgw + rr * 68 + ch * 8);
        u16x4 a1 = *(const u16x4*)(Sgw + rr * 68 + ch * 8 + 4);
        s16x8 v8;
#pragma unroll
        for (int j = 0; j < 4; j++) { v8[j] = (short)a0[j]; v8[4 + j] = (short)a1[j]; }
        *(s16x8*)(Cout + (size_t)(brow + wrb + hh * 32 + rr) * N +
                  (bcol + wc * 64 + ch * 8)) = v8;
      }
    }
  }
}

// ============ fused QKV GEMM: 256x256 tile (MH=2), grid (12,16)=192 ========
// One dispatch round (192 < 256 CUs), K-loop identical to k_gemm256<MH=2>.
// Wave tile = 128 rows x 64 cols -> wave-uniform region routing:
//  Q: qbf[tok][ck] plain, PRE-SCALED by 0.125 (bf16-exact)
//  K: kbf[tok][h*64 + dswz]  (d-chunk XOR tok&7)
//  V: vtbf[b][h][d][s_swz]   (s-chunk XOR d&7), transposed via 2x2 Sg passes
__global__ __launch_bounds__(512, 2) void k_gemm256_qkv(
    const u16* __restrict__ A, const u16* __restrict__ B,
    const float* __restrict__ bq, const float* __restrict__ bk,
    const float* __restrict__ bv, u16* __restrict__ qbf, u16* __restrict__ kbf,
    u16* __restrict__ vtbf, int M, int N, int K) {
  __shared__ alignas(16) u16 lds[2 * 4 * 8192];  // 128 KB
  const int t = threadIdx.x;
  const int w = t >> 6, l = t & 63;
  const int wr = w >> 2, wc = w & 3;
  const int lr = l & 15, lg = l >> 4;
  const int r7 = lr & 7;
  const int lrow8 = l >> 3;

  const int gx = gridDim.x;
  int lin = blockIdx.y * gx + blockIdx.x;
  const int nwg = gx * gridDim.y;
  lin = (lin & 7) * (nwg >> 3) + (lin >> 3);
  const int bx = lin % gx, by = lin / gx;
  const int brow = by * 256, bcol = bx * 256;

  const f32x4 Z4 = {0.f, 0.f, 0.f, 0.f};
  f32x4 acc[8][4];
#pragma unroll
  for (int m = 0; m < 8; m++)
#pragma unroll
    for (int n = 0; n < 4; n++) acc[m][n] = Z4;

  const u16* Ag = A + (size_t)brow * K;
  const u16* Bg = B + (size_t)bcol * K;
  const int swz_src = ((l & 7) ^ ((l >> 3) & 7)) << 3;

  auto ldsH = [&](int buf, int half) { return lds + (buf * 4 + half) * 8192; };
  auto stageA = [&](int kt, int buf) {
#pragma unroll
    for (int h = 0; h < 2; h++) {
      u16* lb = ldsH(buf, h);
      const int rb = h * 128;
      gload_lds16(Ag + (size_t)(rb + w * 8 + lrow8) * K + kt * 64 + swz_src,
                  lb + w * 512);
      gload_lds16(Ag + (size_t)(rb + 64 + w * 8 + lrow8) * K + kt * 64 + swz_src,
                  lb + (8 + w) * 512);
    }
  };
  auto stageB = [&](int kt, int buf) {
#pragma unroll
    for (int h = 0; h < 2; h++) {
      u16* lb = ldsH(buf, 2 + h);
      const int rb = h * 128;
      gload_lds16(Bg + (size_t)(rb + w * 8 + lrow8) * K + kt * 64 + swz_src,
                  lb + w * 512);
      gload_lds16(Bg + (size_t)(rb + 64 + w * 8 + lrow8) * K + kt * 64 + swz_src,
                  lb + (8 + w) * 512);
    }
  };

  stageA(0, 0);
  stageB(0, 0);

  const int nkt = K >> 6;
  const int brb = (wc & 1) * 64;
  for (int kt = 0; kt < nkt; ++kt) {
    const int cur = kt & 1, nx = cur ^ 1;
    if (kt + 1 < nkt) {
      stageA(kt + 1, nx);
      asm volatile("s_waitcnt vmcnt(4)" ::: "memory");
    } else {
      asm volatile("s_waitcnt vmcnt(0)" ::: "memory");
    }
    __builtin_amdgcn_s_barrier();
    __builtin_amdgcn_sched_barrier(0);
    const u16* Ah = ldsH(cur, wr);
    const u16* Bh = ldsH(cur, 2 + (wc >> 1));
#pragma unroll
    for (int kk = 0; kk < 2; kk++) {
      s16x8 bfr[4];
#pragma unroll
      for (int nf = 0; nf < 4; nf++)
        bfr[nf] = *(const s16x8*)(Bh + (brb + nf * 16 + lr) * 64 +
                                  (((kk * 4 + lg) ^ r7) << 3));
#pragma unroll
      for (int mh = 0; mh < 2; mh++) {
        s16x8 afr[4];
#pragma unroll
        for (int i = 0; i < 4; i++)
          afr[i] = *(const s16x8*)(Ah + ((mh * 4 + i) * 16 + lr) * 64 +
                                   (((kk * 4 + lg) ^ r7) << 3));
        __builtin_amdgcn_s_setprio(1);
#pragma unroll
        for (int i = 0; i < 4; i++)
#pragma unroll
          for (int nf = 0; nf < 4; nf++)
            acc[mh * 4 + i][nf] = __builtin_amdgcn_mfma_f32_16x16x32_bf16(
                afr[i], bfr[nf], acc[mh * 4 + i][nf], 0, 0, 0);
        __builtin_amdgcn_s_setprio(0);
      }
      if (kk == 0 && kt + 1 < nkt) stageB(kt + 1, nx);
    }
    __builtin_amdgcn_sched_barrier(0);
    __builtin_amdgcn_s_barrier();
  }

  // epilogue: wave tile = 128 rows x 64 cols, region routing (wave-uniform)
  const int lg4 = lg * 4;
  const int wrb = wr * 128;
  u16* Sgw = lds + w * 2176;  // wave-private [32][68] stage
  const int colw = bcol + wc * 64;
  const int region = colw >> 10;
  const int ck0 = colw & 1023;  // 64-aligned in-region col base
  float bn[4];
  {
    const float* bb = region == 0 ? bq : region == 1 ? bk : bv;
#pragma unroll
    for (int nf = 0; nf < 4; nf++) bn[nf] = bb[ck0 + nf * 16 + lr];
  }
  const int ch = l & 7;
  if (region <= 1) {
#pragma unroll
    for (int hh = 0; hh < 4; hh++) {  // 32-row groups over 128 rows
#pragma unroll
      for (int mm = 0; mm < 2; mm++) {
        const int mf = hh * 2 + mm;
#pragma unroll
        for (int nf = 0; nf < 4; nf++)
#pragma unroll
          for (int r = 0; r < 4; r++) {
            float vv = acc[mf][nf][r] + bn[nf];
            if (region == 0) vv *= 0.125f;
            Sgw[(mm * 16 + lg4 + r) * 68 + nf * 16 + lr] = f2bf(vv);
          }
      }
#pragma unroll
      for (int i = 0; i < 4; i++) {
        const int rr = i * 8 + (l >> 3);
        u16x4 a0 = *(const u16x4*)(Sgw + rr * 68 + ch * 8);
        u16x4 a1 = *(const u16x4*)(Sgw + rr * 68 + ch * 8 + 4);
        s16x8 v8;
#pragma unroll
        for (int j = 0; j < 4; j++) { v8[j] = (short)a0[j]; v8[4 + j] = (short)a1[j]; }
        const int tok = brow + wrb + hh * 32 + rr;
        if (region == 0)
          *(s16x8*)(qbf + (size_t)tok * 1024 + ck0 + ch * 8) = v8;
        else
          *(s16x8*)(kbf + (size_t)tok * 1024 + ck0 + (((ch ^ tok) & 7) << 3)) =
              v8;
      }
    }
  } else {
    // V transposed: 2x2 passes (d-half x tok-half) through the [32][68] stage
    const int hcol = ck0 >> 6;  // head index
#pragma unroll
    for (int dh = 0; dh < 2; dh++)
#pragma unroll
      for (int th = 0; th < 2; th++) {
#pragma unroll
        for (int nn = 0; nn < 2; nn++) {
          const int nf = dh * 2 + nn;
#pragma unroll
          for (int mi = 0; mi < 4; mi++) {
            const int mf = th * 4 + mi;
#pragma unroll
            for (int r = 0; r < 4; r++)
              Sgw[(nn * 16 + lr) * 68 + mi * 16 + lg4 + r] =
                  f2bf(acc[mf][nf][r] + bn[nf]);
          }
        }
#pragma unroll
        for (int i = 0; i < 4; i++) {
          const int rr = i * 8 + (l >> 3);
          u16x4 a0 = *(const u16x4*)(Sgw + rr * 68 + ch * 8);
          u16x4 a1 = *(const u16x4*)(Sgw + rr * 68 + ch * 8 + 4);
          s16x8 v8;
#pragma unroll
          for (int j = 0; j < 4; j++) { v8[j] = (short)a0[j]; v8[4 + j] = (short)a1[j]; }
          const int d = dh * 32 + rr;
          const int tokb = brow + wrb + th * 64 + ch * 8;
          const int b = tokb >> 11, s64b = tokb & 2047;
          const int ssb = (s64b & ~63) + ((((s64b >> 3) ^ d) & 7) << 3);
          *(s16x8*)(vtbf + ((size_t)((b << 4) + hcol) * 64 + d) * 2048 + ssb) =
              v8;
        }
      }
  }
}

// ---------------- causal flash attention (8-wave, QBLK=128, 2 blocks/CU) ----
// Measured best (43.7us, 13 variants bracketed): ONE 128-row q-tile per
// block, grid 16x32 = 512 blocks; CU-pairing map qt = pp<8 ? pp : 23-pp
// (co-resident blocks sum to 17 rounds/CU flat). P buffer single-sub
// (pack/PV in two sub-phases). LDS 80KB = 2 blocks/CU.
__global__ __launch_bounds__(512, 2) void k_attn(const u16* __restrict__ q,
                                                 const u16* __restrict__ kk,
                                                 const u16* __restrict__ vt,
                                                 u16* __restrict__ o) {
  __shared__ alignas(16) u16 Ks[2][2][64 * 64];  // [dbuf][sub] 32KB
  __shared__ alignas(16) u16 Vs[2][2][64 * 64];  // 32KB
  __shared__ alignas(16) u16 Ps[8][16 * 64];     // [wave] 16KB; Q overlay
  const int t = threadIdx.x;
  const int w = t >> 6;   // 0..7
  const int l = t & 63;
  const int idx = blockIdx.x;
  const int bh = idx & 31;  // head-batch in LOW bits
  const int pp = idx >> 5;  // 0..15
  const int qt = (pp < 8) ? pp : (23 - pp);  // co-resident qt's sum to 15
  const int nt = qt + 1;                     // 128-wide kv tiles
  const int b = bh >> 4, h = bh & 15;
  const u16* qb = q + (size_t)b * SEQ * DMODEL + h * HDIM;
  const u16* kb = kk + (size_t)b * SEQ * DMODEL + h * HDIM;
  const u16* vb = vt + (size_t)((b * 16 + h) * 64) * SEQ;

  const int sr = t >> 3;        // 0..63 (full 64-row tile per call)
  const int sc = (t & 7) * 8;   // chunk col
  const int lr = l & 15, lg = l >> 4;
  const int key = lr & 7;
  const f32x4 Z4 = {0.f, 0.f, 0.f, 0.f};
  u16* PsW = &Ps[0][0] + w * 1024;  // wave-private [16][64]

  // stage Q: wave w's 16 rows into its OWN P region (2 calls, 8 rows each)
  gload_lds16(
      qb + (size_t)(qt * 128 + w * 16 + (l >> 3)) * DMODEL + (l & 7) * 8, PsW);
  gload_lds16(
      qb + (size_t)(qt * 128 + w * 16 + 8 + (l >> 3)) * DMODEL + (l & 7) * 8,
      PsW + 512);
  // stage K/V tile 0 (both subs): one call per 64x64 sub-tile
#pragma unroll
  for (int s = 0; s < 2; s++) {
    gload_lds16(kb + (size_t)(s * 64 + sr) * DMODEL + sc,
                &Ks[0][s][0] + w * 512);
    gload_lds16(vb + (size_t)sr * SEQ + s * 64 + sc, &Vs[0][s][0] + w * 512);
  }

  float m_l = -3.0e38f, l_l = 0.f;
  f32x4 oacc[4];
#pragma unroll
  for (int m = 0; m < 4; m++) oacc[m] = Z4;
  s16x8 bq0, bq1;

  for (int jt = 0; jt < nt; jt++) {
    const int cur = jt & 1;
    if (jt + 1 < nt) {
      const int nx = cur ^ 1;
      const int kvb = (jt + 1) * 128;
#pragma unroll
      for (int s = 0; s < 2; s++) {
        gload_lds16(kb + (size_t)(kvb + s * 64 + sr) * DMODEL + sc,
                    &Ks[nx][s][0] + w * 512);
        gload_lds16(vb + (size_t)sr * SEQ + kvb + s * 64 + sc,
                    &Vs[nx][s][0] + w * 512);
      }
      asm volatile("s_waitcnt vmcnt(4)" ::: "memory");
    } else {
      asm volatile("s_waitcnt vmcnt(0)" ::: "memory");
    }
    __builtin_amdgcn_s_barrier();
    __builtin_amdgcn_sched_barrier(0);
    if (jt == 0) {  // Q frags from this wave's P-region overlay
      bq0 = *(const s16x8*)(PsW + lr * 64 + lg * 8);
      bq1 = *(const s16x8*)(PsW + lr * 64 + 32 + lg * 8);
    }
    // S^T = K @ Q^T : 8 kv-frags over 2 subs (kv' = m*16 + lg*4 + r)
    f32x4 sacc[8];
#pragma unroll
    for (int m = 0; m < 8; m++) sacc[m] = Z4;
#pragma unroll
    for (int m = 0; m < 8; m++) {
      const u16* Kc = &Ks[cur][m >> 2][0];
      const int rr = (m & 3) * 16 + lr;
      s16x8 ak0 = *(const s16x8*)(Kc + rr * 64 + ((lg ^ key) << 3));
      s16x8 ak1 = *(const s16x8*)(Kc + rr * 64 + (((4 | lg) ^ key) << 3));
      sacc[m] = __builtin_amdgcn_mfma_f32_16x16x32_bf16(ak0, bq0, sacc[m], 0, 0, 0);
      sacc[m] = __builtin_amdgcn_mfma_f32_16x16x32_bf16(ak1, bq1, sacc[m], 0, 0, 0);
    }
    // mask on last tile: tile-local kv' > qg
    if (jt == nt - 1) {
      const int qg = w * 16 + lr;  // q - jt*128 when jt == qt
#pragma unroll
      for (int m = 0; m < 8; m++)
#pragma unroll
        for (int r = 0; r < 4; r++)
          if (m * 16 + lg * 4 + r > qg) sacc[m][r] = -3.0e38f;
    }
    // tree max over 8 frags + cross-lane, defer-max (T13)
    float mx[8];
#pragma unroll
    for (int m = 0; m < 8; m++)
      mx[m] = fmaxf(fmaxf(sacc[m][0], sacc[m][1]),
                    fmaxf(sacc[m][2], sacc[m][3]));
    float pmax = fmaxf(fmaxf(fmaxf(mx[0], mx[1]), fmaxf(mx[2], mx[3])),
                       fmaxf(fmaxf(mx[4], mx[5]), fmaxf(mx[6], mx[7])));
    pmax = fmaxf(pmax, __shfl_xor(pmax, 16, 64));
    pmax = fmaxf(pmax, __shfl_xor(pmax, 32, 64));
    if (!__all(pmax - m_l <= 8.0f)) {
      const float m_new = fmaxf(m_l, pmax);
      const float alpha = __expf(m_l - m_new);
      m_l = m_new;
      l_l *= alpha;
#pragma unroll
      for (int m = 0; m < 4; m++)
#pragma unroll
        for (int r = 0; r < 4; r++) oacc[m][r] *= alpha;
    }
    float p_[8][4], sm[8];
#pragma unroll
    for (int m = 0; m < 8; m++) {
#pragma unroll
      for (int r = 0; r < 4; r++) p_[m][r] = __expf(sacc[m][r] - m_l);
      sm[m] = (p_[m][0] + p_[m][1]) + (p_[m][2] + p_[m][3]);
    }
    float rs = ((sm[0] + sm[1]) + (sm[2] + sm[3])) +
               ((sm[4] + sm[5]) + (sm[6] + sm[7]));
    rs += __shfl_xor(rs, 16, 64);
    rs += __shfl_xor(rs, 32, 64);
    l_l += rs;
    // pack + PV in TWO sub-phases reusing the single wave-private P region
#pragma unroll
    for (int sub = 0; sub < 2; sub++) {
#pragma unroll
      for (int mi = 0; mi < 4; mi++) {
        const int m = sub * 4 + mi;
#pragma unroll
        for (int pr = 0; pr < 2; pr++) {
          const uint32_t pk = pk_bf16(p_[m][2 * pr], p_[m][2 * pr + 1]);
          const int kvp = mi * 16 + lg * 4 + 2 * pr;  // 0..63 within sub
          ((uint32_t*)PsW)[lr * 32 + (((kvp >> 3) ^ key) << 2) +
                           ((kvp >> 1) & 3)] = pk;
        }
      }
      __builtin_amdgcn_sched_barrier(0);
      const u16* Vc = &Vs[cur][sub][0];
#pragma unroll
      for (int ki = 0; ki < 2; ki++) {
        const int c = ki * 4 + lg;
        s16x8 bp = *(const s16x8*)(PsW + lr * 64 + ((c ^ key) << 3));
#pragma unroll
        for (int m = 0; m < 4; m++) {
          s16x8 av =
              *(const s16x8*)(Vc + (m * 16 + lr) * 64 + ((c ^ key) << 3));
          oacc[m] = __builtin_amdgcn_mfma_f32_16x16x32_bf16(av, bp, oacc[m], 0, 0, 0);
        }
      }
      __builtin_amdgcn_sched_barrier(0);
    }
    __builtin_amdgcn_s_barrier();
  }
  // epilogue: lane holds O[q=lr][d=m*16+lg*4+r]
  const float rl = 1.0f / l_l;
  const int tok = qt * 128 + w * 16 + lr;
  u16* orow = o + (size_t)(b * SEQ + tok) * DMODEL + h * HDIM;
#pragma unroll
  for (int m = 0; m < 4; m++)
#pragma unroll
    for (int pr = 0; pr < 2; pr++) {
      const uint32_t pk =
          pk_bf16(oacc[m][2 * pr] * rl, oacc[m][2 * pr + 1] * rl);
      *(uint32_t*)(orow + m * 16 + lg * 4 + 2 * pr) = pk;
    }
}

// ---------------- fused residual add + LayerNorm (wave-per-row) -------------
// R26: old LN was block-per-row with two __syncthreads-coupled reductions --
// latency-bound (~1.5k cyc/row). Now 4 waves/block, each wave owns ONE row:
// lane l holds elements {l*8..l*8+7} and {512+l*8..+7} (two coalesced 16B
// loads per input), reductions are pure shfl_xor (no LDS, no barriers).
// Grid 4096 -> 1024 blocks. vv = X + Y + Y1, all bf16 inputs.
__global__ __launch_bounds__(256) void k_add_ln(const u16* __restrict__ Xv,
                                                const u16* __restrict__ Y,
                                                const u16* __restrict__ Y1,
                                                const float* __restrict__ w,
                                                const float* __restrict__ bias,
                                                float* __restrict__ of32,
                                                u16* __restrict__ obf) {
  const int t = threadIdx.x;
  const int wv = t >> 6, l = t & 63;
  const size_t row = (size_t)blockIdx.x * 4 + wv;
  const size_t base = row * DMODEL;
  const int e0 = l * 8;        // first 8-elem group
  const int e1 = 512 + l * 8;  // second 8-elem group

  u16x8 xa = *(const u16x8*)(Xv + base + e0);
  u16x8 xb = *(const u16x8*)(Xv + base + e1);
  u16x8 ya = *(const u16x8*)(Y + base + e0);
  u16x8 yb = *(const u16x8*)(Y + base + e1);
  u16x8 za = *(const u16x8*)(Y1 + base + e0);
  u16x8 zb = *(const u16x8*)(Y1 + base + e1);

  float v[16];
#pragma unroll
  for (int i = 0; i < 8; i++) {
    v[i] = b2f(xa[i]) + b2f(ya[i]) + b2f(za[i]);
    v[8 + i] = b2f(xb[i]) + b2f(yb[i]) + b2f(zb[i]);
  }
  float s = 0.f;
#pragma unroll
  for (int i = 0; i < 16; i += 4)
    s += (v[i] + v[i + 1]) + (v[i + 2] + v[i + 3]);
#pragma unroll
  for (int off = 32; off >= 1; off >>= 1) s += __shfl_xor(s, off, 64);
  const float mean = s * (1.0f / DMODEL);
  float ss = 0.f;
#pragma unroll
  for (int i = 0; i < 16; i++) {
    const float d = v[i] - mean;
    v[i] = d;
    ss += d * d;
  }
#pragma unroll
  for (int off = 32; off >= 1; off >>= 1) ss += __shfl_xor(ss, off, 64);
  const float rsd = rsqrtf(ss * (1.0f / DMODEL) + 1e-5f);

  f32x4 w0 = ((const f32x4*)(w + e0))[0];
  f32x4 w1 = ((const f32x4*)(w + e0))[1];
  f32x4 w2 = ((const f32x4*)(w + e1))[0];
  f32x4 w3 = ((const f32x4*)(w + e1))[1];
  f32x4 b0 = ((const f32x4*)(bias + e0))[0];
  f32x4 b1 = ((const f32x4*)(bias + e0))[1];
  f32x4 b2 = ((const f32x4*)(bias + e1))[0];
  f32x4 b3 = ((const f32x4*)(bias + e1))[1];
  float ov[16];
#pragma unroll
  for (int i = 0; i < 4; i++) {
    ov[i] = v[i] * rsd * w0[i] + b0[i];
    ov[4 + i] = v[4 + i] * rsd * w1[i] + b1[i];
    ov[8 + i] = v[8 + i] * rsd * w2[i] + b2[i];
    ov[12 + i] = v[12 + i] * rsd * w3[i] + b3[i];
  }
  if (of32) {
    f32x4 o0, o1, o2, o3;
#pragma unroll
    for (int i = 0; i < 4; i++) {
      o0[i] = ov[i]; o1[i] = ov[4 + i]; o2[i] = ov[8 + i]; o3[i] = ov[12 + i];
    }
    ((f32x4*)(of32 + base + e0))[0] = o0;
    ((f32x4*)(of32 + base + e0))[1] = o1;
    ((f32x4*)(of32 + base + e1))[0] = o2;
    ((f32x4*)(of32 + base + e1))[1] = o3;
  }
  if (obf) {
    u16x8 oa, ob;
#pragma unroll
    for (int i = 0; i < 8; i++) {
      oa[i] = f2bf(ov[i]);
      ob[i] = f2bf(ov[8 + i]);
    }
    *(u16x8*)(obf + base + e0) = oa;
    *(u16x8*)(obf + base + e1) = ob;
  }
}

extern "C" void kernel_launch(void* const* d_in, const int* in_sizes, int n_in,
                              void* d_out, int out_size, void* d_ws,
                              size_t ws_size, hipStream_t stream) {
  const float* X = (const float*)d_in[0];
  const float* Wq = (const float*)d_in[1];
  const float* bq = (const float*)d_in[2];
  const float* Wk = (const float*)d_in[3];
  const float* bk = (const float*)d_in[4];
  const float* Wv = (const float*)d_in[5];
  const float* bvp = (const float*)d_in[6];
  const float* Wo = (const float*)d_in[7];
  const float* bo = (const float*)d_in[8];
  const float* ln1w = (const float*)d_in[9];
  const float* ln1b = (const float*)d_in[10];
  const float* Wup = (const float*)d_in[11];
  const float* bup = (const float*)d_in[12];
  const float* Wdown = (const float*)d_in[13];
  const float* bdown = (const float*)d_in[14];
  const float* ln2w = (const float*)d_in[15];
  const float* ln2b = (const float*)d_in[16];

  char* ws = (char*)d_ws;
  const size_t MB = 1024 * 1024;
  u16* Xbf = (u16*)(ws + 0);          // 8MB; also LN1's bf16 residual input
  u16* qbf = (u16*)(ws + 8 * MB);     // 8MB (pre-scaled by 0.125)
  u16* kbf = (u16*)(ws + 16 * MB);    // 8MB (d-swizzled)
  u16* vtbf = (u16*)(ws + 24 * MB);   // 8MB (transposed + s-swizzled)
  u16* wqkv = (u16*)(ws + 32 * MB);   // 6MB concat [Wq;Wk;Wv] bf16
  u16* wo = (u16*)(ws + 38 * MB);     // 2MB
  u16* attnb = (u16*)(ws + 40 * MB);  // 8MB
  u16* Yb0 = (u16*)(ws + 48 * MB);    // 8MB (split-K partial z=0, bf16)
  u16* Yb1 = (u16*)(ws + 56 * MB);    // 8MB (split-K partial z=1, bf16)
  u16* wbig = (u16*)(ws + 64 * MB);      // 8MB (Wup bf16)
  u16* wdownbf = (u16*)(ws + 72 * MB);   // 8MB (Wdown bf16)
  u16* xbf = (u16*)(ws + 80 * MB);       // 8MB (LN1 out, also LN2 residual)
  u16* upbf = (u16*)(ws + 88 * MB);      // 32MB (up activations)

  const dim3 blk(256);
  // ALL converts in one dispatch: X + Wq/Wk/Wv + Wo + Wup + Wdown
  k_f2bf_all<<<dim3(128, 16), blk, 0, stream>>>(
      X, Wq, Wk, Wv, Wo, Wup, Wdown, Xbf, wqkv, wo, wbig, wdownbf);

  // QKV: 256x256 tile (MH=2) -> grid (12,16) = 192 blocks, single round
  k_gemm256_qkv<<<dim3(12, 16), dim3(512), 0, stream>>>(
      Xbf, wqkv, bq, bk, bvp, qbf, kbf, vtbf, MTOK, 3 * DMODEL, DMODEL);
  // attn: single 128-row q-tile/block, CU-paired map -> 512 blocks, 2/CU
  k_attn<<<16 * NBATCH * NHEAD, dim3(512), 0, stream>>>(qbf, kbf, vtbf, attnb);
  // Wo-proj: bf16 split-K partials -> Yb0/Yb1 (grid (4,32,2) = 256 blocks)
  k_gemm256<1, 2, 1><<<dim3(4, 32, 2), dim3(512), 0, stream>>>(
      attnb, wo, bo, Yb0, Yb1, MTOK, DMODEL, DMODEL);
  // LN1: wave-per-row, all-bf16 inputs (Xbf + Yb0 + Yb1)
  k_add_ln<<<MTOK / 4, blk, 0, stream>>>(Xbf, Yb0, Yb1, ln1w, ln1b,
                                         (float*)nullptr, xbf);

  // up-proj: 256x256 tile -> grid (16,16) = 256 blocks, bf16+relu out
  k_gemm256<2, 1, 2><<<dim3(16, 16), dim3(512), 0, stream>>>(
      xbf, wbig, bup, upbf, nullptr, MTOK, 4 * DMODEL, DMODEL);
  // down-proj: bf16 split-K partials -> Yb0/Yb1
  k_gemm256<1, 2, 1><<<dim3(4, 32, 2), dim3(512), 0, stream>>>(
      upbf, wdownbf, bdown, Yb0, Yb1, MTOK, DMODEL, 4 * DMODEL);
  k_add_ln<<<MTOK / 4, blk, 0, stream>>>(xbf, Yb0, Yb1, ln2w, ln2b,
                                         (float*)d_out, (u16*)nullptr);
}

// Round 27
// 183.400 us; speedup vs baseline: 1.5164x; 1.0068x over previous
//
#include <hip/hip_runtime.h>
#include <stdint.h>

#define DMODEL 1024
#define NHEAD 16
#define HDIM 64
#define SEQ 2048
#define NBATCH 2
#define MTOK 4096  // NBATCH*SEQ

typedef float f32x4 __attribute__((ext_vector_type(4)));
typedef short s16x8 __attribute__((ext_vector_type(8)));
typedef unsigned short u16;
typedef u16 u16x4 __attribute__((ext_vector_type(4)));
typedef u16 u16x8 __attribute__((ext_vector_type(8)));

typedef __attribute__((address_space(1))) const void* as1_cvp;
typedef __attribute__((address_space(3))) void* as3_vp;

__device__ inline u16 f2bf(float f) {
  uint32_t u = __float_as_uint(f);
  u = u + 0x7FFFu + ((u >> 16) & 1u);
  return (u16)(u >> 16);
}

__device__ inline float b2f(u16 x) {
  return __uint_as_float((uint32_t)x << 16);
}

// T12 primitive: single-instr packed f32x2 -> bf16x2 (RNE), no builtin on
// gfx950 (m240) -> inline asm.
__device__ inline uint32_t pk_bf16(float lo, float hi) {
  uint32_t r;
  asm("v_cvt_pk_bf16_f32 %0, %1, %2" : "=v"(r) : "v"(lo), "v"(hi));
  return r;
}

__device__ inline void gload_lds16(const void* g, void* l) {
  __builtin_amdgcn_global_load_lds((as1_cvp)g, (as3_vp)l, 16, 0, 0);
}

// ---------------- ALL fp32 -> bf16 converts in ONE dispatch ----------------
// 16 chunks of 1M elements: X(4) | Wq Wk Wv(3) | Wo(1) | Wup(4) | Wdown(4).
// R27: 16B stores (2x f32x4 load -> 1 u16x8 store) -- halves store instrs.
__global__ __launch_bounds__(256) void k_f2bf_all(
    const float* __restrict__ X, const float* __restrict__ Wq,
    const float* __restrict__ Wk, const float* __restrict__ Wv,
    const float* __restrict__ Wo, const float* __restrict__ Wup,
    const float* __restrict__ Wdown, u16* __restrict__ dX,
    u16* __restrict__ dqkv, u16* __restrict__ dwo, u16* __restrict__ dup,
    u16* __restrict__ ddown) {
  const int c = blockIdx.y;  // 0..15
  const size_t CH = 1024 * 1024;
  const float* src;
  u16* dst;
  if (c < 4) {
    src = X + c * CH; dst = dX + c * CH;
  } else if (c < 7) {
    src = (c == 4 ? Wq : c == 5 ? Wk : Wv) ; dst = dqkv + (size_t)(c - 4) * CH;
  } else if (c == 7) {
    src = Wo; dst = dwo;
  } else if (c < 12) {
    src = Wup + (size_t)(c - 8) * CH; dst = dup + (size_t)(c - 8) * CH;
  } else {
    src = Wdown + (size_t)(c - 12) * CH; dst = ddown + (size_t)(c - 12) * CH;
  }
  const int n8 = (int)(CH / 8);
  int i = blockIdx.x * 256 + threadIdx.x;
  const int stride = gridDim.x * 256;
  for (; i < n8; i += stride) {
    f32x4 v0 = ((const f32x4*)src)[2 * i];
    f32x4 v1 = ((const f32x4*)src)[2 * i + 1];
    u16x8 o;
#pragma unroll
    for (int j = 0; j < 4; j++) {
      o[j] = f2bf(v0[j]);
      o[4 + j] = f2bf(v1[j]);
    }
    ((u16x8*)dst)[i] = o;
  }
}

// ============ 256-col-tile 8-wave GEMM: C[M,N] = A @ B^T + bias ============
// BN=256, BM = MH*128, BK=64, 512 threads = 8 waves (2M x 4N). T2 swizzle
// (linear LDS dest + pre-permuted global source chunk, reads XOR chunk^(row&7)
// -> conflict-free b128), T4 staggered counted vmcnt (A at iter top, B mid),
// T5 setprio. Proven R12.
// NOTE (R27 analysis): an m201-style 8-phase port requires half-tile-granular
// LDS recycling (whole-tile dbuf + per-phase barriers would force vmcnt(0) at
// tile boundaries, destroying T4) -- a new sync template needing race-screen.
// Current structure already maximizes pipeline depth possible with whole-tile
// dbuf: A staged at iter top (vmcnt leaves it in flight), B staged mid-iter.
// MODE: 0 = f32 split-K partial out, 1 = bf16 split-K partials via Sg stage
// (kz-gated; bf16 partials halve the partial round-trip, margin 3.3x),
// 2 = bf16+relu out (no split-K).
template <int MODE, int KSPL, int MH>
__global__ __launch_bounds__(512, 2) void k_gemm256(
    const u16* __restrict__ A, const u16* __restrict__ B,
    const float* __restrict__ bias, void* __restrict__ Cv,
    void* __restrict__ Cv1, int M, int N, int K) {
  constexpr int HALVES = MH + 2;  // MH A-halves + 2 B-halves, 16KB each
  __shared__ alignas(16) u16 lds[2 * HALVES * 8192];
  const int t = threadIdx.x;
  const int w = t >> 6;        // 0..7
  const int l = t & 63;
  const int wr = w >> 2;       // 0..1 (M half)
  const int wc = w & 3;        // 0..3 (N quarter)
  const int lr = l & 15, lg = l >> 4;
  const int r7 = lr & 7;
  const int lrow8 = l >> 3;

  // bijective XCD swizzle on (bx,by); nwg % 8 == 0 for all our grids
  const int gx = gridDim.x;
  int lin = blockIdx.y * gx + blockIdx.x;
  const int nwg = gx * gridDim.y;
  lin = (lin & 7) * (nwg >> 3) + (lin >> 3);
  const int bx = lin % gx, by = lin / gx;
  const int kz = KSPL > 1 ? blockIdx.z : 0;
  const int Kc = K / KSPL, kbeg = kz * Kc;
  const int brow = by * (MH * 128), bcol = bx * 256;

  constexpr int MF = MH * 4;  // m-frags per wave
  const f32x4 Z4 = {0.f, 0.f, 0.f, 0.f};
  f32x4 acc[MF][4];
#pragma unroll
  for (int m = 0; m < MF; m++)
#pragma unroll
    for (int n = 0; n < 4; n++) acc[m][n] = Z4;

  const u16* Ag = A + (size_t)brow * K + kbeg;
  const u16* Bg = B + (size_t)bcol * K + kbeg;
  const int swz_src = ((l & 7) ^ ((l >> 3) & 7)) << 3;  // element offset

  auto ldsH = [&](int buf, int half) { return lds + (buf * HALVES + half) * 8192; };
  auto stageA = [&](int kt, int buf) {
#pragma unroll
    for (int h = 0; h < MH; h++) {
      u16* lb = ldsH(buf, h);
      const int rb = h * 128;
      gload_lds16(Ag + (size_t)(rb + w * 8 + lrow8) * K + kt * 64 + swz_src,
                  lb + w * 512);
      gload_lds16(Ag + (size_t)(rb + 64 + w * 8 + lrow8) * K + kt * 64 + swz_src,
                  lb + (8 + w) * 512);
    }
  };
  auto stageB = [&](int kt, int buf) {
#pragma unroll
    for (int h = 0; h < 2; h++) {
      u16* lb = ldsH(buf, MH + h);
      const int rb = h * 128;
      gload_lds16(Bg + (size_t)(rb + w * 8 + lrow8) * K + kt * 64 + swz_src,
                  lb + w * 512);
      gload_lds16(Bg + (size_t)(rb + 64 + w * 8 + lrow8) * K + kt * 64 + swz_src,
                  lb + (8 + w) * 512);
    }
  };

  stageA(0, 0);
  stageB(0, 0);

  const int nkt = Kc >> 6;
  const int arb = (MH == 2) ? 0 : wr * 64;  // A row base within half
  const int brb = (wc & 1) * 64;            // B row base within half
  for (int kt = 0; kt < nkt; ++kt) {
    const int cur = kt & 1, nx = cur ^ 1;
    if (kt + 1 < nkt) {
      stageA(kt + 1, nx);
      if (MH == 2)
        asm volatile("s_waitcnt vmcnt(4)" ::: "memory");
      else
        asm volatile("s_waitcnt vmcnt(2)" ::: "memory");
    } else {
      asm volatile("s_waitcnt vmcnt(0)" ::: "memory");
    }
    __builtin_amdgcn_s_barrier();
    __builtin_amdgcn_sched_barrier(0);
    const u16* Ah = ldsH(cur, (MH == 2) ? wr : 0);
    const u16* Bh = ldsH(cur, MH + (wc >> 1));
#pragma unroll
    for (int kk = 0; kk < 2; kk++) {
      s16x8 bfr[4];
#pragma unroll
      for (int nf = 0; nf < 4; nf++)
        bfr[nf] = *(const s16x8*)(Bh + (brb + nf * 16 + lr) * 64 +
                                  (((kk * 4 + lg) ^ r7) << 3));
#pragma unroll
      for (int mh = 0; mh < MH; mh++) {
        s16x8 afr[4];
#pragma unroll
        for (int i = 0; i < 4; i++)
          afr[i] = *(const s16x8*)(Ah + (arb + (mh * 4 + i) * 16 + lr) * 64 +
                                   (((kk * 4 + lg) ^ r7) << 3));
        __builtin_amdgcn_s_setprio(1);
#pragma unroll
        for (int i = 0; i < 4; i++)
#pragma unroll
          for (int nf = 0; nf < 4; nf++)
            acc[mh * 4 + i][nf] = __builtin_amdgcn_mfma_f32_16x16x32_bf16(
                afr[i], bfr[nf], acc[mh * 4 + i][nf], 0, 0, 0);
        __builtin_amdgcn_s_setprio(0);
      }
      if (kk == 0 && kt + 1 < nkt) stageB(kt + 1, nx);  // mid-iter issue
    }
    __builtin_amdgcn_sched_barrier(0);
    __builtin_amdgcn_s_barrier();
  }

  const int lg4 = lg * 4;
  const int wrb = wr * (MH == 2 ? 128 : 64);
  if (MODE == 0) {
    float* Co = (kz == 0) ? (float*)Cv : (float*)Cv1;
#pragma unroll
    for (int nf = 0; nf < 4; nf++) {
      const int col = bcol + wc * 64 + nf * 16 + lr;
      const float bvv = (kz == 0) ? bias[col] : 0.0f;
#pragma unroll
      for (int mf = 0; mf < MF; mf++) {
        const int row0 = brow + wrb + mf * 16 + lg4;
#pragma unroll
        for (int r = 0; r < 4; r++)
          Co[(size_t)(row0 + r) * N + col] = acc[mf][nf][r] + bvv;
      }
    }
  } else {
    u16* Sgw = lds + w * 2176;
    u16* Cout = (kz == 0) ? (u16*)Cv : (u16*)Cv1;
    float bn[4];
#pragma unroll
    for (int nf = 0; nf < 4; nf++)
      bn[nf] = (kz == 0) ? bias[bcol + wc * 64 + nf * 16 + lr] : 0.0f;
    const int ch = l & 7;
#pragma unroll
    for (int hh = 0; hh < MH * 2; hh++) {  // 32-row groups
#pragma unroll
      for (int mm = 0; mm < 2; mm++) {
        const int mf = hh * 2 + mm;
#pragma unroll
        for (int nf = 0; nf < 4; nf++)
#pragma unroll
          for (int r = 0; r < 4; r++) {
            float vv = acc[mf][nf][r] + bn[nf];
            if (MODE == 2) vv = vv > 0.f ? vv : 0.f;
            Sgw[(mm * 16 + lg4 + r) * 68 + nf * 16 + lr] = f2bf(vv);
          }
      }
#pragma unroll
      for (int i = 0; i < 4; i++) {
        const int rr = i * 8 + (l >> 3);
        u16x4 a0 = *(const u16x4*)(Sgw + rr * 68 + ch * 8);
        u16x4 a1 = *(const u16x4*)(Sgw + rr * 68 + ch * 8 + 4);
        s16x8 v8;
#pragma unroll
        for (int j = 0; j < 4; j++) { v8[j] = (short)a0[j]; v8[4 + j] = (short)a1[j]; }
        *(s16x8*)(Cout + (size_t)(brow + wrb + hh * 32 + rr) * N +
                  (bcol + wc * 64 + ch * 8)) = v8;
      }
    }
  }
}

// ============ fused QKV GEMM: 256x256 tile (MH=2), grid (12,16)=192 ========
// One dispatch round (192 < 256 CUs), K-loop identical to k_gemm256<MH=2>.
// Wave tile = 128 rows x 64 cols -> wave-uniform region routing:
//  Q: qbf[tok][ck] plain, PRE-SCALED by 0.125 (bf16-exact)
//  K: kbf[tok][h*64 + dswz]  (d-chunk XOR tok&7)
//  V: vtbf[b][h][d][s_swz]   (s-chunk XOR d&7), transposed via 2x2 Sg passes
__global__ __launch_bounds__(512, 2) void k_gemm256_qkv(
    const u16* __restrict__ A, const u16* __restrict__ B,
    const float* __restrict__ bq, const float* __restrict__ bk,
    const float* __restrict__ bv, u16* __restrict__ qbf, u16* __restrict__ kbf,
    u16* __restrict__ vtbf, int M, int N, int K) {
  __shared__ alignas(16) u16 lds[2 * 4 * 8192];  // 128 KB
  const int t = threadIdx.x;
  const int w = t >> 6, l = t & 63;
  const int wr = w >> 2, wc = w & 3;
  const int lr = l & 15, lg = l >> 4;
  const int r7 = lr & 7;
  const int lrow8 = l >> 3;

  const int gx = gridDim.x;
  int lin = blockIdx.y * gx + blockIdx.x;
  const int nwg = gx * gridDim.y;
  lin = (lin & 7) * (nwg >> 3) + (lin >> 3);
  const int bx = lin % gx, by = lin / gx;
  const int brow = by * 256, bcol = bx * 256;

  const f32x4 Z4 = {0.f, 0.f, 0.f, 0.f};
  f32x4 acc[8][4];
#pragma unroll
  for (int m = 0; m < 8; m++)
#pragma unroll
    for (int n = 0; n < 4; n++) acc[m][n] = Z4;

  const u16* Ag = A + (size_t)brow * K;
  const u16* Bg = B + (size_t)bcol * K;
  const int swz_src = ((l & 7) ^ ((l >> 3) & 7)) << 3;

  auto ldsH = [&](int buf, int half) { return lds + (buf * 4 + half) * 8192; };
  auto stageA = [&](int kt, int buf) {
#pragma unroll
    for (int h = 0; h < 2; h++) {
      u16* lb = ldsH(buf, h);
      const int rb = h * 128;
      gload_lds16(Ag + (size_t)(rb + w * 8 + lrow8) * K + kt * 64 + swz_src,
                  lb + w * 512);
      gload_lds16(Ag + (size_t)(rb + 64 + w * 8 + lrow8) * K + kt * 64 + swz_src,
                  lb + (8 + w) * 512);
    }
  };
  auto stageB = [&](int kt, int buf) {
#pragma unroll
    for (int h = 0; h < 2; h++) {
      u16* lb = ldsH(buf, 2 + h);
      const int rb = h * 128;
      gload_lds16(Bg + (size_t)(rb + w * 8 + lrow8) * K + kt * 64 + swz_src,
                  lb + w * 512);
      gload_lds16(Bg + (size_t)(rb + 64 + w * 8 + lrow8) * K + kt * 64 + swz_src,
                  lb + (8 + w) * 512);
    }
  };

  stageA(0, 0);
  stageB(0, 0);

  const int nkt = K >> 6;
  const int brb = (wc & 1) * 64;
  for (int kt = 0; kt < nkt; ++kt) {
    const int cur = kt & 1, nx = cur ^ 1;
    if (kt + 1 < nkt) {
      stageA(kt + 1, nx);
      asm volatile("s_waitcnt vmcnt(4)" ::: "memory");
    } else {
      asm volatile("s_waitcnt vmcnt(0)" ::: "memory");
    }
    __builtin_amdgcn_s_barrier();
    __builtin_amdgcn_sched_barrier(0);
    const u16* Ah = ldsH(cur, wr);
    const u16* Bh = ldsH(cur, 2 + (wc >> 1));
#pragma unroll
    for (int kk = 0; kk < 2; kk++) {
      s16x8 bfr[4];
#pragma unroll
      for (int nf = 0; nf < 4; nf++)
        bfr[nf] = *(const s16x8*)(Bh + (brb + nf * 16 + lr) * 64 +
                                  (((kk * 4 + lg) ^ r7) << 3));
#pragma unroll
      for (int mh = 0; mh < 2; mh++) {
        s16x8 afr[4];
#pragma unroll
        for (int i = 0; i < 4; i++)
          afr[i] = *(const s16x8*)(Ah + ((mh * 4 + i) * 16 + lr) * 64 +
                                   (((kk * 4 + lg) ^ r7) << 3));
        __builtin_amdgcn_s_setprio(1);
#pragma unroll
        for (int i = 0; i < 4; i++)
#pragma unroll
          for (int nf = 0; nf < 4; nf++)
            acc[mh * 4 + i][nf] = __builtin_amdgcn_mfma_f32_16x16x32_bf16(
                afr[i], bfr[nf], acc[mh * 4 + i][nf], 0, 0, 0);
        __builtin_amdgcn_s_setprio(0);
      }
      if (kk == 0 && kt + 1 < nkt) stageB(kt + 1, nx);
    }
    __builtin_amdgcn_sched_barrier(0);
    __builtin_amdgcn_s_barrier();
  }

  // epilogue: wave tile = 128 rows x 64 cols, region routing (wave-uniform)
  const int lg4 = lg * 4;
  const int wrb = wr * 128;
  u16* Sgw = lds + w * 2176;  // wave-private [32][68] stage
  const int colw = bcol + wc * 64;
  const int region = colw >> 10;
  const int ck0 = colw & 1023;  // 64-aligned in-region col base
  float bn[4];
  {
    const float* bb = region == 0 ? bq : region == 1 ? bk : bv;
#pragma unroll
    for (int nf = 0; nf < 4; nf++) bn[nf] = bb[ck0 + nf * 16 + lr];
  }
  const int ch = l & 7;
  if (region <= 1) {
#pragma unroll
    for (int hh = 0; hh < 4; hh++) {  // 32-row groups over 128 rows
#pragma unroll
      for (int mm = 0; mm < 2; mm++) {
        const int mf = hh * 2 + mm;
#pragma unroll
        for (int nf = 0; nf < 4; nf++)
#pragma unroll
          for (int r = 0; r < 4; r++) {
            float vv = acc[mf][nf][r] + bn[nf];
            if (region == 0) vv *= 0.125f;
            Sgw[(mm * 16 + lg4 + r) * 68 + nf * 16 + lr] = f2bf(vv);
          }
      }
#pragma unroll
      for (int i = 0; i < 4; i++) {
        const int rr = i * 8 + (l >> 3);
        u16x4 a0 = *(const u16x4*)(Sgw + rr * 68 + ch * 8);
        u16x4 a1 = *(const u16x4*)(Sgw + rr * 68 + ch * 8 + 4);
        s16x8 v8;
#pragma unroll
        for (int j = 0; j < 4; j++) { v8[j] = (short)a0[j]; v8[4 + j] = (short)a1[j]; }
        const int tok = brow + wrb + hh * 32 + rr;
        if (region == 0)
          *(s16x8*)(qbf + (size_t)tok * 1024 + ck0 + ch * 8) = v8;
        else
          *(s16x8*)(kbf + (size_t)tok * 1024 + ck0 + (((ch ^ tok) & 7) << 3)) =
              v8;
      }
    }
  } else {
    // V transposed: 2x2 passes (d-half x tok-half) through the [32][68] stage
    const int hcol = ck0 >> 6;  // head index
#pragma unroll
    for (int dh = 0; dh < 2; dh++)
#pragma unroll
      for (int th = 0; th < 2; th++) {
#pragma unroll
        for (int nn = 0; nn < 2; nn++) {
          const int nf = dh * 2 + nn;
#pragma unroll
          for (int mi = 0; mi < 4; mi++) {
            const int mf = th * 4 + mi;
#pragma unroll
            for (int r = 0; r < 4; r++)
              Sgw[(nn * 16 + lr) * 68 + mi * 16 + lg4 + r] =
                  f2bf(acc[mf][nf][r] + bn[nf]);
          }
        }
#pragma unroll
        for (int i = 0; i < 4; i++) {
          const int rr = i * 8 + (l >> 3);
          u16x4 a0 = *(const u16x4*)(Sgw + rr * 68 + ch * 8);
          u16x4 a1 = *(const u16x4*)(Sgw + rr * 68 + ch * 8 + 4);
          s16x8 v8;
#pragma unroll
          for (int j = 0; j < 4; j++) { v8[j] = (short)a0[j]; v8[4 + j] = (short)a1[j]; }
          const int d = dh * 32 + rr;
          const int tokb = brow + wrb + th * 64 + ch * 8;
          const int b = tokb >> 11, s64b = tokb & 2047;
          const int ssb = (s64b & ~63) + ((((s64b >> 3) ^ d) & 7) << 3);
          *(s16x8*)(vtbf + ((size_t)((b << 4) + hcol) * 64 + d) * 2048 + ssb) =
              v8;
        }
      }
  }
}

// ---------------- causal flash attention (8-wave, QBLK=128, 2 blocks/CU) ----
// Measured best (43.7us, 13 variants bracketed): ONE 128-row q-tile per
// block, grid 16x32 = 512 blocks; CU-pairing map qt = pp<8 ? pp : 23-pp
// (co-resident blocks sum to 17 rounds/CU flat). P buffer single-sub
// (pack/PV in two sub-phases). LDS 80KB = 2 blocks/CU.
__global__ __launch_bounds__(512, 2) void k_attn(const u16* __restrict__ q,
                                                 const u16* __restrict__ kk,
                                                 const u16* __restrict__ vt,
                                                 u16* __restrict__ o) {
  __shared__ alignas(16) u16 Ks[2][2][64 * 64];  // [dbuf][sub] 32KB
  __shared__ alignas(16) u16 Vs[2][2][64 * 64];  // 32KB
  __shared__ alignas(16) u16 Ps[8][16 * 64];     // [wave] 16KB; Q overlay
  const int t = threadIdx.x;
  const int w = t >> 6;   // 0..7
  const int l = t & 63;
  const int idx = blockIdx.x;
  const int bh = idx & 31;  // head-batch in LOW bits
  const int pp = idx >> 5;  // 0..15
  const int qt = (pp < 8) ? pp : (23 - pp);  // co-resident qt's sum to 15
  const int nt = qt + 1;                     // 128-wide kv tiles
  const int b = bh >> 4, h = bh & 15;
  const u16* qb = q + (size_t)b * SEQ * DMODEL + h * HDIM;
  const u16* kb = kk + (size_t)b * SEQ * DMODEL + h * HDIM;
  const u16* vb = vt + (size_t)((b * 16 + h) * 64) * SEQ;

  const int sr = t >> 3;        // 0..63 (full 64-row tile per call)
  const int sc = (t & 7) * 8;   // chunk col
  const int lr = l & 15, lg = l >> 4;
  const int key = lr & 7;
  const f32x4 Z4 = {0.f, 0.f, 0.f, 0.f};
  u16* PsW = &Ps[0][0] + w * 1024;  // wave-private [16][64]

  // stage Q: wave w's 16 rows into its OWN P region (2 calls, 8 rows each)
  gload_lds16(
      qb + (size_t)(qt * 128 + w * 16 + (l >> 3)) * DMODEL + (l & 7) * 8, PsW);
  gload_lds16(
      qb + (size_t)(qt * 128 + w * 16 + 8 + (l >> 3)) * DMODEL + (l & 7) * 8,
      PsW + 512);
  // stage K/V tile 0 (both subs): one call per 64x64 sub-tile
#pragma unroll
  for (int s = 0; s < 2; s++) {
    gload_lds16(kb + (size_t)(s * 64 + sr) * DMODEL + sc,
                &Ks[0][s][0] + w * 512);
    gload_lds16(vb + (size_t)sr * SEQ + s * 64 + sc, &Vs[0][s][0] + w * 512);
  }

  float m_l = -3.0e38f, l_l = 0.f;
  f32x4 oacc[4];
#pragma unroll
  for (int m = 0; m < 4; m++) oacc[m] = Z4;
  s16x8 bq0, bq1;

  for (int jt = 0; jt < nt; jt++) {
    const int cur = jt & 1;
    if (jt + 1 < nt) {
      const int nx = cur ^ 1;
      const int kvb = (jt + 1) * 128;
#pragma unroll
      for (int s = 0; s < 2; s++) {
        gload_lds16(kb + (size_t)(kvb + s * 64 + sr) * DMODEL + sc,
                    &Ks[nx][s][0] + w * 512);
        gload_lds16(vb + (size_t)sr * SEQ + kvb + s * 64 + sc,
                    &Vs[nx][s][0] + w * 512);
      }
      asm volatile("s_waitcnt vmcnt(4)" ::: "memory");
    } else {
      asm volatile("s_waitcnt vmcnt(0)" ::: "memory");
    }
    __builtin_amdgcn_s_barrier();
    __builtin_amdgcn_sched_barrier(0);
    if (jt == 0) {  // Q frags from this wave's P-region overlay
      bq0 = *(const s16x8*)(PsW + lr * 64 + lg * 8);
      bq1 = *(const s16x8*)(PsW + lr * 64 + 32 + lg * 8);
    }
    // S^T = K @ Q^T : 8 kv-frags over 2 subs (kv' = m*16 + lg*4 + r)
    f32x4 sacc[8];
#pragma unroll
    for (int m = 0; m < 8; m++) sacc[m] = Z4;
#pragma unroll
    for (int m = 0; m < 8; m++) {
      const u16* Kc = &Ks[cur][m >> 2][0];
      const int rr = (m & 3) * 16 + lr;
      s16x8 ak0 = *(const s16x8*)(Kc + rr * 64 + ((lg ^ key) << 3));
      s16x8 ak1 = *(const s16x8*)(Kc + rr * 64 + (((4 | lg) ^ key) << 3));
      sacc[m] = __builtin_amdgcn_mfma_f32_16x16x32_bf16(ak0, bq0, sacc[m], 0, 0, 0);
      sacc[m] = __builtin_amdgcn_mfma_f32_16x16x32_bf16(ak1, bq1, sacc[m], 0, 0, 0);
    }
    // mask on last tile: tile-local kv' > qg
    if (jt == nt - 1) {
      const int qg = w * 16 + lr;  // q - jt*128 when jt == qt
#pragma unroll
      for (int m = 0; m < 8; m++)
#pragma unroll
        for (int r = 0; r < 4; r++)
          if (m * 16 + lg * 4 + r > qg) sacc[m][r] = -3.0e38f;
    }
    // tree max over 8 frags + cross-lane, defer-max (T13)
    float mx[8];
#pragma unroll
    for (int m = 0; m < 8; m++)
      mx[m] = fmaxf(fmaxf(sacc[m][0], sacc[m][1]),
                    fmaxf(sacc[m][2], sacc[m][3]));
    float pmax = fmaxf(fmaxf(fmaxf(mx[0], mx[1]), fmaxf(mx[2], mx[3])),
                       fmaxf(fmaxf(mx[4], mx[5]), fmaxf(mx[6], mx[7])));
    pmax = fmaxf(pmax, __shfl_xor(pmax, 16, 64));
    pmax = fmaxf(pmax, __shfl_xor(pmax, 32, 64));
    if (!__all(pmax - m_l <= 8.0f)) {
      const float m_new = fmaxf(m_l, pmax);
      const float alpha = __expf(m_l - m_new);
      m_l = m_new;
      l_l *= alpha;
#pragma unroll
      for (int m = 0; m < 4; m++)
#pragma unroll
        for (int r = 0; r < 4; r++) oacc[m][r] *= alpha;
    }
    float p_[8][4], sm[8];
#pragma unroll
    for (int m = 0; m < 8; m++) {
#pragma unroll
      for (int r = 0; r < 4; r++) p_[m][r] = __expf(sacc[m][r] - m_l);
      sm[m] = (p_[m][0] + p_[m][1]) + (p_[m][2] + p_[m][3]);
    }
    float rs = ((sm[0] + sm[1]) + (sm[2] + sm[3])) +
               ((sm[4] + sm[5]) + (sm[6] + sm[7]));
    rs += __shfl_xor(rs, 16, 64);
    rs += __shfl_xor(rs, 32, 64);
    l_l += rs;
    // pack + PV in TWO sub-phases reusing the single wave-private P region
#pragma unroll
    for (int sub = 0; sub < 2; sub++) {
#pragma unroll
      for (int mi = 0; mi < 4; mi++) {
        const int m = sub * 4 + mi;
#pragma unroll
        for (int pr = 0; pr < 2; pr++) {
          const uint32_t pk = pk_bf16(p_[m][2 * pr], p_[m][2 * pr + 1]);
          const int kvp = mi * 16 + lg * 4 + 2 * pr;  // 0..63 within sub
          ((uint32_t*)PsW)[lr * 32 + (((kvp >> 3) ^ key) << 2) +
                           ((kvp >> 1) & 3)] = pk;
        }
      }
      __builtin_amdgcn_sched_barrier(0);
      const u16* Vc = &Vs[cur][sub][0];
#pragma unroll
      for (int ki = 0; ki < 2; ki++) {
        const int c = ki * 4 + lg;
        s16x8 bp = *(const s16x8*)(PsW + lr * 64 + ((c ^ key) << 3));
#pragma unroll
        for (int m = 0; m < 4; m++) {
          s16x8 av =
              *(const s16x8*)(Vc + (m * 16 + lr) * 64 + ((c ^ key) << 3));
          oacc[m] = __builtin_amdgcn_mfma_f32_16x16x32_bf16(av, bp, oacc[m], 0, 0, 0);
        }
      }
      __builtin_amdgcn_sched_barrier(0);
    }
    __builtin_amdgcn_s_barrier();
  }
  // epilogue: lane holds O[q=lr][d=m*16+lg*4+r]
  const float rl = 1.0f / l_l;
  const int tok = qt * 128 + w * 16 + lr;
  u16* orow = o + (size_t)(b * SEQ + tok) * DMODEL + h * HDIM;
#pragma unroll
  for (int m = 0; m < 4; m++)
#pragma unroll
    for (int pr = 0; pr < 2; pr++) {
      const uint32_t pk =
          pk_bf16(oacc[m][2 * pr] * rl, oacc[m][2 * pr + 1] * rl);
      *(uint32_t*)(orow + m * 16 + lg * 4 + 2 * pr) = pk;
    }
}

// ---------------- fused residual add + LayerNorm (wave-per-row) -------------
// 4 waves/block, each wave owns ONE row: lane l holds elements {l*8..l*8+7}
// and {512+l*8..+7} (two coalesced 16B loads per input), reductions are pure
// shfl_xor (no LDS, no barriers). vv = X + Y + Y1, all bf16 inputs.
__global__ __launch_bounds__(256) void k_add_ln(const u16* __restrict__ Xv,
                                                const u16* __restrict__ Y,
                                                const u16* __restrict__ Y1,
                                                const float* __restrict__ w,
                                                const float* __restrict__ bias,
                                                float* __restrict__ of32,
                                                u16* __restrict__ obf) {
  const int t = threadIdx.x;
  const int wv = t >> 6, l = t & 63;
  const size_t row = (size_t)blockIdx.x * 4 + wv;
  const size_t base = row * DMODEL;
  const int e0 = l * 8;        // first 8-elem group
  const int e1 = 512 + l * 8;  // second 8-elem group

  u16x8 xa = *(const u16x8*)(Xv + base + e0);
  u16x8 xb = *(const u16x8*)(Xv + base + e1);
  u16x8 ya = *(const u16x8*)(Y + base + e0);
  u16x8 yb = *(const u16x8*)(Y + base + e1);
  u16x8 za = *(const u16x8*)(Y1 + base + e0);
  u16x8 zb = *(const u16x8*)(Y1 + base + e1);

  float v[16];
#pragma unroll
  for (int i = 0; i < 8; i++) {
    v[i] = b2f(xa[i]) + b2f(ya[i]) + b2f(za[i]);
    v[8 + i] = b2f(xb[i]) + b2f(yb[i]) + b2f(zb[i]);
  }
  float s = 0.f;
#pragma unroll
  for (int i = 0; i < 16; i += 4)
    s += (v[i] + v[i + 1]) + (v[i + 2] + v[i + 3]);
#pragma unroll
  for (int off = 32; off >= 1; off >>= 1) s += __shfl_xor(s, off, 64);
  const float mean = s * (1.0f / DMODEL);
  float ss = 0.f;
#pragma unroll
  for (int i = 0; i < 16; i++) {
    const float d = v[i] - mean;
    v[i] = d;
    ss += d * d;
  }
#pragma unroll
  for (int off = 32; off >= 1; off >>= 1) ss += __shfl_xor(ss, off, 64);
  const float rsd = rsqrtf(ss * (1.0f / DMODEL) + 1e-5f);

  f32x4 w0 = ((const f32x4*)(w + e0))[0];
  f32x4 w1 = ((const f32x4*)(w + e0))[1];
  f32x4 w2 = ((const f32x4*)(w + e1))[0];
  f32x4 w3 = ((const f32x4*)(w + e1))[1];
  f32x4 b0 = ((const f32x4*)(bias + e0))[0];
  f32x4 b1 = ((const f32x4*)(bias + e0))[1];
  f32x4 b2 = ((const f32x4*)(bias + e1))[0];
  f32x4 b3 = ((const f32x4*)(bias + e1))[1];
  float ov[16];
#pragma unroll
  for (int i = 0; i < 4; i++) {
    ov[i] = v[i] * rsd * w0[i] + b0[i];
    ov[4 + i] = v[4 + i] * rsd * w1[i] + b1[i];
    ov[8 + i] = v[8 + i] * rsd * w2[i] + b2[i];
    ov[12 + i] = v[12 + i] * rsd * w3[i] + b3[i];
  }
  if (of32) {
    f32x4 o0, o1, o2, o3;
#pragma unroll
    for (int i = 0; i < 4; i++) {
      o0[i] = ov[i]; o1[i] = ov[4 + i]; o2[i] = ov[8 + i]; o3[i] = ov[12 + i];
    }
    ((f32x4*)(of32 + base + e0))[0] = o0;
    ((f32x4*)(of32 + base + e0))[1] = o1;
    ((f32x4*)(of32 + base + e1))[0] = o2;
    ((f32x4*)(of32 + base + e1))[1] = o3;
  }
  if (obf) {
    u16x8 oa, ob;
#pragma unroll
    for (int i = 0; i < 8; i++) {
      oa[i] = f2bf(ov[i]);
      ob[i] = f2bf(ov[8 + i]);
    }
    *(u16x8*)(obf + base + e0) = oa;
    *(u16x8*)(obf + base + e1) = ob;
  }
}

extern "C" void kernel_launch(void* const* d_in, const int* in_sizes, int n_in,
                              void* d_out, int out_size, void* d_ws,
                              size_t ws_size, hipStream_t stream) {
  const float* X = (const float*)d_in[0];
  const float* Wq = (const float*)d_in[1];
  const float* bq = (const float*)d_in[2];
  const float* Wk = (const float*)d_in[3];
  const float* bk = (const float*)d_in[4];
  const float* Wv = (const float*)d_in[5];
  const float* bvp = (const float*)d_in[6];
  const float* Wo = (const float*)d_in[7];
  const float* bo = (const float*)d_in[8];
  const float* ln1w = (const float*)d_in[9];
  const float* ln1b = (const float*)d_in[10];
  const float* Wup = (const float*)d_in[11];
  const float* bup = (const float*)d_in[12];
  const float* Wdown = (const float*)d_in[13];
  const float* bdown = (const float*)d_in[14];
  const float* ln2w = (const float*)d_in[15];
  const float* ln2b = (const float*)d_in[16];

  char* ws = (char*)d_ws;
  const size_t MB = 1024 * 1024;
  u16* Xbf = (u16*)(ws + 0);          // 8MB; also LN1's bf16 residual input
  u16* qbf = (u16*)(ws + 8 * MB);     // 8MB (pre-scaled by 0.125)
  u16* kbf = (u16*)(ws + 16 * MB);    // 8MB (d-swizzled)
  u16* vtbf = (u16*)(ws + 24 * MB);   // 8MB (transposed + s-swizzled)
  u16* wqkv = (u16*)(ws + 32 * MB);   // 6MB concat [Wq;Wk;Wv] bf16
  u16* wo = (u16*)(ws + 38 * MB);     // 2MB
  u16* attnb = (u16*)(ws + 40 * MB);  // 8MB
  u16* Yb0 = (u16*)(ws + 48 * MB);    // 8MB (split-K partial z=0, bf16)
  u16* Yb1 = (u16*)(ws + 56 * MB);    // 8MB (split-K partial z=1, bf16)
  u16* wbig = (u16*)(ws + 64 * MB);      // 8MB (Wup bf16)
  u16* wdownbf = (u16*)(ws + 72 * MB);   // 8MB (Wdown bf16)
  u16* xbf = (u16*)(ws + 80 * MB);       // 8MB (LN1 out, also LN2 residual)
  u16* upbf = (u16*)(ws + 88 * MB);      // 32MB (up activations)

  const dim3 blk(256);
  // ALL converts in one dispatch: X + Wq/Wk/Wv + Wo + Wup + Wdown
  k_f2bf_all<<<dim3(128, 16), blk, 0, stream>>>(
      X, Wq, Wk, Wv, Wo, Wup, Wdown, Xbf, wqkv, wo, wbig, wdownbf);

  // QKV: 256x256 tile (MH=2) -> grid (12,16) = 192 blocks, single round
  k_gemm256_qkv<<<dim3(12, 16), dim3(512), 0, stream>>>(
      Xbf, wqkv, bq, bk, bvp, qbf, kbf, vtbf, MTOK, 3 * DMODEL, DMODEL);
  // attn: single 128-row q-tile/block, CU-paired map -> 512 blocks, 2/CU
  k_attn<<<16 * NBATCH * NHEAD, dim3(512), 0, stream>>>(qbf, kbf, vtbf, attnb);
  // Wo-proj: bf16 split-K partials -> Yb0/Yb1 (grid (4,32,2) = 256 blocks)
  k_gemm256<1, 2, 1><<<dim3(4, 32, 2), dim3(512), 0, stream>>>(
      attnb, wo, bo, Yb0, Yb1, MTOK, DMODEL, DMODEL);
  // LN1: wave-per-row, all-bf16 inputs (Xbf + Yb0 + Yb1)
  k_add_ln<<<MTOK / 4, blk, 0, stream>>>(Xbf, Yb0, Yb1, ln1w, ln1b,
                                         (float*)nullptr, xbf);

  // up-proj: 256x256 tile -> grid (16,16) = 256 blocks, bf16+relu out
  k_gemm256<2, 1, 2><<<dim3(16, 16), dim3(512), 0, stream>>>(
      xbf, wbig, bup, upbf, nullptr, MTOK, 4 * DMODEL, DMODEL);
  // down-proj: bf16 split-K partials -> Yb0/Yb1
  k_gemm256<1, 2, 1><<<dim3(4, 32, 2), dim3(512), 0, stream>>>(
      upbf, wdownbf, bdown, Yb0, Yb1, MTOK, DMODEL, 4 * DMODEL);
  k_add_ln<<<MTOK / 4, blk, 0, stream>>>(xbf, Yb0, Yb1, ln2w, ln2b,
                                         (float*)d_out, (u16*)nullptr);
}